// Round 1
// baseline (1170.233 us; speedup 1.0000x reference)
//
#include <hip/hip_runtime.h>
#include <math.h>

#define SEQ 2048
#define DMODEL 1024
#define DIN 2048
#define NST 16
#define DTR 64

// =====================================================================
// GEMM NT: C[m,n] = sum_k A[m,k]*B[n,k]
// A: M x K row-major (optionally A - A2), B: N x K row-major, C: M x N row-major
// BM=128, BN=64, BK=16, 256 threads, 8x4 micro-tile.
// =====================================================================
template<bool SUB>
__global__ __launch_bounds__(256) void gemm_nt(const float* __restrict__ A,
                                               const float* __restrict__ A2,
                                               const float* __restrict__ B,
                                               float* __restrict__ C,
                                               int M, int N, int K) {
  __shared__ __align__(16) float As[16][128];
  __shared__ __align__(16) float Bs[16][64];
  const int tid = threadIdx.x;
  const int m0 = blockIdx.y * 128;
  const int n0 = blockIdx.x * 64;
  const int ty = tid >> 4, tx = tid & 15;
  const int arow = tid >> 1, acol = (tid & 1) * 8;   // 128 rows x 16 k, 8 floats/thread
  const int brow = tid >> 2, bcol = (tid & 3) * 4;   // 64 rows x 16 k, 4 floats/thread
  float acc[8][4];
#pragma unroll
  for (int i = 0; i < 8; ++i)
#pragma unroll
    for (int j = 0; j < 4; ++j) acc[i][j] = 0.f;

  for (int k0 = 0; k0 < K; k0 += 16) {
    float4 av0 = *(const float4*)&A[(size_t)(m0 + arow) * K + k0 + acol];
    float4 av1 = *(const float4*)&A[(size_t)(m0 + arow) * K + k0 + acol + 4];
    if (SUB) {
      float4 s0 = *(const float4*)&A2[(size_t)(m0 + arow) * K + k0 + acol];
      float4 s1 = *(const float4*)&A2[(size_t)(m0 + arow) * K + k0 + acol + 4];
      av0.x -= s0.x; av0.y -= s0.y; av0.z -= s0.z; av0.w -= s0.w;
      av1.x -= s1.x; av1.y -= s1.y; av1.z -= s1.z; av1.w -= s1.w;
    }
    float4 bv = *(const float4*)&B[(size_t)(n0 + brow) * K + k0 + bcol];
    __syncthreads();
    As[acol + 0][arow] = av0.x; As[acol + 1][arow] = av0.y;
    As[acol + 2][arow] = av0.z; As[acol + 3][arow] = av0.w;
    As[acol + 4][arow] = av1.x; As[acol + 5][arow] = av1.y;
    As[acol + 6][arow] = av1.z; As[acol + 7][arow] = av1.w;
    Bs[bcol + 0][brow] = bv.x; Bs[bcol + 1][brow] = bv.y;
    Bs[bcol + 2][brow] = bv.z; Bs[bcol + 3][brow] = bv.w;
    __syncthreads();
#pragma unroll
    for (int kk = 0; kk < 16; ++kk) {
      float4 a0 = *(const float4*)&As[kk][ty * 4];
      float4 a1 = *(const float4*)&As[kk][64 + ty * 4];
      float4 b  = *(const float4*)&Bs[kk][tx * 4];
      float am[8] = {a0.x, a0.y, a0.z, a0.w, a1.x, a1.y, a1.z, a1.w};
      float bn[4] = {b.x, b.y, b.z, b.w};
#pragma unroll
      for (int i = 0; i < 8; ++i)
#pragma unroll
        for (int j = 0; j < 4; ++j)
          acc[i][j] = fmaf(am[i], bn[j], acc[i][j]);
    }
  }
#pragma unroll
  for (int i = 0; i < 4; ++i) {
    float4 w0 = make_float4(acc[i][0], acc[i][1], acc[i][2], acc[i][3]);
    float4 w1 = make_float4(acc[i + 4][0], acc[i + 4][1], acc[i + 4][2], acc[i + 4][3]);
    *(float4*)&C[(size_t)(m0 + ty * 4 + i) * N + n0 + tx * 4] = w0;
    *(float4*)&C[(size_t)(m0 + 64 + ty * 4 + i) * N + n0 + tx * 4] = w1;
  }
}

// =====================================================================
// Depthwise causal conv (w=4) + bias + SiLU.  x = xz rows [0,2048)
// =====================================================================
__global__ __launch_bounds__(256) void conv_silu_kernel(const float* __restrict__ xz,
                                                        const float* __restrict__ cw,
                                                        const float* __restrict__ cb,
                                                        float* __restrict__ xc) {
  const int d = blockIdx.y;
  const int l = blockIdx.x * 256 + threadIdx.x;
  const float* xrow = xz + (size_t)d * SEQ;
  const float w0 = cw[d * 4 + 0], w1 = cw[d * 4 + 1], w2 = cw[d * 4 + 2], w3 = cw[d * 4 + 3];
  float a = cb[d] + w3 * xrow[l];
  if (l >= 1) a += w2 * xrow[l - 1];
  if (l >= 2) a += w1 * xrow[l - 2];
  if (l >= 3) a += w0 * xrow[l - 3];
  xc[(size_t)d * SEQ + l] = a / (1.f + __expf(-a));
}

// =====================================================================
// x_proj (both branches): dbl[k,l] = sum_d W[k,d]*xc[d,l], k<96.
// K-split over d (8 chunks of 256) -> partials p[c][k][l]; reduced later.
// grid (16 l-tiles, 8 d-chunks, 2 branches), 256 thr, micro 6k x 8l.
// =====================================================================
__global__ __launch_bounds__(256) void xproj_kernel(const float* __restrict__ xc,
                                                    const float* __restrict__ w1,
                                                    const float* __restrict__ w2,
                                                    float* __restrict__ p1,
                                                    float* __restrict__ p2) {
  __shared__ __align__(16) float Xs[32][128];
  __shared__ float Wst[32][97];
  const int tid = threadIdx.x;
  const int l0 = blockIdx.x * 128;
  const int c = blockIdx.y;
  const float* __restrict__ W = blockIdx.z ? w2 : w1;
  float* __restrict__ outp = blockIdx.z ? p2 : p1;
  const int tk = tid >> 4, tl = tid & 15;
  float acc[6][8];
#pragma unroll
  for (int i = 0; i < 6; ++i)
#pragma unroll
    for (int j = 0; j < 8; ++j) acc[i][j] = 0.f;

  for (int s = 0; s < 8; ++s) {
    const int dbase = c * 256 + s * 32;
    __syncthreads();
    for (int i = tid; i < 32 * 128; i += 256) {
      int ddi = i >> 7, ll = i & 127;
      Xs[ddi][ll] = xc[(size_t)(dbase + ddi) * SEQ + l0 + ll];
    }
    for (int i = tid; i < 96 * 32; i += 256) {
      int r = i >> 5, ddi = i & 31;
      Wst[ddi][r] = W[(size_t)r * DIN + dbase + ddi];
    }
    __syncthreads();
    for (int ddi = 0; ddi < 32; ++ddi) {
      float4 xa = *(const float4*)&Xs[ddi][tl * 8];
      float4 xb = *(const float4*)&Xs[ddi][tl * 8 + 4];
      float xv[8] = {xa.x, xa.y, xa.z, xa.w, xb.x, xb.y, xb.z, xb.w};
#pragma unroll
      for (int i = 0; i < 6; ++i) {
        float wv = Wst[ddi][tk * 6 + i];
#pragma unroll
        for (int j = 0; j < 8; ++j) acc[i][j] = fmaf(wv, xv[j], acc[i][j]);
      }
    }
  }
#pragma unroll
  for (int i = 0; i < 6; ++i) {
    int k = tk * 6 + i;
    size_t base = ((size_t)c * 96 + k) * SEQ + l0 + tl * 8;
    *(float4*)&outp[base]     = make_float4(acc[i][0], acc[i][1], acc[i][2], acc[i][3]);
    *(float4*)&outp[base + 4] = make_float4(acc[i][4], acc[i][5], acc[i][6], acc[i][7]);
  }
}

// Sum the 8 K-split partials -> dbl1, dbl2.
__global__ __launch_bounds__(256) void reduce_dbl_kernel(const float* __restrict__ p1,
                                                         const float* __restrict__ p2,
                                                         float* __restrict__ o1,
                                                         float* __restrict__ o2) {
  const int NE = 96 * SEQ;
  int idx = blockIdx.x * 256 + threadIdx.x;
  const float* p = p1; float* o = o1; int j = idx;
  if (idx >= NE) { p = p2; o = o2; j = idx - NE; }
  float s = 0.f;
#pragma unroll
  for (int cc = 0; cc < 8; ++cc) s += p[(size_t)cc * NE + j];
  o[j] = s;
}

// =====================================================================
// dt GEMM: dt[d,l] = sum_r dtw[d,r]*dbl[r,l], r<64.
// grid (32 l-tiles, 32 d-tiles, 2 branches), 64x64 tile, 4x4 micro.
// =====================================================================
__global__ __launch_bounds__(256) void dt_gemm_kernel(const float* __restrict__ dbl1,
                                                      const float* __restrict__ dbl2,
                                                      const float* __restrict__ w1,
                                                      const float* __restrict__ w2,
                                                      float* __restrict__ o1,
                                                      float* __restrict__ o2) {
  const int br = blockIdx.z;
  const float* __restrict__ dbl = br ? dbl2 : dbl1;
  const float* __restrict__ W = br ? w2 : w1;
  float* __restrict__ outp = br ? o2 : o1;
  const int l0 = blockIdx.x * 64, d0 = blockIdx.y * 64;
  __shared__ __align__(16) float Wt[64][68];  // [r][dd]
  __shared__ __align__(16) float Bs[64][68];  // [r][ll]
  const int tid = threadIdx.x;
  for (int i = tid; i < 4096; i += 256) {
    int a = i >> 6, b = i & 63;
    Wt[b][a] = W[(size_t)(d0 + a) * DTR + b];
    Bs[a][b] = dbl[(size_t)a * SEQ + l0 + b];
  }
  __syncthreads();
  const int td = tid >> 4, tl = tid & 15;
  float acc[4][4];
#pragma unroll
  for (int i = 0; i < 4; ++i)
#pragma unroll
    for (int j = 0; j < 4; ++j) acc[i][j] = 0.f;
  for (int r = 0; r < 64; ++r) {
    float4 av = *(const float4*)&Wt[r][td * 4];
    float4 bv = *(const float4*)&Bs[r][tl * 4];
    float am[4] = {av.x, av.y, av.z, av.w};
    float bn[4] = {bv.x, bv.y, bv.z, bv.w};
#pragma unroll
    for (int i = 0; i < 4; ++i)
#pragma unroll
      for (int j = 0; j < 4; ++j) acc[i][j] = fmaf(am[i], bn[j], acc[i][j]);
  }
#pragma unroll
  for (int i = 0; i < 4; ++i) {
    *(float4*)&outp[(size_t)(d0 + td * 4 + i) * SEQ + l0 + tl * 4] =
        make_float4(acc[i][0], acc[i][1], acc[i][2], acc[i][3]);
  }
}

// =====================================================================
// Selective scan, one branch per block.z-half (grid 128 x 2), 256 thr:
// thread = (dd = tid>>4, nn = tid&15).  Chunked T=64 LDS staging.
// Writes y_br * silu(z) in (l, d) layout for the out_proj GEMM.
// =====================================================================
__global__ __launch_bounds__(256) void scan_kernel(const float* __restrict__ xc,
                                                   const float* __restrict__ xz,
                                                   const float* __restrict__ dt1,
                                                   const float* __restrict__ dt2,
                                                   const float* __restrict__ dbl1,
                                                   const float* __restrict__ dbl2,
                                                   const float* __restrict__ b1,
                                                   const float* __restrict__ b2,
                                                   const float* __restrict__ Al1,
                                                   const float* __restrict__ Al2,
                                                   const float* __restrict__ D1,
                                                   const float* __restrict__ D2,
                                                   float* __restrict__ y1t,
                                                   float* __restrict__ y2t) {
  const int br = blockIdx.y;
  const float* __restrict__ dt = br ? dt2 : dt1;
  const float* __restrict__ dbl = br ? dbl2 : dbl1;
  const float* __restrict__ dtb = br ? b2 : b1;
  const float* __restrict__ Al = br ? Al2 : Al1;
  const float* __restrict__ Dp = br ? D2 : D1;
  float* __restrict__ yt = br ? y2t : y1t;

  const int d0 = blockIdx.x * 16;
  const int tid = threadIdx.x;
  const int dd = tid >> 4, nn = tid & 15;
  const int d = d0 + dd;

  // A = -exp(A_log); pre-scale by log2(e) so dA = exp2(sp * An)
  const float An = -__expf(Al[(size_t)d * NST + nn]) * 1.4426950408889634f;
  const float Dd = Dp[d];
  float h = 0.f;

  __shared__ float2 pq_s[16][65];  // (softplus(dt+bias), sp*u)
  __shared__ float2 bc_s[16][65];  // (B[n,t], C[n,t])
  __shared__ float u_s[16][65];
  __shared__ float sz_s[16][65];   // silu(z)
  __shared__ float y_s[16][65];

  for (int c = 0; c < SEQ / 64; ++c) {
    const int t0 = c * 64;
    __syncthreads();
    for (int i = tid; i < 1024; i += 256) {
      int di = i >> 6, ti = i & 63;
      size_t g = (size_t)(d0 + di) * SEQ + t0 + ti;
      float u = xc[g];
      float z = xz[(size_t)(DIN + d0 + di) * SEQ + t0 + ti];
      float dv = dt[g] + dtb[d0 + di];
      float sp = dv > 20.f ? dv : log1pf(__expf(dv));
      pq_s[di][ti] = make_float2(sp, sp * u);
      u_s[di][ti] = u;
      sz_s[di][ti] = z / (1.f + __expf(-z));
      bc_s[di][ti] = make_float2(dbl[(size_t)(DTR + di) * SEQ + t0 + ti],
                                 dbl[(size_t)(DTR + NST + di) * SEQ + t0 + ti]);
    }
    __syncthreads();
#pragma unroll 8
    for (int t = 0; t < 64; ++t) {
      float2 pq = pq_s[dd][t];
      float2 bc = bc_s[nn][t];
      float dA = exp2f(pq.x * An);
      h = fmaf(dA, h, pq.y * bc.x);
      float v = h * bc.y;
      v += __shfl_xor(v, 8, 16);
      v += __shfl_xor(v, 4, 16);
      v += __shfl_xor(v, 2, 16);
      v += __shfl_xor(v, 1, 16);
      if (nn == 0) y_s[dd][t] = v + Dd * u_s[dd][t];
    }
    __syncthreads();
    for (int i = tid; i < 1024; i += 256) {
      int ti = i >> 4, di = i & 15;
      yt[(size_t)(t0 + ti) * DIN + d0 + di] = y_s[di][ti] * sz_s[di][ti];
    }
  }
}

// =====================================================================
extern "C" void kernel_launch(void* const* d_in, const int* in_sizes, int n_in,
                              void* d_out, int out_size, void* d_ws, size_t ws_size,
                              hipStream_t stream) {
  const float* hidden = (const float*)d_in[0];
  const float* in_proj_w = (const float*)d_in[1];
  const float* conv_w = (const float*)d_in[2];
  const float* conv_b = (const float*)d_in[3];
  const float* x1w = (const float*)d_in[4];
  const float* dtw1 = (const float*)d_in[5];
  const float* dtb1 = (const float*)d_in[6];
  const float* Al1 = (const float*)d_in[7];
  const float* D1 = (const float*)d_in[8];
  const float* x2w = (const float*)d_in[9];
  const float* dtw2 = (const float*)d_in[10];
  const float* dtb2 = (const float*)d_in[11];
  const float* Al2 = (const float*)d_in[12];
  const float* D2 = (const float*)d_in[13];
  const float* outw = (const float*)d_in[14];
  float* out = (float*)d_out;

  // Workspace layout (floats). Total 29,753,344 f = 119 MB.
  float* ws = (float*)d_ws;
  float* xz = ws;                                  // 4096*2048  (x rows 0..2047, z rows 2048..4095)
  float* xc = xz + (size_t)4096 * SEQ;             // 2048*2048  conv+silu output
  float* dbl1 = xc + (size_t)DIN * SEQ;            // 96*2048
  float* dbl2 = dbl1 + (size_t)96 * SEQ;           // 96*2048
  float* dt1 = dbl2 + (size_t)96 * SEQ;            // 2048*2048
  float* dt2 = dt1 + (size_t)DIN * SEQ;            // 2048*2048
  float* y1t = dt2 + (size_t)DIN * SEQ;            // 2048*2048  (l, d) layout
  float* y2t = y1t + (size_t)SEQ * DIN;            // 2048*2048
  // x_proj partials alias dt1/dt2 (consumed by reduce before dt_gemm writes dt)
  float* p1 = dt1;                                 // 8*96*2048
  float* p2 = dt2;

  dim3 blk(256);

  // 1) in_proj: xz[e,l] = sum_d W[e,d]*hidden[l,d]
  gemm_nt<false><<<dim3(SEQ / 64, 4096 / 128), blk, 0, stream>>>(
      in_proj_w, nullptr, hidden, xz, 4096, SEQ, DMODEL);

  // 2) causal conv + silu
  conv_silu_kernel<<<dim3(SEQ / 256, DIN), blk, 0, stream>>>(xz, conv_w, conv_b, xc);

  // 3) x_proj partials (both branches)
  xproj_kernel<<<dim3(SEQ / 128, 8, 2), blk, 0, stream>>>(xc, x1w, x2w, p1, p2);

  // 4) reduce partials -> dbl1, dbl2
  reduce_dbl_kernel<<<dim3(2 * 96 * SEQ / 256), blk, 0, stream>>>(p1, p2, dbl1, dbl2);

  // 5) dt projection (overwrites partial space, which is now dead)
  dt_gemm_kernel<<<dim3(SEQ / 64, DIN / 64, 2), blk, 0, stream>>>(
      dbl1, dbl2, dtw1, dtw2, dt1, dt2);

  // 6) selective scan, both branches
  scan_kernel<<<dim3(DIN / 16, 2), blk, 0, stream>>>(
      xc, xz, dt1, dt2, dbl1, dbl2, dtb1, dtb2, Al1, Al2, D1, D2, y1t, y2t);

  // 7) out_proj: out[l,o] = sum_d (y1-y2)[l,d] * Wout[o,d]
  gemm_nt<true><<<dim3(DMODEL / 64, SEQ / 128), blk, 0, stream>>>(
      y1t, y2t, outw, out, SEQ, DMODEL, DIN);
}

// Round 2
// 805.706 us; speedup vs baseline: 1.4524x; 1.4524x over previous
//
#include <hip/hip_runtime.h>
#include <math.h>

#define SEQ 2048
#define DMODEL 1024
#define DIN 2048
#define NST 16
#define DTR 64
#define CH 64
#define NCH (SEQ / CH)

// =====================================================================
// GEMM NT: C[m,n] = sum_k A[m,k]*B[n,k]
// A: M x K row-major (optionally A - A2), B: N x K row-major, C: M x N row-major
// =====================================================================
template<bool SUB>
__global__ __launch_bounds__(256) void gemm_nt(const float* __restrict__ A,
                                               const float* __restrict__ A2,
                                               const float* __restrict__ B,
                                               float* __restrict__ C,
                                               int M, int N, int K) {
  __shared__ __align__(16) float As[16][128];
  __shared__ __align__(16) float Bs[16][64];
  const int tid = threadIdx.x;
  const int m0 = blockIdx.y * 128;
  const int n0 = blockIdx.x * 64;
  const int ty = tid >> 4, tx = tid & 15;
  const int arow = tid >> 1, acol = (tid & 1) * 8;
  const int brow = tid >> 2, bcol = (tid & 3) * 4;
  float acc[8][4];
#pragma unroll
  for (int i = 0; i < 8; ++i)
#pragma unroll
    for (int j = 0; j < 4; ++j) acc[i][j] = 0.f;

  for (int k0 = 0; k0 < K; k0 += 16) {
    float4 av0 = *(const float4*)&A[(size_t)(m0 + arow) * K + k0 + acol];
    float4 av1 = *(const float4*)&A[(size_t)(m0 + arow) * K + k0 + acol + 4];
    if (SUB) {
      float4 s0 = *(const float4*)&A2[(size_t)(m0 + arow) * K + k0 + acol];
      float4 s1 = *(const float4*)&A2[(size_t)(m0 + arow) * K + k0 + acol + 4];
      av0.x -= s0.x; av0.y -= s0.y; av0.z -= s0.z; av0.w -= s0.w;
      av1.x -= s1.x; av1.y -= s1.y; av1.z -= s1.z; av1.w -= s1.w;
    }
    float4 bv = *(const float4*)&B[(size_t)(n0 + brow) * K + k0 + bcol];
    __syncthreads();
    As[acol + 0][arow] = av0.x; As[acol + 1][arow] = av0.y;
    As[acol + 2][arow] = av0.z; As[acol + 3][arow] = av0.w;
    As[acol + 4][arow] = av1.x; As[acol + 5][arow] = av1.y;
    As[acol + 6][arow] = av1.z; As[acol + 7][arow] = av1.w;
    Bs[bcol + 0][brow] = bv.x; Bs[bcol + 1][brow] = bv.y;
    Bs[bcol + 2][brow] = bv.z; Bs[bcol + 3][brow] = bv.w;
    __syncthreads();
#pragma unroll
    for (int kk = 0; kk < 16; ++kk) {
      float4 a0 = *(const float4*)&As[kk][ty * 4];
      float4 a1 = *(const float4*)&As[kk][64 + ty * 4];
      float4 b  = *(const float4*)&Bs[kk][tx * 4];
      float am[8] = {a0.x, a0.y, a0.z, a0.w, a1.x, a1.y, a1.z, a1.w};
      float bn[4] = {b.x, b.y, b.z, b.w};
#pragma unroll
      for (int i = 0; i < 8; ++i)
#pragma unroll
        for (int j = 0; j < 4; ++j)
          acc[i][j] = fmaf(am[i], bn[j], acc[i][j]);
    }
  }
#pragma unroll
  for (int i = 0; i < 4; ++i) {
    float4 w0 = make_float4(acc[i][0], acc[i][1], acc[i][2], acc[i][3]);
    float4 w1 = make_float4(acc[i + 4][0], acc[i + 4][1], acc[i + 4][2], acc[i + 4][3]);
    *(float4*)&C[(size_t)(m0 + ty * 4 + i) * N + n0 + tx * 4] = w0;
    *(float4*)&C[(size_t)(m0 + 64 + ty * 4 + i) * N + n0 + tx * 4] = w1;
  }
}

// =====================================================================
// Depthwise causal conv (w=4) + bias + SiLU.
// =====================================================================
__global__ __launch_bounds__(256) void conv_silu_kernel(const float* __restrict__ xz,
                                                        const float* __restrict__ cw,
                                                        const float* __restrict__ cb,
                                                        float* __restrict__ xc) {
  const int d = blockIdx.y;
  const int l = blockIdx.x * 256 + threadIdx.x;
  const float* xrow = xz + (size_t)d * SEQ;
  const float w0 = cw[d * 4 + 0], w1 = cw[d * 4 + 1], w2 = cw[d * 4 + 2], w3 = cw[d * 4 + 3];
  float a = cb[d] + w3 * xrow[l];
  if (l >= 1) a += w2 * xrow[l - 1];
  if (l >= 2) a += w1 * xrow[l - 2];
  if (l >= 3) a += w0 * xrow[l - 3];
  xc[(size_t)d * SEQ + l] = a / (1.f + __expf(-a));
}

// =====================================================================
// x_proj (both branches), K-split over d -> partials.
// =====================================================================
__global__ __launch_bounds__(256) void xproj_kernel(const float* __restrict__ xc,
                                                    const float* __restrict__ w1,
                                                    const float* __restrict__ w2,
                                                    float* __restrict__ p1,
                                                    float* __restrict__ p2) {
  __shared__ __align__(16) float Xs[32][128];
  __shared__ float Wst[32][97];
  const int tid = threadIdx.x;
  const int l0 = blockIdx.x * 128;
  const int c = blockIdx.y;
  const float* __restrict__ W = blockIdx.z ? w2 : w1;
  float* __restrict__ outp = blockIdx.z ? p2 : p1;
  const int tk = tid >> 4, tl = tid & 15;
  float acc[6][8];
#pragma unroll
  for (int i = 0; i < 6; ++i)
#pragma unroll
    for (int j = 0; j < 8; ++j) acc[i][j] = 0.f;

  for (int s = 0; s < 8; ++s) {
    const int dbase = c * 256 + s * 32;
    __syncthreads();
    for (int i = tid; i < 32 * 128; i += 256) {
      int ddi = i >> 7, ll = i & 127;
      Xs[ddi][ll] = xc[(size_t)(dbase + ddi) * SEQ + l0 + ll];
    }
    for (int i = tid; i < 96 * 32; i += 256) {
      int r = i >> 5, ddi = i & 31;
      Wst[ddi][r] = W[(size_t)r * DIN + dbase + ddi];
    }
    __syncthreads();
    for (int ddi = 0; ddi < 32; ++ddi) {
      float4 xa = *(const float4*)&Xs[ddi][tl * 8];
      float4 xb = *(const float4*)&Xs[ddi][tl * 8 + 4];
      float xv[8] = {xa.x, xa.y, xa.z, xa.w, xb.x, xb.y, xb.z, xb.w};
#pragma unroll
      for (int i = 0; i < 6; ++i) {
        float wv = Wst[ddi][tk * 6 + i];
#pragma unroll
        for (int j = 0; j < 8; ++j) acc[i][j] = fmaf(wv, xv[j], acc[i][j]);
      }
    }
  }
#pragma unroll
  for (int i = 0; i < 6; ++i) {
    int k = tk * 6 + i;
    size_t base = ((size_t)c * 96 + k) * SEQ + l0 + tl * 8;
    *(float4*)&outp[base]     = make_float4(acc[i][0], acc[i][1], acc[i][2], acc[i][3]);
    *(float4*)&outp[base + 4] = make_float4(acc[i][4], acc[i][5], acc[i][6], acc[i][7]);
  }
}

__global__ __launch_bounds__(256) void reduce_dbl_kernel(const float* __restrict__ p1,
                                                         const float* __restrict__ p2,
                                                         float* __restrict__ o1,
                                                         float* __restrict__ o2) {
  const int NE = 96 * SEQ;
  int idx = blockIdx.x * 256 + threadIdx.x;
  const float* p = p1; float* o = o1; int j = idx;
  if (idx >= NE) { p = p2; o = o2; j = idx - NE; }
  float s = 0.f;
#pragma unroll
  for (int cc = 0; cc < 8; ++cc) s += p[(size_t)cc * NE + j];
  o[j] = s;
}

// =====================================================================
// dt GEMM, TRANSPOSED output: dtt[l,d] = sum_r dtw[d,r]*dbl[r,l].
// =====================================================================
__global__ __launch_bounds__(256) void dt_gemm_kernel(const float* __restrict__ dbl1,
                                                      const float* __restrict__ dbl2,
                                                      const float* __restrict__ w1,
                                                      const float* __restrict__ w2,
                                                      float* __restrict__ o1,
                                                      float* __restrict__ o2) {
  const int br = blockIdx.z;
  const float* __restrict__ dbl = br ? dbl2 : dbl1;
  const float* __restrict__ W = br ? w2 : w1;
  float* __restrict__ outp = br ? o2 : o1;
  const int l0 = blockIdx.x * 64, d0 = blockIdx.y * 64;
  __shared__ __align__(16) float Wt[64][68];  // [r][dd]
  __shared__ __align__(16) float Bs[64][68];  // [r][ll]
  const int tid = threadIdx.x;
  for (int i = tid; i < 4096; i += 256) {
    int a = i >> 6, b = i & 63;
    Wt[b][a] = W[(size_t)(d0 + a) * DTR + b];
    Bs[a][b] = dbl[(size_t)a * SEQ + l0 + b];
  }
  __syncthreads();
  const int tl_ = tid >> 4, td_ = tid & 15;  // tl_: l group, td_: d group (d fastest -> coalesced store)
  float acc[4][4];
#pragma unroll
  for (int i = 0; i < 4; ++i)
#pragma unroll
    for (int j = 0; j < 4; ++j) acc[i][j] = 0.f;
  for (int r = 0; r < 64; ++r) {
    float4 av = *(const float4*)&Bs[r][tl_ * 4];
    float4 bv = *(const float4*)&Wt[r][td_ * 4];
    float am[4] = {av.x, av.y, av.z, av.w};
    float bn[4] = {bv.x, bv.y, bv.z, bv.w};
#pragma unroll
    for (int i = 0; i < 4; ++i)
#pragma unroll
      for (int j = 0; j < 4; ++j) acc[i][j] = fmaf(am[i], bn[j], acc[i][j]);
  }
#pragma unroll
  for (int i = 0; i < 4; ++i) {
    *(float4*)&outp[(size_t)(l0 + tl_ * 4 + i) * DIN + d0 + td_ * 4] =
        make_float4(acc[i][0], acc[i][1], acc[i][2], acc[i][3]);
  }
}

// =====================================================================
// Chunked selective scan.
// Phase A: per (chunk, d): local scan h0=0 over CH steps, all 16 n-states
// in registers; emit h_end, P_end = prod(dA).
// =====================================================================
__global__ __launch_bounds__(256) void scan_phase_a(const float* __restrict__ xc,
                                                    const float* __restrict__ dtt1,
                                                    const float* __restrict__ dtt2,
                                                    const float* __restrict__ dbl1,
                                                    const float* __restrict__ dbl2,
                                                    const float* __restrict__ b1,
                                                    const float* __restrict__ b2,
                                                    const float* __restrict__ Al1,
                                                    const float* __restrict__ Al2,
                                                    float* __restrict__ hend,
                                                    float* __restrict__ Pend) {
  const int br = blockIdx.z;
  const float* __restrict__ dtt = br ? dtt2 : dtt1;
  const float* __restrict__ dbl = br ? dbl2 : dbl1;
  const float* __restrict__ dtb = br ? b2 : b1;
  const float* __restrict__ Al = br ? Al2 : Al1;
  const int c = blockIdx.y;
  const int t0 = c * CH;
  const int d = blockIdx.x * 256 + threadIdx.x;

  __shared__ __align__(16) float Bs[CH][NST];
  for (int i = threadIdx.x; i < CH * NST; i += 256) {
    int n = i >> 6, t = i & 63;
    Bs[t][n] = dbl[(size_t)(DTR + n) * SEQ + t0 + t];
  }
  __syncthreads();

  const float bias = dtb[d];
  float An[NST], h[NST], P[NST];
#pragma unroll
  for (int n = 0; n < NST; ++n) {
    An[n] = -__expf(Al[(size_t)d * NST + n]) * 1.4426950408889634f;
    h[n] = 0.f;
    P[n] = 1.f;
  }
  for (int tt = 0; tt < CH / 4; ++tt) {
    float4 u4 = *(const float4*)&xc[(size_t)d * SEQ + t0 + tt * 4];
    float uarr[4] = {u4.x, u4.y, u4.z, u4.w};
#pragma unroll
    for (int j = 0; j < 4; ++j) {
      const int t = tt * 4 + j;
      float dv = dtt[(size_t)(t0 + t) * DIN + d] + bias;
      float sp = dv > 20.f ? dv : log1pf(__expf(dv));
      float spu = sp * uarr[j];
#pragma unroll
      for (int ng = 0; ng < 4; ++ng) {
        float4 bq = *(const float4*)&Bs[t][ng * 4];
        float bf[4] = {bq.x, bq.y, bq.z, bq.w};
#pragma unroll
        for (int k = 0; k < 4; ++k) {
          int n = ng * 4 + k;
          float dA = exp2f(An[n] * sp);
          P[n] *= dA;
          h[n] = fmaf(dA, h[n], spu * bf[k]);
        }
      }
    }
  }
  size_t base = ((size_t)(br * NCH + c) * DIN + d) * NST;
#pragma unroll
  for (int n = 0; n < NST; n += 4) {
    *(float4*)&hend[base + n] = make_float4(h[n], h[n + 1], h[n + 2], h[n + 3]);
    *(float4*)&Pend[base + n] = make_float4(P[n], P[n + 1], P[n + 2], P[n + 3]);
  }
}

// Phase B: carry recurrence across the 32 chunks, per (br,d,n).
__global__ __launch_bounds__(256) void scan_carry(const float* __restrict__ hend,
                                                  const float* __restrict__ Pend,
                                                  float* __restrict__ hin) {
  const int flat = blockIdx.x * 256 + threadIdx.x;  // [br][d*16+n], 2*32768
  const int br = flat >> 15;
  const int dn = flat & 32767;
  float h = 0.f;
  for (int c = 0; c < NCH; ++c) {
    size_t idx = ((size_t)(br * NCH + c) << 15) + dn;
    hin[idx] = h;
    h = fmaf(Pend[idx], h, hend[idx]);
  }
}

// Phase C: full scan per chunk seeded with hin; y = (C.h + D*u)*silu(z),
// written to (l,d) layout for out_proj.
__global__ __launch_bounds__(256) void scan_phase_c(const float* __restrict__ xc,
                                                    const float* __restrict__ xz,
                                                    const float* __restrict__ dtt1,
                                                    const float* __restrict__ dtt2,
                                                    const float* __restrict__ dbl1,
                                                    const float* __restrict__ dbl2,
                                                    const float* __restrict__ b1,
                                                    const float* __restrict__ b2,
                                                    const float* __restrict__ Al1,
                                                    const float* __restrict__ Al2,
                                                    const float* __restrict__ D1,
                                                    const float* __restrict__ D2,
                                                    const float* __restrict__ hin,
                                                    float* __restrict__ y1t,
                                                    float* __restrict__ y2t) {
  const int br = blockIdx.z;
  const float* __restrict__ dtt = br ? dtt2 : dtt1;
  const float* __restrict__ dbl = br ? dbl2 : dbl1;
  const float* __restrict__ dtb = br ? b2 : b1;
  const float* __restrict__ Al = br ? Al2 : Al1;
  const float* __restrict__ Dp = br ? D2 : D1;
  float* __restrict__ yt = br ? y2t : y1t;
  const int c = blockIdx.y;
  const int t0 = c * CH;
  const int d = blockIdx.x * 256 + threadIdx.x;

  __shared__ __align__(16) float bc_s[CH][2 * NST];  // [t][2n]=B, [t][2n+1]=C
  for (int i = threadIdx.x; i < CH * NST; i += 256) {
    int n = i >> 6, t = i & 63;
    bc_s[t][2 * n]     = dbl[(size_t)(DTR + n) * SEQ + t0 + t];
    bc_s[t][2 * n + 1] = dbl[(size_t)(DTR + NST + n) * SEQ + t0 + t];
  }
  __syncthreads();

  const float bias = dtb[d];
  const float Dd = Dp[d];
  float An[NST], h[NST];
#pragma unroll
  for (int n = 0; n < NST; ++n)
    An[n] = -__expf(Al[(size_t)d * NST + n]) * 1.4426950408889634f;
  const size_t hbase = ((size_t)(br * NCH + c) * DIN + d) * NST;
#pragma unroll
  for (int n = 0; n < NST; n += 4) {
    float4 hv = *(const float4*)&hin[hbase + n];
    h[n] = hv.x; h[n + 1] = hv.y; h[n + 2] = hv.z; h[n + 3] = hv.w;
  }

  for (int tt = 0; tt < CH / 4; ++tt) {
    float4 u4 = *(const float4*)&xc[(size_t)d * SEQ + t0 + tt * 4];
    float4 z4 = *(const float4*)&xz[(size_t)(DIN + d) * SEQ + t0 + tt * 4];
    float uarr[4] = {u4.x, u4.y, u4.z, u4.w};
    float zarr[4] = {z4.x, z4.y, z4.z, z4.w};
#pragma unroll
    for (int j = 0; j < 4; ++j) {
      const int t = tt * 4 + j;
      float dv = dtt[(size_t)(t0 + t) * DIN + d] + bias;
      float sp = dv > 20.f ? dv : log1pf(__expf(dv));
      float spu = sp * uarr[j];
      float y = 0.f;
#pragma unroll
      for (int ng = 0; ng < 4; ++ng) {
        float4 v0 = *(const float4*)&bc_s[t][ng * 8];
        float4 v1 = *(const float4*)&bc_s[t][ng * 8 + 4];
        float bf[4] = {v0.x, v0.z, v1.x, v1.z};
        float cf[4] = {v0.y, v0.w, v1.y, v1.w};
#pragma unroll
        for (int k = 0; k < 4; ++k) {
          int n = ng * 4 + k;
          float dA = exp2f(An[n] * sp);
          h[n] = fmaf(dA, h[n], spu * bf[k]);
          y = fmaf(h[n], cf[k], y);
        }
      }
      float zz = zarr[j];
      float sz = zz / (1.f + __expf(-zz));
      yt[(size_t)(t0 + t) * DIN + d] = (y + Dd * uarr[j]) * sz;
    }
  }
}

// =====================================================================
extern "C" void kernel_launch(void* const* d_in, const int* in_sizes, int n_in,
                              void* d_out, int out_size, void* d_ws, size_t ws_size,
                              hipStream_t stream) {
  const float* hidden = (const float*)d_in[0];
  const float* in_proj_w = (const float*)d_in[1];
  const float* conv_w = (const float*)d_in[2];
  const float* conv_b = (const float*)d_in[3];
  const float* x1w = (const float*)d_in[4];
  const float* dtw1 = (const float*)d_in[5];
  const float* dtb1 = (const float*)d_in[6];
  const float* Al1 = (const float*)d_in[7];
  const float* D1 = (const float*)d_in[8];
  const float* x2w = (const float*)d_in[9];
  const float* dtw2 = (const float*)d_in[10];
  const float* dtb2 = (const float*)d_in[11];
  const float* Al2 = (const float*)d_in[12];
  const float* D2 = (const float*)d_in[13];
  const float* outw = (const float*)d_in[14];
  float* out = (float*)d_out;

  // Workspace layout (floats). Total ~36.0M floats = 144 MB.
  float* ws = (float*)d_ws;
  float* xz = ws;                                  // 4096*2048
  float* xc = xz + (size_t)4096 * SEQ;             // 2048*2048
  float* dbl1 = xc + (size_t)DIN * SEQ;            // 96*2048
  float* dbl2 = dbl1 + (size_t)96 * SEQ;           // 96*2048
  float* dtt1 = dbl2 + (size_t)96 * SEQ;           // 2048*2048 (l,d) layout
  float* dtt2 = dtt1 + (size_t)SEQ * DIN;          // 2048*2048 (l,d)
  float* y1t = dtt2 + (size_t)SEQ * DIN;           // 2048*2048 (l,d)
  float* y2t = y1t + (size_t)SEQ * DIN;            // 2048*2048 (l,d)
  float* hend = y2t + (size_t)SEQ * DIN;           // 2*32*2048*16
  float* Pend = hend + (size_t)2 * NCH * DIN * NST;
  float* hin = Pend + (size_t)2 * NCH * DIN * NST;
  // x_proj partials alias dtt1/dtt2 (consumed by reduce before dt_gemm writes)
  float* p1 = dtt1;
  float* p2 = dtt2;

  dim3 blk(256);

  // 1) in_proj
  gemm_nt<false><<<dim3(SEQ / 64, 4096 / 128), blk, 0, stream>>>(
      in_proj_w, nullptr, hidden, xz, 4096, SEQ, DMODEL);

  // 2) causal conv + silu
  conv_silu_kernel<<<dim3(SEQ / 256, DIN), blk, 0, stream>>>(xz, conv_w, conv_b, xc);

  // 3) x_proj partials
  xproj_kernel<<<dim3(SEQ / 128, 8, 2), blk, 0, stream>>>(xc, x1w, x2w, p1, p2);

  // 4) reduce partials
  reduce_dbl_kernel<<<dim3(2 * 96 * SEQ / 256), blk, 0, stream>>>(p1, p2, dbl1, dbl2);

  // 5) dt projection -> transposed (l,d)
  dt_gemm_kernel<<<dim3(SEQ / 64, DIN / 64, 2), blk, 0, stream>>>(
      dbl1, dbl2, dtw1, dtw2, dtt1, dtt2);

  // 6) chunked selective scan
  scan_phase_a<<<dim3(DIN / 256, NCH, 2), blk, 0, stream>>>(
      xc, dtt1, dtt2, dbl1, dbl2, dtb1, dtb2, Al1, Al2, hend, Pend);
  scan_carry<<<dim3(2 * DIN * NST / 256), blk, 0, stream>>>(hend, Pend, hin);
  scan_phase_c<<<dim3(DIN / 256, NCH, 2), blk, 0, stream>>>(
      xc, xz, dtt1, dtt2, dbl1, dbl2, dtb1, dtb2, Al1, Al2, D1, D2, hin, y1t, y2t);

  // 7) out_proj
  gemm_nt<true><<<dim3(DMODEL / 64, SEQ / 128), blk, 0, stream>>>(
      y1t, y2t, outw, out, SEQ, DMODEL, DIN);
}

// Round 3
// 498.574 us; speedup vs baseline: 2.3472x; 1.6160x over previous
//
#include <hip/hip_runtime.h>
#include <math.h>

#define SEQ 2048
#define DMODEL 1024
#define DIN 2048
#define NST 16
#define DTR 64
#define CH 64
#define NCH (SEQ / CH)

typedef __attribute__((ext_vector_type(8))) short bf16x8;
typedef __attribute__((ext_vector_type(4))) float f32x4;

__device__ __forceinline__ ushort f2bf(float f) {
  union { float f; unsigned u; } c; c.f = f;
  return (ushort)((c.u + 0x7fffu + ((c.u >> 16) & 1u)) >> 16);
}
__device__ __forceinline__ float bf2f(ushort h) {
  union { unsigned u; float f; } c; c.u = ((unsigned)h) << 16;
  return c.f;
}

#define GLL(g, l) __builtin_amdgcn_global_load_lds( \
    (const __attribute__((address_space(1))) void*)(g), \
    (__attribute__((address_space(3))) void*)(l), 16, 0, 0)

// =====================================================================
// Split-bf16 3-pass MFMA GEMM (fp32-accurate).
// C[m,n] = sum_k A[m,k]*B[n,k]; A,B given as bf16 hi/lo planes, K-contig.
// BMxBN tile, BK=32, 256 thr = 4 waves (2x2), wave tile (BM/2)x(BN/2).
// SPLITK>1: each z-block does K/SPLITK, writes partial slab z.
// =====================================================================
template<int BM, int BN, int SPLITK>
__global__ __launch_bounds__(256) void gemm3p(const ushort* __restrict__ Ahi,
                                              const ushort* __restrict__ Alo,
                                              const ushort* __restrict__ Bhi,
                                              const ushort* __restrict__ Blo,
                                              float* __restrict__ C,
                                              int M, int N, int K) {
  constexpr int BK = 32;
  constexpr int WM = BM / 2, WN = BN / 2, TM = WM / 16, TN = WN / 16;
  constexpr int SA = BM / 16, SB = BN / 16;  // 16-row LDS segments per plane
  __shared__ __align__(16) ushort sAh[BM * BK], sAl[BM * BK];
  __shared__ __align__(16) ushort sBh[BN * BK], sBl[BN * BK];
  const int tid = threadIdx.x, wid = tid >> 6, lane = tid & 63;
  const int m0 = blockIdx.y * BM, n0 = blockIdx.x * BN;
  const int Kc = K / SPLITK, kbeg = blockIdx.z * Kc;
  const int wm0 = (wid >> 1) * WM, wn0 = (wid & 1) * WN;
  const int fr = lane & 15, fk = (lane >> 4) * 8;
  const int lrow = lane >> 2, lk = (lane & 3) * 8;

  f32x4 acc[TM][TN];
#pragma unroll
  for (int mi = 0; mi < TM; ++mi)
#pragma unroll
    for (int ni = 0; ni < TN; ++ni)
#pragma unroll
      for (int r = 0; r < 4; ++r) acc[mi][ni][r] = 0.f;

  for (int k0 = 0; k0 < Kc; k0 += BK) {
    __syncthreads();
    const int kg = kbeg + k0 + lk;
#pragma unroll
    for (int i = 0; i < SA / 4; ++i) {
      const int seg = wid * (SA / 4) + i;
      const size_t ga = (size_t)(m0 + seg * 16 + lrow) * K + kg;
      GLL(&Ahi[ga], &sAh[seg * 512]);
      GLL(&Alo[ga], &sAl[seg * 512]);
    }
#pragma unroll
    for (int i = 0; i < SB / 4; ++i) {
      const int seg = wid * (SB / 4) + i;
      const size_t ga = (size_t)(n0 + seg * 16 + lrow) * K + kg;
      GLL(&Bhi[ga], &sBh[seg * 512]);
      GLL(&Blo[ga], &sBl[seg * 512]);
    }
    __syncthreads();  // compiler emits vmcnt(0) drain before barrier

    bf16x8 ah[TM], al[TM], bh[TN], bl[TN];
#pragma unroll
    for (int mi = 0; mi < TM; ++mi) {
      const int r = (wm0 + mi * 16 + fr) * 32 + fk;
      ah[mi] = *(const bf16x8*)&sAh[r];
      al[mi] = *(const bf16x8*)&sAl[r];
    }
#pragma unroll
    for (int ni = 0; ni < TN; ++ni) {
      const int r = (wn0 + ni * 16 + fr) * 32 + fk;
      bh[ni] = *(const bf16x8*)&sBh[r];
      bl[ni] = *(const bf16x8*)&sBl[r];
    }
#pragma unroll
    for (int mi = 0; mi < TM; ++mi)
#pragma unroll
      for (int ni = 0; ni < TN; ++ni) {
        acc[mi][ni] = __builtin_amdgcn_mfma_f32_16x16x32_bf16(ah[mi], bh[ni], acc[mi][ni], 0, 0, 0);
        acc[mi][ni] = __builtin_amdgcn_mfma_f32_16x16x32_bf16(ah[mi], bl[ni], acc[mi][ni], 0, 0, 0);
        acc[mi][ni] = __builtin_amdgcn_mfma_f32_16x16x32_bf16(al[mi], bh[ni], acc[mi][ni], 0, 0, 0);
      }
  }

  float* __restrict__ Co = C + (size_t)blockIdx.z * M * N;
#pragma unroll
  for (int mi = 0; mi < TM; ++mi)
#pragma unroll
    for (int ni = 0; ni < TN; ++ni)
#pragma unroll
      for (int r = 0; r < 4; ++r)
        Co[(size_t)(m0 + wm0 + mi * 16 + (lane >> 4) * 4 + r) * N + n0 + wn0 + ni * 16 + fr] =
            acc[mi][ni][r];
}

// Split fp32 -> bf16 hi/lo planes.
__global__ __launch_bounds__(256) void cvt_split(const float* __restrict__ x,
                                                 ushort* __restrict__ hi,
                                                 ushort* __restrict__ lo, int n) {
  const int i = (blockIdx.x * 256 + threadIdx.x) * 4;
  if (i >= n) return;
  float4 v = *(const float4*)&x[i];
  ushort h0 = f2bf(v.x), h1 = f2bf(v.y), h2 = f2bf(v.z), h3 = f2bf(v.w);
  ushort l0 = f2bf(v.x - bf2f(h0)), l1 = f2bf(v.y - bf2f(h1));
  ushort l2 = f2bf(v.z - bf2f(h2)), l3 = f2bf(v.w - bf2f(h3));
  *(ushort4*)&hi[i] = make_ushort4(h0, h1, h2, h3);
  *(ushort4*)&lo[i] = make_ushort4(l0, l1, l2, l3);
}

// (y1 - y2) -> bf16 hi/lo planes.
__global__ __launch_bounds__(256) void cvt_ydiff(const float* __restrict__ y1,
                                                 const float* __restrict__ y2,
                                                 ushort* __restrict__ hi,
                                                 ushort* __restrict__ lo, int n) {
  const int i = (blockIdx.x * 256 + threadIdx.x) * 4;
  if (i >= n) return;
  float4 a = *(const float4*)&y1[i];
  float4 b = *(const float4*)&y2[i];
  float d0 = a.x - b.x, d1 = a.y - b.y, d2 = a.z - b.z, d3 = a.w - b.w;
  ushort h0 = f2bf(d0), h1 = f2bf(d1), h2 = f2bf(d2), h3 = f2bf(d3);
  ushort l0 = f2bf(d0 - bf2f(h0)), l1 = f2bf(d1 - bf2f(h1));
  ushort l2 = f2bf(d2 - bf2f(h2)), l3 = f2bf(d3 - bf2f(h3));
  *(ushort4*)&hi[i] = make_ushort4(h0, h1, h2, h3);
  *(ushort4*)&lo[i] = make_ushort4(l0, l1, l2, l3);
}

// Sum 4 split-K partial slabs.
__global__ __launch_bounds__(256) void reduce_out(const float* __restrict__ p,
                                                  float* __restrict__ o, int n) {
  const int i = (blockIdx.x * 256 + threadIdx.x) * 4;
  if (i >= n) return;
  float4 a = *(const float4*)&p[i];
  float4 b = *(const float4*)&p[(size_t)n + i];
  float4 c = *(const float4*)&p[(size_t)2 * n + i];
  float4 d = *(const float4*)&p[(size_t)3 * n + i];
  *(float4*)&o[i] = make_float4(a.x + b.x + c.x + d.x, a.y + b.y + c.y + d.y,
                                a.z + b.z + c.z + d.z, a.w + b.w + c.w + d.w);
}

// =====================================================================
// Depthwise causal conv (w=4) + bias + SiLU.
// =====================================================================
__global__ __launch_bounds__(256) void conv_silu_kernel(const float* __restrict__ xz,
                                                        const float* __restrict__ cw,
                                                        const float* __restrict__ cb,
                                                        float* __restrict__ xc) {
  const int d = blockIdx.y;
  const int l = blockIdx.x * 256 + threadIdx.x;
  const float* xrow = xz + (size_t)d * SEQ;
  const float w0 = cw[d * 4 + 0], w1 = cw[d * 4 + 1], w2 = cw[d * 4 + 2], w3 = cw[d * 4 + 3];
  float a = cb[d] + w3 * xrow[l];
  if (l >= 1) a += w2 * xrow[l - 1];
  if (l >= 2) a += w1 * xrow[l - 2];
  if (l >= 3) a += w0 * xrow[l - 3];
  xc[(size_t)d * SEQ + l] = a / (1.f + __expf(-a));
}

// =====================================================================
// x_proj (both branches), K-split over d -> partials.
// =====================================================================
__global__ __launch_bounds__(256) void xproj_kernel(const float* __restrict__ xc,
                                                    const float* __restrict__ w1,
                                                    const float* __restrict__ w2,
                                                    float* __restrict__ p1,
                                                    float* __restrict__ p2) {
  __shared__ __align__(16) float Xs[32][128];
  __shared__ float Wst[32][97];
  const int tid = threadIdx.x;
  const int l0 = blockIdx.x * 128;
  const int c = blockIdx.y;
  const float* __restrict__ W = blockIdx.z ? w2 : w1;
  float* __restrict__ outp = blockIdx.z ? p2 : p1;
  const int tk = tid >> 4, tl = tid & 15;
  float acc[6][8];
#pragma unroll
  for (int i = 0; i < 6; ++i)
#pragma unroll
    for (int j = 0; j < 8; ++j) acc[i][j] = 0.f;

  for (int s = 0; s < 8; ++s) {
    const int dbase = c * 256 + s * 32;
    __syncthreads();
    for (int i = tid; i < 32 * 128; i += 256) {
      int ddi = i >> 7, ll = i & 127;
      Xs[ddi][ll] = xc[(size_t)(dbase + ddi) * SEQ + l0 + ll];
    }
    for (int i = tid; i < 96 * 32; i += 256) {
      int r = i >> 5, ddi = i & 31;
      Wst[ddi][r] = W[(size_t)r * DIN + dbase + ddi];
    }
    __syncthreads();
    for (int ddi = 0; ddi < 32; ++ddi) {
      float4 xa = *(const float4*)&Xs[ddi][tl * 8];
      float4 xb = *(const float4*)&Xs[ddi][tl * 8 + 4];
      float xv[8] = {xa.x, xa.y, xa.z, xa.w, xb.x, xb.y, xb.z, xb.w};
#pragma unroll
      for (int i = 0; i < 6; ++i) {
        float wv = Wst[ddi][tk * 6 + i];
#pragma unroll
        for (int j = 0; j < 8; ++j) acc[i][j] = fmaf(wv, xv[j], acc[i][j]);
      }
    }
  }
#pragma unroll
  for (int i = 0; i < 6; ++i) {
    int k = tk * 6 + i;
    size_t base = ((size_t)c * 96 + k) * SEQ + l0 + tl * 8;
    *(float4*)&outp[base]     = make_float4(acc[i][0], acc[i][1], acc[i][2], acc[i][3]);
    *(float4*)&outp[base + 4] = make_float4(acc[i][4], acc[i][5], acc[i][6], acc[i][7]);
  }
}

__global__ __launch_bounds__(256) void reduce_dbl_kernel(const float* __restrict__ p1,
                                                         const float* __restrict__ p2,
                                                         float* __restrict__ o1,
                                                         float* __restrict__ o2) {
  const int NE = 96 * SEQ;
  int idx = blockIdx.x * 256 + threadIdx.x;
  const float* p = p1; float* o = o1; int j = idx;
  if (idx >= NE) { p = p2; o = o2; j = idx - NE; }
  float s = 0.f;
#pragma unroll
  for (int cc = 0; cc < 8; ++cc) s += p[(size_t)cc * NE + j];
  o[j] = s;
}

// =====================================================================
// dt GEMM, TRANSPOSED output: dtt[l,d] = sum_r dtw[d,r]*dbl[r,l].
// =====================================================================
__global__ __launch_bounds__(256) void dt_gemm_kernel(const float* __restrict__ dbl1,
                                                      const float* __restrict__ dbl2,
                                                      const float* __restrict__ w1,
                                                      const float* __restrict__ w2,
                                                      float* __restrict__ o1,
                                                      float* __restrict__ o2) {
  const int br = blockIdx.z;
  const float* __restrict__ dbl = br ? dbl2 : dbl1;
  const float* __restrict__ W = br ? w2 : w1;
  float* __restrict__ outp = br ? o2 : o1;
  const int l0 = blockIdx.x * 64, d0 = blockIdx.y * 64;
  __shared__ __align__(16) float Wt[64][68];
  __shared__ __align__(16) float Bs[64][68];
  const int tid = threadIdx.x;
  for (int i = tid; i < 4096; i += 256) {
    int a = i >> 6, b = i & 63;
    Wt[b][a] = W[(size_t)(d0 + a) * DTR + b];
    Bs[a][b] = dbl[(size_t)a * SEQ + l0 + b];
  }
  __syncthreads();
  const int tl_ = tid >> 4, td_ = tid & 15;
  float acc[4][4];
#pragma unroll
  for (int i = 0; i < 4; ++i)
#pragma unroll
    for (int j = 0; j < 4; ++j) acc[i][j] = 0.f;
  for (int r = 0; r < 64; ++r) {
    float4 av = *(const float4*)&Bs[r][tl_ * 4];
    float4 bv = *(const float4*)&Wt[r][td_ * 4];
    float am[4] = {av.x, av.y, av.z, av.w};
    float bn[4] = {bv.x, bv.y, bv.z, bv.w};
#pragma unroll
    for (int i = 0; i < 4; ++i)
#pragma unroll
      for (int j = 0; j < 4; ++j) acc[i][j] = fmaf(am[i], bn[j], acc[i][j]);
  }
#pragma unroll
  for (int i = 0; i < 4; ++i) {
    *(float4*)&outp[(size_t)(l0 + tl_ * 4 + i) * DIN + d0 + td_ * 4] =
        make_float4(acc[i][0], acc[i][1], acc[i][2], acc[i][3]);
  }
}

// =====================================================================
// Chunked selective scan (A: local scans, B: carry, C: final pass).
// =====================================================================
__global__ __launch_bounds__(256) void scan_phase_a(const float* __restrict__ xc,
                                                    const float* __restrict__ dtt1,
                                                    const float* __restrict__ dtt2,
                                                    const float* __restrict__ dbl1,
                                                    const float* __restrict__ dbl2,
                                                    const float* __restrict__ b1,
                                                    const float* __restrict__ b2,
                                                    const float* __restrict__ Al1,
                                                    const float* __restrict__ Al2,
                                                    float* __restrict__ hend,
                                                    float* __restrict__ Pend) {
  const int br = blockIdx.z;
  const float* __restrict__ dtt = br ? dtt2 : dtt1;
  const float* __restrict__ dbl = br ? dbl2 : dbl1;
  const float* __restrict__ dtb = br ? b2 : b1;
  const float* __restrict__ Al = br ? Al2 : Al1;
  const int c = blockIdx.y;
  const int t0 = c * CH;
  const int d = blockIdx.x * 256 + threadIdx.x;

  __shared__ __align__(16) float Bs[CH][NST];
  for (int i = threadIdx.x; i < CH * NST; i += 256) {
    int n = i >> 6, t = i & 63;
    Bs[t][n] = dbl[(size_t)(DTR + n) * SEQ + t0 + t];
  }
  __syncthreads();

  const float bias = dtb[d];
  float An[NST], h[NST], P[NST];
#pragma unroll
  for (int n = 0; n < NST; ++n) {
    An[n] = -__expf(Al[(size_t)d * NST + n]) * 1.4426950408889634f;
    h[n] = 0.f;
    P[n] = 1.f;
  }
  for (int tt = 0; tt < CH / 4; ++tt) {
    float4 u4 = *(const float4*)&xc[(size_t)d * SEQ + t0 + tt * 4];
    float uarr[4] = {u4.x, u4.y, u4.z, u4.w};
#pragma unroll
    for (int j = 0; j < 4; ++j) {
      const int t = tt * 4 + j;
      float dv = dtt[(size_t)(t0 + t) * DIN + d] + bias;
      float sp = dv > 20.f ? dv : log1pf(__expf(dv));
      float spu = sp * uarr[j];
#pragma unroll
      for (int ng = 0; ng < 4; ++ng) {
        float4 bq = *(const float4*)&Bs[t][ng * 4];
        float bf[4] = {bq.x, bq.y, bq.z, bq.w};
#pragma unroll
        for (int k = 0; k < 4; ++k) {
          int n = ng * 4 + k;
          float dA = exp2f(An[n] * sp);
          P[n] *= dA;
          h[n] = fmaf(dA, h[n], spu * bf[k]);
        }
      }
    }
  }
  size_t base = ((size_t)(br * NCH + c) * DIN + d) * NST;
#pragma unroll
  for (int n = 0; n < NST; n += 4) {
    *(float4*)&hend[base + n] = make_float4(h[n], h[n + 1], h[n + 2], h[n + 3]);
    *(float4*)&Pend[base + n] = make_float4(P[n], P[n + 1], P[n + 2], P[n + 3]);
  }
}

__global__ __launch_bounds__(256) void scan_carry(const float* __restrict__ hend,
                                                  const float* __restrict__ Pend,
                                                  float* __restrict__ hin) {
  const int flat = blockIdx.x * 256 + threadIdx.x;
  const int br = flat >> 15;
  const int dn = flat & 32767;
  float h = 0.f;
  for (int c = 0; c < NCH; ++c) {
    size_t idx = ((size_t)(br * NCH + c) << 15) + dn;
    hin[idx] = h;
    h = fmaf(Pend[idx], h, hend[idx]);
  }
}

__global__ __launch_bounds__(256) void scan_phase_c(const float* __restrict__ xc,
                                                    const float* __restrict__ xz,
                                                    const float* __restrict__ dtt1,
                                                    const float* __restrict__ dtt2,
                                                    const float* __restrict__ dbl1,
                                                    const float* __restrict__ dbl2,
                                                    const float* __restrict__ b1,
                                                    const float* __restrict__ b2,
                                                    const float* __restrict__ Al1,
                                                    const float* __restrict__ Al2,
                                                    const float* __restrict__ D1,
                                                    const float* __restrict__ D2,
                                                    const float* __restrict__ hin,
                                                    float* __restrict__ y1t,
                                                    float* __restrict__ y2t) {
  const int br = blockIdx.z;
  const float* __restrict__ dtt = br ? dtt2 : dtt1;
  const float* __restrict__ dbl = br ? dbl2 : dbl1;
  const float* __restrict__ dtb = br ? b2 : b1;
  const float* __restrict__ Al = br ? Al2 : Al1;
  const float* __restrict__ Dp = br ? D2 : D1;
  float* __restrict__ yt = br ? y2t : y1t;
  const int c = blockIdx.y;
  const int t0 = c * CH;
  const int d = blockIdx.x * 256 + threadIdx.x;

  __shared__ __align__(16) float bc_s[CH][2 * NST];
  for (int i = threadIdx.x; i < CH * NST; i += 256) {
    int n = i >> 6, t = i & 63;
    bc_s[t][2 * n]     = dbl[(size_t)(DTR + n) * SEQ + t0 + t];
    bc_s[t][2 * n + 1] = dbl[(size_t)(DTR + NST + n) * SEQ + t0 + t];
  }
  __syncthreads();

  const float bias = dtb[d];
  const float Dd = Dp[d];
  float An[NST], h[NST];
#pragma unroll
  for (int n = 0; n < NST; ++n)
    An[n] = -__expf(Al[(size_t)d * NST + n]) * 1.4426950408889634f;
  const size_t hbase = ((size_t)(br * NCH + c) * DIN + d) * NST;
#pragma unroll
  for (int n = 0; n < NST; n += 4) {
    float4 hv = *(const float4*)&hin[hbase + n];
    h[n] = hv.x; h[n + 1] = hv.y; h[n + 2] = hv.z; h[n + 3] = hv.w;
  }

  for (int tt = 0; tt < CH / 4; ++tt) {
    float4 u4 = *(const float4*)&xc[(size_t)d * SEQ + t0 + tt * 4];
    float4 z4 = *(const float4*)&xz[(size_t)(DIN + d) * SEQ + t0 + tt * 4];
    float uarr[4] = {u4.x, u4.y, u4.z, u4.w};
    float zarr[4] = {z4.x, z4.y, z4.z, z4.w};
#pragma unroll
    for (int j = 0; j < 4; ++j) {
      const int t = tt * 4 + j;
      float dv = dtt[(size_t)(t0 + t) * DIN + d] + bias;
      float sp = dv > 20.f ? dv : log1pf(__expf(dv));
      float spu = sp * uarr[j];
      float y = 0.f;
#pragma unroll
      for (int ng = 0; ng < 4; ++ng) {
        float4 v0 = *(const float4*)&bc_s[t][ng * 8];
        float4 v1 = *(const float4*)&bc_s[t][ng * 8 + 4];
        float bf[4] = {v0.x, v0.z, v1.x, v1.z};
        float cf[4] = {v0.y, v0.w, v1.y, v1.w};
#pragma unroll
        for (int k = 0; k < 4; ++k) {
          int n = ng * 4 + k;
          float dA = exp2f(An[n] * sp);
          h[n] = fmaf(dA, h[n], spu * bf[k]);
          y = fmaf(h[n], cf[k], y);
        }
      }
      float zz = zarr[j];
      float sz = zz / (1.f + __expf(-zz));
      yt[(size_t)(t0 + t) * DIN + d] = (y + Dd * uarr[j]) * sz;
    }
  }
}

// =====================================================================
extern "C" void kernel_launch(void* const* d_in, const int* in_sizes, int n_in,
                              void* d_out, int out_size, void* d_ws, size_t ws_size,
                              hipStream_t stream) {
  const float* hidden = (const float*)d_in[0];
  const float* in_proj_w = (const float*)d_in[1];
  const float* conv_w = (const float*)d_in[2];
  const float* conv_b = (const float*)d_in[3];
  const float* x1w = (const float*)d_in[4];
  const float* dtw1 = (const float*)d_in[5];
  const float* dtb1 = (const float*)d_in[6];
  const float* Al1 = (const float*)d_in[7];
  const float* D1 = (const float*)d_in[8];
  const float* x2w = (const float*)d_in[9];
  const float* dtw2 = (const float*)d_in[10];
  const float* dtb2 = (const float*)d_in[11];
  const float* Al2 = (const float*)d_in[12];
  const float* D2 = (const float*)d_in[13];
  const float* outw = (const float*)d_in[14];
  float* out = (float*)d_out;

  // Workspace layout (floats), same footprint as round 2 (~137.5 MB).
  float* ws = (float*)d_ws;
  float* xz = ws;                                  // 8M
  float* xc = xz + (size_t)4096 * SEQ;             // 4M
  float* dbl1 = xc + (size_t)DIN * SEQ;            // 96*2048
  float* dbl2 = dbl1 + (size_t)96 * SEQ;
  float* dtt1 = dbl2 + (size_t)96 * SEQ;           // 4M
  float* dtt2 = dtt1 + (size_t)SEQ * DIN;          // 4M
  float* y1t = dtt2 + (size_t)SEQ * DIN;           // 4M
  float* y2t = y1t + (size_t)SEQ * DIN;            // 4M
  float* hend = y2t + (size_t)SEQ * DIN;           // 2M
  float* Pend = hend + (size_t)2 * NCH * DIN * NST;// 2M
  float* hin = Pend + (size_t)2 * NCH * DIN * NST; // 2M

  // Aliases (all lifetime-disjoint):
  float* p1 = dtt1;                         // xproj partials, dead before dt_gemm
  float* p2 = dtt2;
  ushort* w_hi = (ushort*)y1t;              // in_proj_w planes, dead after in_proj
  ushort* w_lo = (ushort*)(y1t + 2 * 1024 * 1024);
  ushort* h_hi = (ushort*)y2t;              // hidden planes, dead after in_proj
  ushort* h_lo = (ushort*)(y2t + 1024 * 1024);
  ushort* yd_hi = (ushort*)xc;              // ydiff planes, written after xc dead
  ushort* yd_lo = (ushort*)(xc + 2 * 1024 * 1024);
  ushort* ow_hi = (ushort*)hend;            // outw planes, written after carry
  ushort* ow_lo = (ushort*)(hend + 1024 * 1024);
  float* opart = dtt1;                      // out_proj split-K partials (8M = dtt1+dtt2)

  dim3 blk(256);

  // 1) split-convert in_proj_w and hidden
  cvt_split<<<dim3(4096), blk, 0, stream>>>(in_proj_w, w_hi, w_lo, 4096 * DMODEL);
  cvt_split<<<dim3(2048), blk, 0, stream>>>(hidden, h_hi, h_lo, SEQ * DMODEL);

  // 2) in_proj via 3-pass bf16 MFMA: xz[e,l], M=4096,N=2048,K=1024
  gemm3p<128, 128, 1><<<dim3(SEQ / 128, 4096 / 128, 1), blk, 0, stream>>>(
      w_hi, w_lo, h_hi, h_lo, xz, 4096, SEQ, DMODEL);

  // 3) causal conv + silu
  conv_silu_kernel<<<dim3(SEQ / 256, DIN), blk, 0, stream>>>(xz, conv_w, conv_b, xc);

  // 4) x_proj partials + reduce
  xproj_kernel<<<dim3(SEQ / 128, 8, 2), blk, 0, stream>>>(xc, x1w, x2w, p1, p2);
  reduce_dbl_kernel<<<dim3(2 * 96 * SEQ / 256), blk, 0, stream>>>(p1, p2, dbl1, dbl2);

  // 5) dt projection -> (l,d)
  dt_gemm_kernel<<<dim3(SEQ / 64, DIN / 64, 2), blk, 0, stream>>>(
      dbl1, dbl2, dtw1, dtw2, dtt1, dtt2);

  // 6) chunked selective scan
  scan_phase_a<<<dim3(DIN / 256, NCH, 2), blk, 0, stream>>>(
      xc, dtt1, dtt2, dbl1, dbl2, dtb1, dtb2, Al1, Al2, hend, Pend);
  scan_carry<<<dim3(2 * DIN * NST / 256), blk, 0, stream>>>(hend, Pend, hin);
  cvt_split<<<dim3(2048), blk, 0, stream>>>(outw, ow_hi, ow_lo, DMODEL * DIN);
  scan_phase_c<<<dim3(DIN / 256, NCH, 2), blk, 0, stream>>>(
      xc, xz, dtt1, dtt2, dbl1, dbl2, dtb1, dtb2, Al1, Al2, D1, D2, hin, y1t, y2t);

  // 7) ydiff -> bf16 planes (xc region)
  cvt_ydiff<<<dim3(4096), blk, 0, stream>>>(y1t, y2t, yd_hi, yd_lo, SEQ * DIN);

  // 8) out_proj via 3-pass bf16 MFMA, split-K=4: out[l,o], M=2048,N=1024,K=2048
  gemm3p<128, 128, 4><<<dim3(DMODEL / 128, SEQ / 128, 4), blk, 0, stream>>>(
      yd_hi, yd_lo, ow_hi, ow_lo, opart, SEQ, DMODEL, DIN);
  reduce_out<<<dim3(SEQ * DMODEL / 1024), blk, 0, stream>>>(opart, out, SEQ * DMODEL);
}

// Round 4
// 429.256 us; speedup vs baseline: 2.7262x; 1.1615x over previous
//
#include <hip/hip_runtime.h>
#include <math.h>

#define SEQ 2048
#define DMODEL 1024
#define DIN 2048
#define NST 16
#define DTR 64
#define CH 64
#define NCH (SEQ / CH)

typedef __attribute__((ext_vector_type(8))) short bf16x8;
typedef __attribute__((ext_vector_type(4))) float f32x4;

__device__ __forceinline__ ushort f2bf(float f) {
  union { float f; unsigned u; } c; c.f = f;
  return (ushort)((c.u + 0x7fffu + ((c.u >> 16) & 1u)) >> 16);
}
__device__ __forceinline__ float bf2f(ushort h) {
  union { unsigned u; float f; } c; c.u = ((unsigned)h) << 16;
  return c.f;
}
__device__ __forceinline__ float splus(float v) {
  return v > 20.f ? v : log1pf(__expf(v));
}
// p[n] = e^(n+1), depth-4 mul tree (no transcendentals).
__device__ __forceinline__ void powers16(float e, float* p) {
  float e2 = e * e, e4 = e2 * e2, e8 = e4 * e4;
  p[0] = e;       p[1] = e2;       p[2] = e2 * e;   p[3] = e4;
  p[4] = e4 * e;  p[5] = e4 * e2;  p[6] = e4 * p[2]; p[7] = e8;
  p[8] = e8 * e;  p[9] = e8 * e2;  p[10] = e8 * p[2]; p[11] = e8 * e4;
  p[12] = e8 * p[4]; p[13] = e8 * p[5]; p[14] = e8 * p[6]; p[15] = e8 * e8;
}

#define GLL(g, l) __builtin_amdgcn_global_load_lds( \
    (const __attribute__((address_space(1))) void*)(g), \
    (__attribute__((address_space(3))) void*)(l), 16, 0, 0)

// =====================================================================
// Split-bf16 3-pass MFMA GEMM (fp32-accurate).  C[m,n]=sum_k A[m,k]B[n,k]
// =====================================================================
template<int BM, int BN, int SPLITK>
__global__ __launch_bounds__(256) void gemm3p(const ushort* __restrict__ Ahi,
                                              const ushort* __restrict__ Alo,
                                              const ushort* __restrict__ Bhi,
                                              const ushort* __restrict__ Blo,
                                              float* __restrict__ C,
                                              int M, int N, int K) {
  constexpr int BK = 32;
  constexpr int WM = BM / 2, WN = BN / 2, TM = WM / 16, TN = WN / 16;
  constexpr int SA = BM / 16, SB = BN / 16;
  __shared__ __align__(16) ushort sAh[BM * BK], sAl[BM * BK];
  __shared__ __align__(16) ushort sBh[BN * BK], sBl[BN * BK];
  const int tid = threadIdx.x, wid = tid >> 6, lane = tid & 63;
  const int m0 = blockIdx.y * BM, n0 = blockIdx.x * BN;
  const int Kc = K / SPLITK, kbeg = blockIdx.z * Kc;
  const int wm0 = (wid >> 1) * WM, wn0 = (wid & 1) * WN;
  const int fr = lane & 15, fk = (lane >> 4) * 8;
  const int lrow = lane >> 2, lk = (lane & 3) * 8;

  f32x4 acc[TM][TN];
#pragma unroll
  for (int mi = 0; mi < TM; ++mi)
#pragma unroll
    for (int ni = 0; ni < TN; ++ni)
#pragma unroll
      for (int r = 0; r < 4; ++r) acc[mi][ni][r] = 0.f;

  for (int k0 = 0; k0 < Kc; k0 += BK) {
    __syncthreads();
    const int kg = kbeg + k0 + lk;
#pragma unroll
    for (int i = 0; i < SA / 4; ++i) {
      const int seg = wid * (SA / 4) + i;
      const size_t ga = (size_t)(m0 + seg * 16 + lrow) * K + kg;
      GLL(&Ahi[ga], &sAh[seg * 512]);
      GLL(&Alo[ga], &sAl[seg * 512]);
    }
#pragma unroll
    for (int i = 0; i < SB / 4; ++i) {
      const int seg = wid * (SB / 4) + i;
      const size_t ga = (size_t)(n0 + seg * 16 + lrow) * K + kg;
      GLL(&Bhi[ga], &sBh[seg * 512]);
      GLL(&Blo[ga], &sBl[seg * 512]);
    }
    __syncthreads();

    bf16x8 ah[TM], al[TM], bh[TN], bl[TN];
#pragma unroll
    for (int mi = 0; mi < TM; ++mi) {
      const int r = (wm0 + mi * 16 + fr) * 32 + fk;
      ah[mi] = *(const bf16x8*)&sAh[r];
      al[mi] = *(const bf16x8*)&sAl[r];
    }
#pragma unroll
    for (int ni = 0; ni < TN; ++ni) {
      const int r = (wn0 + ni * 16 + fr) * 32 + fk;
      bh[ni] = *(const bf16x8*)&sBh[r];
      bl[ni] = *(const bf16x8*)&sBl[r];
    }
#pragma unroll
    for (int mi = 0; mi < TM; ++mi)
#pragma unroll
      for (int ni = 0; ni < TN; ++ni) {
        acc[mi][ni] = __builtin_amdgcn_mfma_f32_16x16x32_bf16(ah[mi], bh[ni], acc[mi][ni], 0, 0, 0);
        acc[mi][ni] = __builtin_amdgcn_mfma_f32_16x16x32_bf16(ah[mi], bl[ni], acc[mi][ni], 0, 0, 0);
        acc[mi][ni] = __builtin_amdgcn_mfma_f32_16x16x32_bf16(al[mi], bh[ni], acc[mi][ni], 0, 0, 0);
      }
  }

  float* __restrict__ Co = C + (size_t)blockIdx.z * M * N;
#pragma unroll
  for (int mi = 0; mi < TM; ++mi)
#pragma unroll
    for (int ni = 0; ni < TN; ++ni)
#pragma unroll
      for (int r = 0; r < 4; ++r)
        Co[(size_t)(m0 + wm0 + mi * 16 + (lane >> 4) * 4 + r) * N + n0 + wn0 + ni * 16 + fr] =
            acc[mi][ni][r];
}

__global__ __launch_bounds__(256) void cvt_split(const float* __restrict__ x,
                                                 ushort* __restrict__ hi,
                                                 ushort* __restrict__ lo, int n) {
  const int i = (blockIdx.x * 256 + threadIdx.x) * 4;
  if (i >= n) return;
  float4 v = *(const float4*)&x[i];
  ushort h0 = f2bf(v.x), h1 = f2bf(v.y), h2 = f2bf(v.z), h3 = f2bf(v.w);
  ushort l0 = f2bf(v.x - bf2f(h0)), l1 = f2bf(v.y - bf2f(h1));
  ushort l2 = f2bf(v.z - bf2f(h2)), l3 = f2bf(v.w - bf2f(h3));
  *(ushort4*)&hi[i] = make_ushort4(h0, h1, h2, h3);
  *(ushort4*)&lo[i] = make_ushort4(l0, l1, l2, l3);
}

__global__ __launch_bounds__(256) void cvt_ydiff(const float* __restrict__ y1,
                                                 const float* __restrict__ y2,
                                                 ushort* __restrict__ hi,
                                                 ushort* __restrict__ lo, int n) {
  const int i = (blockIdx.x * 256 + threadIdx.x) * 4;
  if (i >= n) return;
  float4 a = *(const float4*)&y1[i];
  float4 b = *(const float4*)&y2[i];
  float d0 = a.x - b.x, d1 = a.y - b.y, d2 = a.z - b.z, d3 = a.w - b.w;
  ushort h0 = f2bf(d0), h1 = f2bf(d1), h2 = f2bf(d2), h3 = f2bf(d3);
  ushort l0 = f2bf(d0 - bf2f(h0)), l1 = f2bf(d1 - bf2f(h1));
  ushort l2 = f2bf(d2 - bf2f(h2)), l3 = f2bf(d3 - bf2f(h3));
  *(ushort4*)&hi[i] = make_ushort4(h0, h1, h2, h3);
  *(ushort4*)&lo[i] = make_ushort4(l0, l1, l2, l3);
}

__global__ __launch_bounds__(256) void reduce_out(const float* __restrict__ p,
                                                  float* __restrict__ o, int n) {
  const int i = (blockIdx.x * 256 + threadIdx.x) * 4;
  if (i >= n) return;
  float4 a = *(const float4*)&p[i];
  float4 b = *(const float4*)&p[(size_t)n + i];
  float4 c = *(const float4*)&p[(size_t)2 * n + i];
  float4 d = *(const float4*)&p[(size_t)3 * n + i];
  *(float4*)&o[i] = make_float4(a.x + b.x + c.x + d.x, a.y + b.y + c.y + d.y,
                                a.z + b.z + c.z + d.z, a.w + b.w + c.w + d.w);
}

// =====================================================================
// Depthwise causal conv (w=4) + bias + SiLU.
// =====================================================================
__global__ __launch_bounds__(256) void conv_silu_kernel(const float* __restrict__ xz,
                                                        const float* __restrict__ cw,
                                                        const float* __restrict__ cb,
                                                        float* __restrict__ xc) {
  const int d = blockIdx.y;
  const int l = blockIdx.x * 256 + threadIdx.x;
  const float* xrow = xz + (size_t)d * SEQ;
  const float w0 = cw[d * 4 + 0], w1 = cw[d * 4 + 1], w2 = cw[d * 4 + 2], w3 = cw[d * 4 + 3];
  float a = cb[d] + w3 * xrow[l];
  if (l >= 1) a += w2 * xrow[l - 1];
  if (l >= 2) a += w1 * xrow[l - 2];
  if (l >= 3) a += w0 * xrow[l - 3];
  xc[(size_t)d * SEQ + l] = a / (1.f + __expf(-a));
}

// =====================================================================
// x_proj (both branches), K-split over d -> partials.
// =====================================================================
__global__ __launch_bounds__(256) void xproj_kernel(const float* __restrict__ xc,
                                                    const float* __restrict__ w1,
                                                    const float* __restrict__ w2,
                                                    float* __restrict__ p1,
                                                    float* __restrict__ p2) {
  __shared__ __align__(16) float Xs[32][128];
  __shared__ float Wst[32][97];
  const int tid = threadIdx.x;
  const int l0 = blockIdx.x * 128;
  const int c = blockIdx.y;
  const float* __restrict__ W = blockIdx.z ? w2 : w1;
  float* __restrict__ outp = blockIdx.z ? p2 : p1;
  const int tk = tid >> 4, tl = tid & 15;
  float acc[6][8];
#pragma unroll
  for (int i = 0; i < 6; ++i)
#pragma unroll
    for (int j = 0; j < 8; ++j) acc[i][j] = 0.f;

  for (int s = 0; s < 8; ++s) {
    const int dbase = c * 256 + s * 32;
    __syncthreads();
    for (int i = tid; i < 32 * 128; i += 256) {
      int ddi = i >> 7, ll = i & 127;
      Xs[ddi][ll] = xc[(size_t)(dbase + ddi) * SEQ + l0 + ll];
    }
    for (int i = tid; i < 96 * 32; i += 256) {
      int r = i >> 5, ddi = i & 31;
      Wst[ddi][r] = W[(size_t)r * DIN + dbase + ddi];
    }
    __syncthreads();
    for (int ddi = 0; ddi < 32; ++ddi) {
      float4 xa = *(const float4*)&Xs[ddi][tl * 8];
      float4 xb = *(const float4*)&Xs[ddi][tl * 8 + 4];
      float xv[8] = {xa.x, xa.y, xa.z, xa.w, xb.x, xb.y, xb.z, xb.w};
#pragma unroll
      for (int i = 0; i < 6; ++i) {
        float wv = Wst[ddi][tk * 6 + i];
#pragma unroll
        for (int j = 0; j < 8; ++j) acc[i][j] = fmaf(wv, xv[j], acc[i][j]);
      }
    }
  }
#pragma unroll
  for (int i = 0; i < 6; ++i) {
    int k = tk * 6 + i;
    size_t base = ((size_t)c * 96 + k) * SEQ + l0 + tl * 8;
    *(float4*)&outp[base]     = make_float4(acc[i][0], acc[i][1], acc[i][2], acc[i][3]);
    *(float4*)&outp[base + 4] = make_float4(acc[i][4], acc[i][5], acc[i][6], acc[i][7]);
  }
}

// Reduce partials -> dbl; also transpose B/C rows into (l,n) tables.
__global__ __launch_bounds__(256) void reduce_dbl_kernel(const float* __restrict__ p1,
                                                         const float* __restrict__ p2,
                                                         float* __restrict__ o1,
                                                         float* __restrict__ o2,
                                                         float* __restrict__ BT1,
                                                         float* __restrict__ CT1,
                                                         float* __restrict__ BT2,
                                                         float* __restrict__ CT2) {
  const int NE = 96 * SEQ;
  int idx = blockIdx.x * 256 + threadIdx.x;
  const int br = idx >= NE;
  const float* p = br ? p2 : p1;
  float* o = br ? o2 : o1;
  float* BT = br ? BT2 : BT1;
  float* CT = br ? CT2 : CT1;
  const int j = idx - br * NE;
  float s = 0.f;
#pragma unroll
  for (int cc = 0; cc < 8; ++cc) s += p[(size_t)cc * NE + j];
  o[j] = s;
  const int k = j >> 11, l = j & (SEQ - 1);
  if (k >= DTR && k < DTR + NST)      BT[l * NST + (k - DTR)] = s;
  else if (k >= DTR + NST)            CT[l * NST + (k - DTR - NST)] = s;
}

// =====================================================================
// dt GEMM with fused softplus(dt+bias); output sp in (d,l) layout.
// =====================================================================
__global__ __launch_bounds__(256) void dt_gemm_kernel(const float* __restrict__ dbl1,
                                                      const float* __restrict__ dbl2,
                                                      const float* __restrict__ w1,
                                                      const float* __restrict__ w2,
                                                      const float* __restrict__ b1,
                                                      const float* __restrict__ b2,
                                                      float* __restrict__ o1,
                                                      float* __restrict__ o2) {
  const int br = blockIdx.z;
  const float* __restrict__ dbl = br ? dbl2 : dbl1;
  const float* __restrict__ W = br ? w2 : w1;
  const float* __restrict__ dtb = br ? b2 : b1;
  float* __restrict__ outp = br ? o2 : o1;
  const int l0 = blockIdx.x * 64, d0 = blockIdx.y * 64;
  __shared__ __align__(16) float Wt[64][68];
  __shared__ __align__(16) float Bs[64][68];
  const int tid = threadIdx.x;
  for (int i = tid; i < 4096; i += 256) {
    int a = i >> 6, b = i & 63;
    Wt[b][a] = W[(size_t)(d0 + a) * DTR + b];
    Bs[a][b] = dbl[(size_t)a * SEQ + l0 + b];
  }
  __syncthreads();
  const int tl_ = tid >> 4, td_ = tid & 15;
  float acc[4][4];  // [i: l][j: d]
#pragma unroll
  for (int i = 0; i < 4; ++i)
#pragma unroll
    for (int j = 0; j < 4; ++j) acc[i][j] = 0.f;
  for (int r = 0; r < 64; ++r) {
    float4 av = *(const float4*)&Bs[r][tl_ * 4];
    float4 bv = *(const float4*)&Wt[r][td_ * 4];
    float am[4] = {av.x, av.y, av.z, av.w};
    float bn[4] = {bv.x, bv.y, bv.z, bv.w};
#pragma unroll
    for (int i = 0; i < 4; ++i)
#pragma unroll
      for (int j = 0; j < 4; ++j) acc[i][j] = fmaf(am[i], bn[j], acc[i][j]);
  }
#pragma unroll
  for (int j = 0; j < 4; ++j) {
    const int dd = d0 + td_ * 4 + j;
    const float bias = dtb[dd];
    float4 w = make_float4(splus(acc[0][j] + bias), splus(acc[1][j] + bias),
                           splus(acc[2][j] + bias), splus(acc[3][j] + bias));
    *(float4*)&outp[(size_t)dd * SEQ + l0 + tl_ * 4] = w;
  }
}

// =====================================================================
// Chunked selective scan.  dA_n = exp(-k_n*sp); fast path when
// k_n = exp(A_log) == n+1 (true for this model): one exp + mul tree.
// =====================================================================
__global__ __launch_bounds__(256) void scan_phase_a(const float* __restrict__ xc,
                                                    const float* __restrict__ sp1p,
                                                    const float* __restrict__ sp2p,
                                                    const float* __restrict__ BT1,
                                                    const float* __restrict__ BT2,
                                                    const float* __restrict__ Al1,
                                                    const float* __restrict__ Al2,
                                                    float* __restrict__ hend,
                                                    float* __restrict__ Pend) {
  const int br = blockIdx.z;
  const float* __restrict__ spp = br ? sp2p : sp1p;
  const float* __restrict__ BT = br ? BT2 : BT1;
  const float* __restrict__ Al = br ? Al2 : Al1;
  const int c = blockIdx.y;
  const int t0 = c * CH;
  const int d = blockIdx.x * 256 + threadIdx.x;

  __shared__ __align__(16) float Bs[CH][NST];
  ((float4*)Bs)[threadIdx.x] = ((const float4*)&BT[t0 * NST])[threadIdx.x];
  __syncthreads();

  bool fast = true;
#pragma unroll
  for (int n = 0; n < NST; ++n) {
    float kx = __expf(Al[(size_t)d * NST + n]);
    fast = fast && (fabsf(kx - (float)(n + 1)) < 1e-3f);
  }
  float h[NST];
#pragma unroll
  for (int n = 0; n < NST; ++n) h[n] = 0.f;
  float S = 0.f;

  if (fast) {
    for (int tt = 0; tt < CH / 4; ++tt) {
      float4 sp4 = *(const float4*)&spp[(size_t)d * SEQ + t0 + tt * 4];
      float4 u4 = *(const float4*)&xc[(size_t)d * SEQ + t0 + tt * 4];
      float sparr[4] = {sp4.x, sp4.y, sp4.z, sp4.w};
      float uarr[4] = {u4.x, u4.y, u4.z, u4.w};
#pragma unroll
      for (int j = 0; j < 4; ++j) {
        const int t = tt * 4 + j;
        const float sp = sparr[j];
        S += sp;
        const float spu = sp * uarr[j];
        const float e = __expf(-sp);
        float p[NST];
        powers16(e, p);
#pragma unroll
        for (int ng = 0; ng < 4; ++ng) {
          float4 bq = *(const float4*)&Bs[t][ng * 4];
          float bf[4] = {bq.x, bq.y, bq.z, bq.w};
#pragma unroll
          for (int k = 0; k < 4; ++k) {
            int n = ng * 4 + k;
            h[n] = fmaf(p[n], h[n], spu * bf[k]);
          }
        }
      }
    }
  } else {
    float AnL2[NST];
#pragma unroll
    for (int n = 0; n < NST; ++n)
      AnL2[n] = -__expf(Al[(size_t)d * NST + n]) * 1.4426950408889634f;
    for (int tt = 0; tt < CH / 4; ++tt) {
      float4 sp4 = *(const float4*)&spp[(size_t)d * SEQ + t0 + tt * 4];
      float4 u4 = *(const float4*)&xc[(size_t)d * SEQ + t0 + tt * 4];
      float sparr[4] = {sp4.x, sp4.y, sp4.z, sp4.w};
      float uarr[4] = {u4.x, u4.y, u4.z, u4.w};
#pragma unroll
      for (int j = 0; j < 4; ++j) {
        const int t = tt * 4 + j;
        const float sp = sparr[j];
        S += sp;
        const float spu = sp * uarr[j];
#pragma unroll
        for (int ng = 0; ng < 4; ++ng) {
          float4 bq = *(const float4*)&Bs[t][ng * 4];
          float bf[4] = {bq.x, bq.y, bq.z, bq.w};
#pragma unroll
          for (int k = 0; k < 4; ++k) {
            int n = ng * 4 + k;
            float dA = exp2f(AnL2[n] * sp);
            h[n] = fmaf(dA, h[n], spu * bf[k]);
          }
        }
      }
    }
  }

  float P[NST];
  if (fast) {
    powers16(__expf(-S), P);
  } else {
#pragma unroll
    for (int n = 0; n < NST; ++n)
      P[n] = exp2f(-__expf(Al[(size_t)d * NST + n]) * 1.4426950408889634f * S);
  }
  size_t base = ((size_t)(br * NCH + c) * DIN + d) * NST;
#pragma unroll
  for (int n = 0; n < NST; n += 4) {
    *(float4*)&hend[base + n] = make_float4(h[n], h[n + 1], h[n + 2], h[n + 3]);
    *(float4*)&Pend[base + n] = make_float4(P[n], P[n + 1], P[n + 2], P[n + 3]);
  }
}

// Carry across chunks; hin overwrites Pend in place (read P first).
__global__ __launch_bounds__(256) void scan_carry(const float* __restrict__ hend,
                                                  float* __restrict__ PendHin) {
  const int flat = blockIdx.x * 256 + threadIdx.x;
  const int br = flat >> 15;
  const int dn = flat & 32767;
  float h = 0.f;
  for (int c = 0; c < NCH; ++c) {
    size_t idx = ((size_t)(br * NCH + c) << 15) + dn;
    float Pv = PendHin[idx];
    float he = hend[idx];
    PendHin[idx] = h;
    h = fmaf(Pv, h, he);
  }
}

__global__ __launch_bounds__(256) void scan_phase_c(const float* __restrict__ xc,
                                                    const float* __restrict__ xz,
                                                    const float* __restrict__ sp1p,
                                                    const float* __restrict__ sp2p,
                                                    const float* __restrict__ BT1,
                                                    const float* __restrict__ CT1,
                                                    const float* __restrict__ BT2,
                                                    const float* __restrict__ CT2,
                                                    const float* __restrict__ Al1,
                                                    const float* __restrict__ Al2,
                                                    const float* __restrict__ D1,
                                                    const float* __restrict__ D2,
                                                    const float* __restrict__ hin,
                                                    float* __restrict__ y1t,
                                                    float* __restrict__ y2t) {
  const int br = blockIdx.z;
  const float* __restrict__ spp = br ? sp2p : sp1p;
  const float* __restrict__ BT = br ? BT2 : BT1;
  const float* __restrict__ CT = br ? CT2 : CT1;
  const float* __restrict__ Al = br ? Al2 : Al1;
  const float* __restrict__ Dp = br ? D2 : D1;
  float* __restrict__ yt = br ? y2t : y1t;
  const int c = blockIdx.y;
  const int t0 = c * CH;
  const int d = blockIdx.x * 256 + threadIdx.x;

  __shared__ __align__(16) float Bs[CH][NST];
  __shared__ __align__(16) float Cs[CH][NST];
  ((float4*)Bs)[threadIdx.x] = ((const float4*)&BT[t0 * NST])[threadIdx.x];
  ((float4*)Cs)[threadIdx.x] = ((const float4*)&CT[t0 * NST])[threadIdx.x];
  __syncthreads();

  bool fast = true;
#pragma unroll
  for (int n = 0; n < NST; ++n) {
    float kx = __expf(Al[(size_t)d * NST + n]);
    fast = fast && (fabsf(kx - (float)(n + 1)) < 1e-3f);
  }
  const float Dd = Dp[d];
  float h[NST];
  const size_t hbase = ((size_t)(br * NCH + c) * DIN + d) * NST;
#pragma unroll
  for (int n = 0; n < NST; n += 4) {
    float4 hv = *(const float4*)&hin[hbase + n];
    h[n] = hv.x; h[n + 1] = hv.y; h[n + 2] = hv.z; h[n + 3] = hv.w;
  }

  if (fast) {
    for (int tt = 0; tt < CH / 4; ++tt) {
      float4 sp4 = *(const float4*)&spp[(size_t)d * SEQ + t0 + tt * 4];
      float4 u4 = *(const float4*)&xc[(size_t)d * SEQ + t0 + tt * 4];
      float4 z4 = *(const float4*)&xz[(size_t)(DIN + d) * SEQ + t0 + tt * 4];
      float sparr[4] = {sp4.x, sp4.y, sp4.z, sp4.w};
      float uarr[4] = {u4.x, u4.y, u4.z, u4.w};
      float zarr[4] = {z4.x, z4.y, z4.z, z4.w};
#pragma unroll
      for (int j = 0; j < 4; ++j) {
        const int t = tt * 4 + j;
        const float sp = sparr[j];
        const float spu = sp * uarr[j];
        const float e = __expf(-sp);
        float p[NST];
        powers16(e, p);
        float y = 0.f;
#pragma unroll
        for (int ng = 0; ng < 4; ++ng) {
          float4 bq = *(const float4*)&Bs[t][ng * 4];
          float4 cq = *(const float4*)&Cs[t][ng * 4];
          float bf[4] = {bq.x, bq.y, bq.z, bq.w};
          float cf[4] = {cq.x, cq.y, cq.z, cq.w};
#pragma unroll
          for (int k = 0; k < 4; ++k) {
            int n = ng * 4 + k;
            h[n] = fmaf(p[n], h[n], spu * bf[k]);
            y = fmaf(h[n], cf[k], y);
          }
        }
        const float zz = zarr[j];
        const float sz = zz / (1.f + __expf(-zz));
        yt[(size_t)(t0 + t) * DIN + d] = (y + Dd * uarr[j]) * sz;
      }
    }
  } else {
    float AnL2[NST];
#pragma unroll
    for (int n = 0; n < NST; ++n)
      AnL2[n] = -__expf(Al[(size_t)d * NST + n]) * 1.4426950408889634f;
    for (int tt = 0; tt < CH / 4; ++tt) {
      float4 sp4 = *(const float4*)&spp[(size_t)d * SEQ + t0 + tt * 4];
      float4 u4 = *(const float4*)&xc[(size_t)d * SEQ + t0 + tt * 4];
      float4 z4 = *(const float4*)&xz[(size_t)(DIN + d) * SEQ + t0 + tt * 4];
      float sparr[4] = {sp4.x, sp4.y, sp4.z, sp4.w};
      float uarr[4] = {u4.x, u4.y, u4.z, u4.w};
      float zarr[4] = {z4.x, z4.y, z4.z, z4.w};
#pragma unroll
      for (int j = 0; j < 4; ++j) {
        const int t = tt * 4 + j;
        const float sp = sparr[j];
        const float spu = sp * uarr[j];
        float y = 0.f;
#pragma unroll
        for (int ng = 0; ng < 4; ++ng) {
          float4 bq = *(const float4*)&Bs[t][ng * 4];
          float4 cq = *(const float4*)&Cs[t][ng * 4];
          float bf[4] = {bq.x, bq.y, bq.z, bq.w};
          float cf[4] = {cq.x, cq.y, cq.z, cq.w};
#pragma unroll
          for (int k = 0; k < 4; ++k) {
            int n = ng * 4 + k;
            float dA = exp2f(AnL2[n] * sp);
            h[n] = fmaf(dA, h[n], spu * bf[k]);
            y = fmaf(h[n], cf[k], y);
          }
        }
        const float zz = zarr[j];
        const float sz = zz / (1.f + __expf(-zz));
        yt[(size_t)(t0 + t) * DIN + d] = (y + Dd * uarr[j]) * sz;
      }
    }
  }
}

// =====================================================================
extern "C" void kernel_launch(void* const* d_in, const int* in_sizes, int n_in,
                              void* d_out, int out_size, void* d_ws, size_t ws_size,
                              hipStream_t stream) {
  const float* hidden = (const float*)d_in[0];
  const float* in_proj_w = (const float*)d_in[1];
  const float* conv_w = (const float*)d_in[2];
  const float* conv_b = (const float*)d_in[3];
  const float* x1w = (const float*)d_in[4];
  const float* dtw1 = (const float*)d_in[5];
  const float* dtb1 = (const float*)d_in[6];
  const float* Al1 = (const float*)d_in[7];
  const float* D1 = (const float*)d_in[8];
  const float* x2w = (const float*)d_in[9];
  const float* dtw2 = (const float*)d_in[10];
  const float* dtb2 = (const float*)d_in[11];
  const float* Al2 = (const float*)d_in[12];
  const float* D2 = (const float*)d_in[13];
  const float* outw = (const float*)d_in[14];
  float* out = (float*)d_out;

  // Workspace layout (floats), ~136.8 MB (< round-2/3's proven 144.2 MB).
  float* ws = (float*)d_ws;
  float* xz = ws;                                  // 8.39M
  float* xc = xz + (size_t)4096 * SEQ;             // 4.19M
  float* dbl1 = xc + (size_t)DIN * SEQ;            // 196K
  float* dbl2 = dbl1 + (size_t)96 * SEQ;           // 196K
  float* sp1p = dbl2 + (size_t)96 * SEQ;           // 4.19M  sp plane br1, (d,l)
  float* sp2p = sp1p + (size_t)SEQ * DIN;          // 4.19M
  float* y1t = sp2p + (size_t)SEQ * DIN;           // 4.19M  (l,d)
  float* y2t = y1t + (size_t)SEQ * DIN;            // 4.19M
  float* hend = y2t + (size_t)SEQ * DIN;           // 2.10M
  float* Pend = hend + (size_t)2 * NCH * DIN * NST;// 2.10M (also reused as hin)
  float* BT1 = Pend + (size_t)2 * NCH * DIN * NST; // 32K each
  float* CT1 = BT1 + (size_t)SEQ * NST;
  float* BT2 = CT1 + (size_t)SEQ * NST;
  float* CT2 = BT2 + (size_t)SEQ * NST;

  // Aliases (lifetime-disjoint):
  float* p1 = sp1p;                         // xproj partials, dead before dt_gemm
  float* p2 = sp2p;
  ushort* w_hi = (ushort*)y1t;
  ushort* w_lo = (ushort*)(y1t + 2 * 1024 * 1024);
  ushort* h_hi = (ushort*)y2t;
  ushort* h_lo = (ushort*)(y2t + 1024 * 1024);
  ushort* yd_hi = (ushort*)xc;              // written after xc dead
  ushort* yd_lo = (ushort*)(xc + 2 * 1024 * 1024);
  ushort* ow_hi = (ushort*)hend;            // written after carry
  ushort* ow_lo = (ushort*)(hend + 1024 * 1024);
  float* opart = sp1p;                      // out_proj split-K partials (8M)

  dim3 blk(256);

  // 1) split-convert in_proj_w and hidden
  cvt_split<<<dim3(4096), blk, 0, stream>>>(in_proj_w, w_hi, w_lo, 4096 * DMODEL);
  cvt_split<<<dim3(2048), blk, 0, stream>>>(hidden, h_hi, h_lo, SEQ * DMODEL);

  // 2) in_proj via 3-pass bf16 MFMA
  gemm3p<128, 128, 1><<<dim3(SEQ / 128, 4096 / 128, 1), blk, 0, stream>>>(
      w_hi, w_lo, h_hi, h_lo, xz, 4096, SEQ, DMODEL);

  // 3) causal conv + silu
  conv_silu_kernel<<<dim3(SEQ / 256, DIN), blk, 0, stream>>>(xz, conv_w, conv_b, xc);

  // 4) x_proj partials + reduce (+ B/C transpose tables)
  xproj_kernel<<<dim3(SEQ / 128, 8, 2), blk, 0, stream>>>(xc, x1w, x2w, p1, p2);
  reduce_dbl_kernel<<<dim3(2 * 96 * SEQ / 256), blk, 0, stream>>>(
      p1, p2, dbl1, dbl2, BT1, CT1, BT2, CT2);

  // 5) dt projection + fused softplus -> sp planes, (d,l)
  dt_gemm_kernel<<<dim3(SEQ / 64, DIN / 64, 2), blk, 0, stream>>>(
      dbl1, dbl2, dtw1, dtw2, dtb1, dtb2, sp1p, sp2p);

  // 6) chunked selective scan
  scan_phase_a<<<dim3(DIN / 256, NCH, 2), blk, 0, stream>>>(
      xc, sp1p, sp2p, BT1, BT2, Al1, Al2, hend, Pend);
  scan_carry<<<dim3(2 * DIN * NST / 256), blk, 0, stream>>>(hend, Pend);
  cvt_split<<<dim3(2048), blk, 0, stream>>>(outw, ow_hi, ow_lo, DMODEL * DIN);
  scan_phase_c<<<dim3(DIN / 256, NCH, 2), blk, 0, stream>>>(
      xc, xz, sp1p, sp2p, BT1, CT1, BT2, CT2, Al1, Al2, D1, D2, Pend, y1t, y2t);

  // 7) ydiff -> bf16 planes
  cvt_ydiff<<<dim3(4096), blk, 0, stream>>>(y1t, y2t, yd_hi, yd_lo, SEQ * DIN);

  // 8) out_proj via 3-pass bf16 MFMA, split-K=4
  gemm3p<128, 128, 4><<<dim3(DMODEL / 128, SEQ / 128, 4), blk, 0, stream>>>(
      yd_hi, yd_lo, ow_hi, ow_lo, opart, SEQ, DMODEL, DIN);
  reduce_out<<<dim3(SEQ * DMODEL / 1024), blk, 0, stream>>>(opart, out, SEQ * DMODEL);
}

// Round 5
// 368.539 us; speedup vs baseline: 3.1753x; 1.1647x over previous
//
#include <hip/hip_runtime.h>
#include <math.h>

#define SEQ 2048
#define DMODEL 1024
#define DIN 2048
#define NST 16
#define DTR 64
#define CH 64
#define NCH (SEQ / CH)

typedef __attribute__((ext_vector_type(8))) short bf16x8;
typedef __attribute__((ext_vector_type(4))) float f32x4;

__device__ __forceinline__ ushort f2bf(float f) {
  union { float f; unsigned u; } c; c.f = f;
  return (ushort)((c.u + 0x7fffu + ((c.u >> 16) & 1u)) >> 16);
}
__device__ __forceinline__ float bf2f(ushort h) {
  union { unsigned u; float f; } c; c.u = ((unsigned)h) << 16;
  return c.f;
}
__device__ __forceinline__ float splus(float v) {
  return v > 20.f ? v : log1pf(__expf(v));
}
// p[n] = e^(n+1), depth-4 mul tree (no transcendentals).
__device__ __forceinline__ void powers16(float e, float* p) {
  float e2 = e * e, e4 = e2 * e2, e8 = e4 * e4;
  p[0] = e;       p[1] = e2;       p[2] = e2 * e;   p[3] = e4;
  p[4] = e4 * e;  p[5] = e4 * e2;  p[6] = e4 * p[2]; p[7] = e8;
  p[8] = e8 * e;  p[9] = e8 * e2;  p[10] = e8 * p[2]; p[11] = e8 * e4;
  p[12] = e8 * p[4]; p[13] = e8 * p[5]; p[14] = e8 * p[6]; p[15] = e8 * e8;
}

#define GLL(g, l) __builtin_amdgcn_global_load_lds( \
    (const __attribute__((address_space(1))) void*)(g), \
    (__attribute__((address_space(3))) void*)(l), 16, 0, 0)

// =====================================================================
// Split-bf16 3-pass MFMA GEMM (fp32-accurate).  C[m,n]=sum_k A[m,k]B[n,k]
// =====================================================================
template<int BM, int BN, int SPLITK>
__global__ __launch_bounds__(256) void gemm3p(const ushort* __restrict__ Ahi,
                                              const ushort* __restrict__ Alo,
                                              const ushort* __restrict__ Bhi,
                                              const ushort* __restrict__ Blo,
                                              float* __restrict__ C,
                                              int M, int N, int K) {
  constexpr int BK = 32;
  constexpr int WM = BM / 2, WN = BN / 2, TM = WM / 16, TN = WN / 16;
  constexpr int SA = BM / 16, SB = BN / 16;
  __shared__ __align__(16) ushort sAh[BM * BK], sAl[BM * BK];
  __shared__ __align__(16) ushort sBh[BN * BK], sBl[BN * BK];
  const int tid = threadIdx.x, wid = tid >> 6, lane = tid & 63;
  const int m0 = blockIdx.y * BM, n0 = blockIdx.x * BN;
  const int Kc = K / SPLITK, kbeg = blockIdx.z * Kc;
  const int wm0 = (wid >> 1) * WM, wn0 = (wid & 1) * WN;
  const int fr = lane & 15, fk = (lane >> 4) * 8;
  const int lrow = lane >> 2, lk = (lane & 3) * 8;

  f32x4 acc[TM][TN];
#pragma unroll
  for (int mi = 0; mi < TM; ++mi)
#pragma unroll
    for (int ni = 0; ni < TN; ++ni)
#pragma unroll
      for (int r = 0; r < 4; ++r) acc[mi][ni][r] = 0.f;

  for (int k0 = 0; k0 < Kc; k0 += BK) {
    __syncthreads();
    const int kg = kbeg + k0 + lk;
#pragma unroll
    for (int i = 0; i < SA / 4; ++i) {
      const int seg = wid * (SA / 4) + i;
      const size_t ga = (size_t)(m0 + seg * 16 + lrow) * K + kg;
      GLL(&Ahi[ga], &sAh[seg * 512]);
      GLL(&Alo[ga], &sAl[seg * 512]);
    }
#pragma unroll
    for (int i = 0; i < SB / 4; ++i) {
      const int seg = wid * (SB / 4) + i;
      const size_t ga = (size_t)(n0 + seg * 16 + lrow) * K + kg;
      GLL(&Bhi[ga], &sBh[seg * 512]);
      GLL(&Blo[ga], &sBl[seg * 512]);
    }
    __syncthreads();

    bf16x8 ah[TM], al[TM], bh[TN], bl[TN];
#pragma unroll
    for (int mi = 0; mi < TM; ++mi) {
      const int r = (wm0 + mi * 16 + fr) * 32 + fk;
      ah[mi] = *(const bf16x8*)&sAh[r];
      al[mi] = *(const bf16x8*)&sAl[r];
    }
#pragma unroll
    for (int ni = 0; ni < TN; ++ni) {
      const int r = (wn0 + ni * 16 + fr) * 32 + fk;
      bh[ni] = *(const bf16x8*)&sBh[r];
      bl[ni] = *(const bf16x8*)&sBl[r];
    }
#pragma unroll
    for (int mi = 0; mi < TM; ++mi)
#pragma unroll
      for (int ni = 0; ni < TN; ++ni) {
        acc[mi][ni] = __builtin_amdgcn_mfma_f32_16x16x32_bf16(ah[mi], bh[ni], acc[mi][ni], 0, 0, 0);
        acc[mi][ni] = __builtin_amdgcn_mfma_f32_16x16x32_bf16(ah[mi], bl[ni], acc[mi][ni], 0, 0, 0);
        acc[mi][ni] = __builtin_amdgcn_mfma_f32_16x16x32_bf16(al[mi], bh[ni], acc[mi][ni], 0, 0, 0);
      }
  }

  float* __restrict__ Co = C + (size_t)blockIdx.z * M * N;
#pragma unroll
  for (int mi = 0; mi < TM; ++mi)
#pragma unroll
    for (int ni = 0; ni < TN; ++ni)
#pragma unroll
      for (int r = 0; r < 4; ++r)
        Co[(size_t)(m0 + wm0 + mi * 16 + (lane >> 4) * 4 + r) * N + n0 + wn0 + ni * 16 + fr] =
            acc[mi][ni][r];
}

__global__ __launch_bounds__(256) void cvt_split(const float* __restrict__ x,
                                                 ushort* __restrict__ hi,
                                                 ushort* __restrict__ lo, int n) {
  const int i = (blockIdx.x * 256 + threadIdx.x) * 4;
  if (i >= n) return;
  float4 v = *(const float4*)&x[i];
  ushort h0 = f2bf(v.x), h1 = f2bf(v.y), h2 = f2bf(v.z), h3 = f2bf(v.w);
  ushort l0 = f2bf(v.x - bf2f(h0)), l1 = f2bf(v.y - bf2f(h1));
  ushort l2 = f2bf(v.z - bf2f(h2)), l3 = f2bf(v.w - bf2f(h3));
  *(ushort4*)&hi[i] = make_ushort4(h0, h1, h2, h3);
  *(ushort4*)&lo[i] = make_ushort4(l0, l1, l2, l3);
}

__global__ __launch_bounds__(256) void cvt_ydiff(const float* __restrict__ y1,
                                                 const float* __restrict__ y2,
                                                 ushort* __restrict__ hi,
                                                 ushort* __restrict__ lo, int n) {
  const int i = (blockIdx.x * 256 + threadIdx.x) * 4;
  if (i >= n) return;
  float4 a = *(const float4*)&y1[i];
  float4 b = *(const float4*)&y2[i];
  float d0 = a.x - b.x, d1 = a.y - b.y, d2 = a.z - b.z, d3 = a.w - b.w;
  ushort h0 = f2bf(d0), h1 = f2bf(d1), h2 = f2bf(d2), h3 = f2bf(d3);
  ushort l0 = f2bf(d0 - bf2f(h0)), l1 = f2bf(d1 - bf2f(h1));
  ushort l2 = f2bf(d2 - bf2f(h2)), l3 = f2bf(d3 - bf2f(h3));
  *(ushort4*)&hi[i] = make_ushort4(h0, h1, h2, h3);
  *(ushort4*)&lo[i] = make_ushort4(l0, l1, l2, l3);
}

__global__ __launch_bounds__(256) void reduce_out(const float* __restrict__ p,
                                                  float* __restrict__ o, int n) {
  const int i = (blockIdx.x * 256 + threadIdx.x) * 4;
  if (i >= n) return;
  float4 a = *(const float4*)&p[i];
  float4 b = *(const float4*)&p[(size_t)n + i];
  float4 c = *(const float4*)&p[(size_t)2 * n + i];
  float4 d = *(const float4*)&p[(size_t)3 * n + i];
  *(float4*)&o[i] = make_float4(a.x + b.x + c.x + d.x, a.y + b.y + c.y + d.y,
                                a.z + b.z + c.z + d.z, a.w + b.w + c.w + d.w);
}

// =====================================================================
// Fused: depthwise causal conv (w=4) + bias + SiLU -> xc (d,l) fp32
// AND transposed bf16 hi/lo planes xcT (l,d) for the x_proj MFMA GEMM.
// 64x64 tiles; LDS transpose with conflict-free stride-65 access.
// =====================================================================
__global__ __launch_bounds__(256) void conv_tr_kernel(const float* __restrict__ xz,
                                                      const float* __restrict__ cw,
                                                      const float* __restrict__ cb,
                                                      float* __restrict__ xc,
                                                      ushort* __restrict__ xcT_hi,
                                                      ushort* __restrict__ xcT_lo) {
  const int l0 = blockIdx.x * 64, d0 = blockIdx.y * 64;
  const int tid = threadIdx.x;
  __shared__ float xin[64][68];  // cols 0..66 = l0-3 .. l0+63
  __shared__ float To[64][65];
  __shared__ float cwS[64][4];
  __shared__ float cbS[64];

  // main tile load (float4 rows)
  for (int i = tid; i < 1024; i += 256) {
    const int d = i >> 4, q = i & 15;
    float4 v = *(const float4*)&xz[(size_t)(d0 + d) * SEQ + l0 + q * 4];
    xin[d][3 + q * 4 + 0] = v.x; xin[d][3 + q * 4 + 1] = v.y;
    xin[d][3 + q * 4 + 2] = v.z; xin[d][3 + q * 4 + 3] = v.w;
  }
  // halo (3 cols)
  if (tid < 192) {
    const int j = tid >> 6, d = tid & 63;
    const int l = l0 - 3 + j;
    xin[d][j] = (l >= 0) ? xz[(size_t)(d0 + d) * SEQ + l] : 0.f;
  }
  if (tid < 64) {
    cbS[tid] = cb[d0 + tid];
    float4 w = *(const float4*)&cw[(d0 + tid) * 4];
    cwS[tid][0] = w.x; cwS[tid][1] = w.y; cwS[tid][2] = w.z; cwS[tid][3] = w.w;
  }
  __syncthreads();

  for (int i = tid; i < 4096; i += 256) {
    const int d = i >> 6, l = i & 63;
    float a = cbS[d] + cwS[d][0] * xin[d][l] + cwS[d][1] * xin[d][l + 1] +
              cwS[d][2] * xin[d][l + 2] + cwS[d][3] * xin[d][l + 3];
    float v = a / (1.f + __expf(-a));
    xc[(size_t)(d0 + d) * SEQ + l0 + l] = v;
    To[d][l] = v;
  }
  __syncthreads();

  for (int i = tid; i < 4096; i += 256) {
    const int l = i >> 6, dd = i & 63;
    float v = To[dd][l];  // stride-65: conflict-free
    ushort h = f2bf(v);
    xcT_hi[(size_t)(l0 + l) * DIN + d0 + dd] = h;
    xcT_lo[(size_t)(l0 + l) * DIN + d0 + dd] = f2bf(v - bf2f(h));
  }
}

// Reduce 8 x_proj split-K slabs (192 x SEQ) -> dblS; emit B/C (l,n) tables.
__global__ __launch_bounds__(256) void reduce_dblS_kernel(const float* __restrict__ p,
                                                          float* __restrict__ o,
                                                          float* __restrict__ BT1,
                                                          float* __restrict__ CT1,
                                                          float* __restrict__ BT2,
                                                          float* __restrict__ CT2) {
  const int NE = 192 * SEQ;
  const int idx = blockIdx.x * 256 + threadIdx.x;
  float s = 0.f;
#pragma unroll
  for (int cc = 0; cc < 8; ++cc) s += p[(size_t)cc * NE + idx];
  o[idx] = s;
  const int k = idx >> 11, l = idx & (SEQ - 1);
  if (k >= 64 && k < 80)        BT1[l * NST + (k - 64)] = s;
  else if (k >= 80 && k < 96)   CT1[l * NST + (k - 80)] = s;
  else if (k >= 160 && k < 176) BT2[l * NST + (k - 160)] = s;
  else if (k >= 176)            CT2[l * NST + (k - 176)] = s;
}

// =====================================================================
// dt GEMM with fused softplus(dt+bias); output sp in (d,l) layout.
// =====================================================================
__global__ __launch_bounds__(256) void dt_gemm_kernel(const float* __restrict__ dbl1,
                                                      const float* __restrict__ dbl2,
                                                      const float* __restrict__ w1,
                                                      const float* __restrict__ w2,
                                                      const float* __restrict__ b1,
                                                      const float* __restrict__ b2,
                                                      float* __restrict__ o1,
                                                      float* __restrict__ o2) {
  const int br = blockIdx.z;
  const float* __restrict__ dbl = br ? dbl2 : dbl1;
  const float* __restrict__ W = br ? w2 : w1;
  const float* __restrict__ dtb = br ? b2 : b1;
  float* __restrict__ outp = br ? o2 : o1;
  const int l0 = blockIdx.x * 64, d0 = blockIdx.y * 64;
  __shared__ __align__(16) float Wt[64][68];
  __shared__ __align__(16) float Bs[64][68];
  const int tid = threadIdx.x;
  for (int i = tid; i < 4096; i += 256) {
    int a = i >> 6, b = i & 63;
    Wt[b][a] = W[(size_t)(d0 + a) * DTR + b];
    Bs[a][b] = dbl[(size_t)a * SEQ + l0 + b];
  }
  __syncthreads();
  const int tl_ = tid >> 4, td_ = tid & 15;
  float acc[4][4];  // [i: l][j: d]
#pragma unroll
  for (int i = 0; i < 4; ++i)
#pragma unroll
    for (int j = 0; j < 4; ++j) acc[i][j] = 0.f;
  for (int r = 0; r < 64; ++r) {
    float4 av = *(const float4*)&Bs[r][tl_ * 4];
    float4 bv = *(const float4*)&Wt[r][td_ * 4];
    float am[4] = {av.x, av.y, av.z, av.w};
    float bn[4] = {bv.x, bv.y, bv.z, bv.w};
#pragma unroll
    for (int i = 0; i < 4; ++i)
#pragma unroll
      for (int j = 0; j < 4; ++j) acc[i][j] = fmaf(am[i], bn[j], acc[i][j]);
  }
#pragma unroll
  for (int j = 0; j < 4; ++j) {
    const int dd = d0 + td_ * 4 + j;
    const float bias = dtb[dd];
    float4 w = make_float4(splus(acc[0][j] + bias), splus(acc[1][j] + bias),
                           splus(acc[2][j] + bias), splus(acc[3][j] + bias));
    *(float4*)&outp[(size_t)dd * SEQ + l0 + tl_ * 4] = w;
  }
}

// =====================================================================
// Chunked selective scan.  dA_n = exp(-k_n*sp); fast path when
// k_n = exp(A_log) == n+1 (true for this model): one exp + mul tree.
// =====================================================================
__global__ __launch_bounds__(256) void scan_phase_a(const float* __restrict__ xc,
                                                    const float* __restrict__ sp1p,
                                                    const float* __restrict__ sp2p,
                                                    const float* __restrict__ BT1,
                                                    const float* __restrict__ BT2,
                                                    const float* __restrict__ Al1,
                                                    const float* __restrict__ Al2,
                                                    float* __restrict__ hend,
                                                    float* __restrict__ Pend) {
  const int br = blockIdx.z;
  const float* __restrict__ spp = br ? sp2p : sp1p;
  const float* __restrict__ BT = br ? BT2 : BT1;
  const float* __restrict__ Al = br ? Al2 : Al1;
  const int c = blockIdx.y;
  const int t0 = c * CH;
  const int d = blockIdx.x * 256 + threadIdx.x;

  __shared__ __align__(16) float Bs[CH][NST];
  ((float4*)Bs)[threadIdx.x] = ((const float4*)&BT[t0 * NST])[threadIdx.x];
  __syncthreads();

  bool fast = true;
#pragma unroll
  for (int n = 0; n < NST; ++n) {
    float kx = __expf(Al[(size_t)d * NST + n]);
    fast = fast && (fabsf(kx - (float)(n + 1)) < 1e-3f);
  }
  float h[NST];
#pragma unroll
  for (int n = 0; n < NST; ++n) h[n] = 0.f;
  float S = 0.f;

  if (fast) {
    for (int tt = 0; tt < CH / 4; ++tt) {
      float4 sp4 = *(const float4*)&spp[(size_t)d * SEQ + t0 + tt * 4];
      float4 u4 = *(const float4*)&xc[(size_t)d * SEQ + t0 + tt * 4];
      float sparr[4] = {sp4.x, sp4.y, sp4.z, sp4.w};
      float uarr[4] = {u4.x, u4.y, u4.z, u4.w};
#pragma unroll
      for (int j = 0; j < 4; ++j) {
        const int t = tt * 4 + j;
        const float sp = sparr[j];
        S += sp;
        const float spu = sp * uarr[j];
        const float e = __expf(-sp);
        float p[NST];
        powers16(e, p);
#pragma unroll
        for (int ng = 0; ng < 4; ++ng) {
          float4 bq = *(const float4*)&Bs[t][ng * 4];
          float bf[4] = {bq.x, bq.y, bq.z, bq.w};
#pragma unroll
          for (int k = 0; k < 4; ++k) {
            int n = ng * 4 + k;
            h[n] = fmaf(p[n], h[n], spu * bf[k]);
          }
        }
      }
    }
  } else {
    float AnL2[NST];
#pragma unroll
    for (int n = 0; n < NST; ++n)
      AnL2[n] = -__expf(Al[(size_t)d * NST + n]) * 1.4426950408889634f;
    for (int tt = 0; tt < CH / 4; ++tt) {
      float4 sp4 = *(const float4*)&spp[(size_t)d * SEQ + t0 + tt * 4];
      float4 u4 = *(const float4*)&xc[(size_t)d * SEQ + t0 + tt * 4];
      float sparr[4] = {sp4.x, sp4.y, sp4.z, sp4.w};
      float uarr[4] = {u4.x, u4.y, u4.z, u4.w};
#pragma unroll
      for (int j = 0; j < 4; ++j) {
        const int t = tt * 4 + j;
        const float sp = sparr[j];
        S += sp;
        const float spu = sp * uarr[j];
#pragma unroll
        for (int ng = 0; ng < 4; ++ng) {
          float4 bq = *(const float4*)&Bs[t][ng * 4];
          float bf[4] = {bq.x, bq.y, bq.z, bq.w};
#pragma unroll
          for (int k = 0; k < 4; ++k) {
            int n = ng * 4 + k;
            float dA = exp2f(AnL2[n] * sp);
            h[n] = fmaf(dA, h[n], spu * bf[k]);
          }
        }
      }
    }
  }

  float P[NST];
  if (fast) {
    powers16(__expf(-S), P);
  } else {
#pragma unroll
    for (int n = 0; n < NST; ++n)
      P[n] = exp2f(-__expf(Al[(size_t)d * NST + n]) * 1.4426950408889634f * S);
  }
  size_t base = ((size_t)(br * NCH + c) * DIN + d) * NST;
#pragma unroll
  for (int n = 0; n < NST; n += 4) {
    *(float4*)&hend[base + n] = make_float4(h[n], h[n + 1], h[n + 2], h[n + 3]);
    *(float4*)&Pend[base + n] = make_float4(P[n], P[n + 1], P[n + 2], P[n + 3]);
  }
}

// Carry across chunks; hin overwrites Pend in place (read P first).
__global__ __launch_bounds__(256) void scan_carry(const float* __restrict__ hend,
                                                  float* __restrict__ PendHin) {
  const int flat = blockIdx.x * 256 + threadIdx.x;
  const int br = flat >> 15;
  const int dn = flat & 32767;
  float h = 0.f;
  for (int c = 0; c < NCH; ++c) {
    size_t idx = ((size_t)(br * NCH + c) << 15) + dn;
    float Pv = PendHin[idx];
    float he = hend[idx];
    PendHin[idx] = h;
    h = fmaf(Pv, h, he);
  }
}

__global__ __launch_bounds__(256) void scan_phase_c(const float* __restrict__ xc,
                                                    const float* __restrict__ xz,
                                                    const float* __restrict__ sp1p,
                                                    const float* __restrict__ sp2p,
                                                    const float* __restrict__ BT1,
                                                    const float* __restrict__ CT1,
                                                    const float* __restrict__ BT2,
                                                    const float* __restrict__ CT2,
                                                    const float* __restrict__ Al1,
                                                    const float* __restrict__ Al2,
                                                    const float* __restrict__ D1,
                                                    const float* __restrict__ D2,
                                                    const float* __restrict__ hin,
                                                    float* __restrict__ y1t,
                                                    float* __restrict__ y2t) {
  const int br = blockIdx.z;
  const float* __restrict__ spp = br ? sp2p : sp1p;
  const float* __restrict__ BT = br ? BT2 : BT1;
  const float* __restrict__ CT = br ? CT2 : CT1;
  const float* __restrict__ Al = br ? Al2 : Al1;
  const float* __restrict__ Dp = br ? D2 : D1;
  float* __restrict__ yt = br ? y2t : y1t;
  const int c = blockIdx.y;
  const int t0 = c * CH;
  const int d = blockIdx.x * 256 + threadIdx.x;

  __shared__ __align__(16) float Bs[CH][NST];
  __shared__ __align__(16) float Cs[CH][NST];
  ((float4*)Bs)[threadIdx.x] = ((const float4*)&BT[t0 * NST])[threadIdx.x];
  ((float4*)Cs)[threadIdx.x] = ((const float4*)&CT[t0 * NST])[threadIdx.x];
  __syncthreads();

  bool fast = true;
#pragma unroll
  for (int n = 0; n < NST; ++n) {
    float kx = __expf(Al[(size_t)d * NST + n]);
    fast = fast && (fabsf(kx - (float)(n + 1)) < 1e-3f);
  }
  const float Dd = Dp[d];
  float h[NST];
  const size_t hbase = ((size_t)(br * NCH + c) * DIN + d) * NST;
#pragma unroll
  for (int n = 0; n < NST; n += 4) {
    float4 hv = *(const float4*)&hin[hbase + n];
    h[n] = hv.x; h[n + 1] = hv.y; h[n + 2] = hv.z; h[n + 3] = hv.w;
  }

  if (fast) {
    for (int tt = 0; tt < CH / 4; ++tt) {
      float4 sp4 = *(const float4*)&spp[(size_t)d * SEQ + t0 + tt * 4];
      float4 u4 = *(const float4*)&xc[(size_t)d * SEQ + t0 + tt * 4];
      float4 z4 = *(const float4*)&xz[(size_t)(DIN + d) * SEQ + t0 + tt * 4];
      float sparr[4] = {sp4.x, sp4.y, sp4.z, sp4.w};
      float uarr[4] = {u4.x, u4.y, u4.z, u4.w};
      float zarr[4] = {z4.x, z4.y, z4.z, z4.w};
#pragma unroll
      for (int j = 0; j < 4; ++j) {
        const int t = tt * 4 + j;
        const float sp = sparr[j];
        const float spu = sp * uarr[j];
        const float e = __expf(-sp);
        float p[NST];
        powers16(e, p);
        float y = 0.f;
#pragma unroll
        for (int ng = 0; ng < 4; ++ng) {
          float4 bq = *(const float4*)&Bs[t][ng * 4];
          float4 cq = *(const float4*)&Cs[t][ng * 4];
          float bf[4] = {bq.x, bq.y, bq.z, bq.w};
          float cf[4] = {cq.x, cq.y, cq.z, cq.w};
#pragma unroll
          for (int k = 0; k < 4; ++k) {
            int n = ng * 4 + k;
            h[n] = fmaf(p[n], h[n], spu * bf[k]);
            y = fmaf(h[n], cf[k], y);
          }
        }
        const float zz = zarr[j];
        const float sz = zz / (1.f + __expf(-zz));
        yt[(size_t)(t0 + t) * DIN + d] = (y + Dd * uarr[j]) * sz;
      }
    }
  } else {
    float AnL2[NST];
#pragma unroll
    for (int n = 0; n < NST; ++n)
      AnL2[n] = -__expf(Al[(size_t)d * NST + n]) * 1.4426950408889634f;
    for (int tt = 0; tt < CH / 4; ++tt) {
      float4 sp4 = *(const float4*)&spp[(size_t)d * SEQ + t0 + tt * 4];
      float4 u4 = *(const float4*)&xc[(size_t)d * SEQ + t0 + tt * 4];
      float4 z4 = *(const float4*)&xz[(size_t)(DIN + d) * SEQ + t0 + tt * 4];
      float sparr[4] = {sp4.x, sp4.y, sp4.z, sp4.w};
      float uarr[4] = {u4.x, u4.y, u4.z, u4.w};
      float zarr[4] = {z4.x, z4.y, z4.z, z4.w};
#pragma unroll
      for (int j = 0; j < 4; ++j) {
        const int t = tt * 4 + j;
        const float sp = sparr[j];
        const float spu = sp * uarr[j];
        float y = 0.f;
#pragma unroll
        for (int ng = 0; ng < 4; ++ng) {
          float4 bq = *(const float4*)&Bs[t][ng * 4];
          float4 cq = *(const float4*)&Cs[t][ng * 4];
          float bf[4] = {bq.x, bq.y, bq.z, bq.w};
          float cf[4] = {cq.x, cq.y, cq.z, cq.w};
#pragma unroll
          for (int k = 0; k < 4; ++k) {
            int n = ng * 4 + k;
            float dA = exp2f(AnL2[n] * sp);
            h[n] = fmaf(dA, h[n], spu * bf[k]);
            y = fmaf(h[n], cf[k], y);
          }
        }
        const float zz = zarr[j];
        const float sz = zz / (1.f + __expf(-zz));
        yt[(size_t)(t0 + t) * DIN + d] = (y + Dd * uarr[j]) * sz;
      }
    }
  }
}

// =====================================================================
extern "C" void kernel_launch(void* const* d_in, const int* in_sizes, int n_in,
                              void* d_out, int out_size, void* d_ws, size_t ws_size,
                              hipStream_t stream) {
  const float* hidden = (const float*)d_in[0];
  const float* in_proj_w = (const float*)d_in[1];
  const float* conv_w = (const float*)d_in[2];
  const float* conv_b = (const float*)d_in[3];
  const float* x1w = (const float*)d_in[4];
  const float* dtw1 = (const float*)d_in[5];
  const float* dtb1 = (const float*)d_in[6];
  const float* Al1 = (const float*)d_in[7];
  const float* D1 = (const float*)d_in[8];
  const float* x2w = (const float*)d_in[9];
  const float* dtw2 = (const float*)d_in[10];
  const float* dtb2 = (const float*)d_in[11];
  const float* Al2 = (const float*)d_in[12];
  const float* D2 = (const float*)d_in[13];
  const float* outw = (const float*)d_in[14];
  float* out = (float*)d_out;

  // Workspace layout (floats), ~137.9 MB (< proven 144.2 MB).
  float* ws = (float*)d_ws;
  float* xz = ws;                                  // 8.39M
  float* xc = xz + (size_t)4096 * SEQ;             // 4.19M
  float* dblS = xc + (size_t)DIN * SEQ;            // 192*2048 = 393K (both branches)
  float* sp1p = dblS + (size_t)192 * SEQ;          // 4.19M
  float* sp2p = sp1p + (size_t)SEQ * DIN;          // 4.19M
  float* y1t = sp2p + (size_t)SEQ * DIN;           // 4.19M  (l,d)
  float* y2t = y1t + (size_t)SEQ * DIN;            // 4.19M
  float* hend = y2t + (size_t)SEQ * DIN;           // 2.10M
  float* Pend = hend + (size_t)2 * NCH * DIN * NST;// 2.10M (reused as hin)
  float* BT1 = Pend + (size_t)2 * NCH * DIN * NST; // 32K each
  float* CT1 = BT1 + (size_t)SEQ * NST;
  float* BT2 = CT1 + (size_t)SEQ * NST;
  float* CT2 = BT2 + (size_t)SEQ * NST;
  float* wxp = CT2 + (size_t)SEQ * NST;            // 393K: stacked x_proj W planes

  float* dbl1 = dblS;                              // rows 0..95 (br1)
  float* dbl2 = dblS + (size_t)96 * SEQ;           // rows 96..191 (br2)

  // Aliases (lifetime-disjoint):
  ushort* w_hi = (ushort*)y1t;              // in_proj_w planes (dead after step 2)
  ushort* w_lo = (ushort*)(y1t + 2 * 1024 * 1024);
  ushort* h_hi = (ushort*)y2t;              // hidden planes (dead after step 2)
  ushort* h_lo = (ushort*)(y2t + 1024 * 1024);
  ushort* xcT_hi = (ushort*)y1t;            // xcT planes (steps 3-5; y1t written step 8)
  ushort* xcT_lo = (ushort*)(y1t + 2 * 1024 * 1024);
  ushort* wx_hi = (ushort*)wxp;             // stacked x_proj weights (192x2048)
  ushort* wx_lo = (ushort*)(wxp + (size_t)96 * SEQ);
  float* xp_part = sp1p;                    // 8 slabs x 192*2048 = 3.15M < 4.19M
  ushort* yd_hi = (ushort*)xc;              // ydiff planes (after xc dead)
  ushort* yd_lo = (ushort*)(xc + 2 * 1024 * 1024);
  ushort* ow_hi = (ushort*)hend;            // outw planes (after carry)
  ushort* ow_lo = (ushort*)(hend + 1024 * 1024);
  float* opart = sp1p;                      // out_proj split-K partials (8M)

  dim3 blk(256);

  // 1) split-convert in_proj_w and hidden
  cvt_split<<<dim3(4096), blk, 0, stream>>>(in_proj_w, w_hi, w_lo, 4096 * DMODEL);
  cvt_split<<<dim3(2048), blk, 0, stream>>>(hidden, h_hi, h_lo, SEQ * DMODEL);

  // 2) in_proj via 3-pass bf16 MFMA
  gemm3p<128, 128, 1><<<dim3(SEQ / 128, 4096 / 128, 1), blk, 0, stream>>>(
      w_hi, w_lo, h_hi, h_lo, xz, 4096, SEQ, DMODEL);

  // 3) conv + silu -> xc (d,l) AND xcT bf16 planes (l,d)
  conv_tr_kernel<<<dim3(SEQ / 64, DIN / 64), blk, 0, stream>>>(
      xz, conv_w, conv_b, xc, xcT_hi, xcT_lo);

  // 4) stacked x_proj weights -> bf16 planes; x_proj via MFMA, split-K=8
  cvt_split<<<dim3(192), blk, 0, stream>>>(x1w, wx_hi, wx_lo, 96 * DIN);
  cvt_split<<<dim3(192), blk, 0, stream>>>(x2w, wx_hi + (size_t)96 * DIN,
                                           wx_lo + (size_t)96 * DIN, 96 * DIN);
  gemm3p<64, 128, 8><<<dim3(SEQ / 128, 192 / 64, 8), blk, 0, stream>>>(
      wx_hi, wx_lo, xcT_hi, xcT_lo, xp_part, 192, SEQ, DIN);

  // 5) reduce slabs -> dblS + B/C transpose tables
  reduce_dblS_kernel<<<dim3(192 * SEQ / 256), blk, 0, stream>>>(
      xp_part, dblS, BT1, CT1, BT2, CT2);

  // 6) dt projection + fused softplus -> sp planes, (d,l)
  dt_gemm_kernel<<<dim3(SEQ / 64, DIN / 64, 2), blk, 0, stream>>>(
      dbl1, dbl2, dtw1, dtw2, dtb1, dtb2, sp1p, sp2p);

  // 7) chunked selective scan
  scan_phase_a<<<dim3(DIN / 256, NCH, 2), blk, 0, stream>>>(
      xc, sp1p, sp2p, BT1, BT2, Al1, Al2, hend, Pend);
  scan_carry<<<dim3(2 * DIN * NST / 256), blk, 0, stream>>>(hend, Pend);
  cvt_split<<<dim3(2048), blk, 0, stream>>>(outw, ow_hi, ow_lo, DMODEL * DIN);
  scan_phase_c<<<dim3(DIN / 256, NCH, 2), blk, 0, stream>>>(
      xc, xz, sp1p, sp2p, BT1, CT1, BT2, CT2, Al1, Al2, D1, D2, Pend, y1t, y2t);

  // 8) ydiff -> bf16 planes
  cvt_ydiff<<<dim3(4096), blk, 0, stream>>>(y1t, y2t, yd_hi, yd_lo, SEQ * DIN);

  // 9) out_proj via 3-pass bf16 MFMA, split-K=4
  gemm3p<128, 128, 4><<<dim3(DMODEL / 128, SEQ / 128, 4), blk, 0, stream>>>(
      yd_hi, yd_lo, ow_hi, ow_lo, opart, SEQ, DMODEL, DIN);
  reduce_out<<<dim3(SEQ * DMODEL / 1024), blk, 0, stream>>>(opart, out, SEQ * DMODEL);
}

// Round 7
// 358.718 us; speedup vs baseline: 3.2623x; 1.0274x over previous
//
#include <hip/hip_runtime.h>
#include <math.h>

#define SEQ 2048
#define DMODEL 1024
#define DIN 2048
#define NST 16
#define DTR 64
#define CH 64
#define NCH (SEQ / CH)

typedef __attribute__((ext_vector_type(8))) short bf16x8;
typedef __attribute__((ext_vector_type(4))) float f32x4;

__device__ __forceinline__ ushort f2bf(float f) {
  union { float f; unsigned u; } c; c.f = f;
  return (ushort)((c.u + 0x7fffu + ((c.u >> 16) & 1u)) >> 16);
}
__device__ __forceinline__ float bf2f(ushort h) {
  union { unsigned u; float f; } c; c.u = ((unsigned)h) << 16;
  return c.f;
}
__device__ __forceinline__ float splus(float v) {
  return v > 20.f ? v : log1pf(__expf(v));
}
// p[n] = e^(n+1), depth-4 mul tree (no transcendentals).
__device__ __forceinline__ void powers16(float e, float* p) {
  float e2 = e * e, e4 = e2 * e2, e8 = e4 * e4;
  p[0] = e;       p[1] = e2;       p[2] = e2 * e;   p[3] = e4;
  p[4] = e4 * e;  p[5] = e4 * e2;  p[6] = e4 * p[2]; p[7] = e8;
  p[8] = e8 * e;  p[9] = e8 * e2;  p[10] = e8 * p[2]; p[11] = e8 * e4;
  p[12] = e8 * p[4]; p[13] = e8 * p[5]; p[14] = e8 * p[6]; p[15] = e8 * e8;
}

#define GLL(g, l) __builtin_amdgcn_global_load_lds( \
    (const __attribute__((address_space(1))) void*)(g), \
    (__attribute__((address_space(3))) void*)(l), 16, 0, 0)

// =====================================================================
// Split-bf16 3-pass MFMA GEMM (fp32-accurate).  C[m,n]=sum_k A[m,k]B[n,k]
// LDS holds fragments LANE-ORDERED: lane L's 16B at seg*1024 + L*16
// (seg = 16 rows x 32 k).  Staging lane map matches the MFMA A/B operand
// order, so ds_read_b128 is perfectly linear -> zero bank conflicts.
// =====================================================================
template<int BM, int BN, int SPLITK>
__global__ __launch_bounds__(256) void gemm3p(const ushort* __restrict__ Ahi,
                                              const ushort* __restrict__ Alo,
                                              const ushort* __restrict__ Bhi,
                                              const ushort* __restrict__ Blo,
                                              float* __restrict__ C,
                                              int M, int N, int K) {
  constexpr int BK = 32;
  constexpr int WM = BM / 2, WN = BN / 2, TM = WM / 16, TN = WN / 16;
  constexpr int SA = BM / 16, SB = BN / 16;
  __shared__ __align__(16) ushort sAh[BM * BK], sAl[BM * BK];
  __shared__ __align__(16) ushort sBh[BN * BK], sBl[BN * BK];
  const int tid = threadIdx.x, wid = tid >> 6, lane = tid & 63;
  const int m0 = blockIdx.y * BM, n0 = blockIdx.x * BN;
  const int Kc = K / SPLITK, kbeg = blockIdx.z * Kc;
  const int wm0 = (wid >> 1) * WM, wn0 = (wid & 1) * WN;
  const int fr = lane & 15;
  const int lrow = lane & 15, lk = (lane >> 4) * 8;  // fragment-ordered staging

  f32x4 acc[TM][TN];
#pragma unroll
  for (int mi = 0; mi < TM; ++mi)
#pragma unroll
    for (int ni = 0; ni < TN; ++ni)
#pragma unroll
      for (int r = 0; r < 4; ++r) acc[mi][ni][r] = 0.f;

  for (int k0 = 0; k0 < Kc; k0 += BK) {
    __syncthreads();
    const int kg = kbeg + k0 + lk;
#pragma unroll
    for (int i = 0; i < SA / 4; ++i) {
      const int seg = wid * (SA / 4) + i;
      const size_t ga = (size_t)(m0 + seg * 16 + lrow) * K + kg;
      GLL(&Ahi[ga], &sAh[seg * 512]);
      GLL(&Alo[ga], &sAl[seg * 512]);
    }
#pragma unroll
    for (int i = 0; i < SB / 4; ++i) {
      const int seg = wid * (SB / 4) + i;
      const size_t ga = (size_t)(n0 + seg * 16 + lrow) * K + kg;
      GLL(&Bhi[ga], &sBh[seg * 512]);
      GLL(&Blo[ga], &sBl[seg * 512]);
    }
    __syncthreads();

    bf16x8 ah[TM], al[TM], bh[TN], bl[TN];
#pragma unroll
    for (int mi = 0; mi < TM; ++mi) {
      const int r = (wm0 / 16 + mi) * 512 + lane * 8;  // lane-ordered: conflict-free
      ah[mi] = *(const bf16x8*)&sAh[r];
      al[mi] = *(const bf16x8*)&sAl[r];
    }
#pragma unroll
    for (int ni = 0; ni < TN; ++ni) {
      const int r = (wn0 / 16 + ni) * 512 + lane * 8;
      bh[ni] = *(const bf16x8*)&sBh[r];
      bl[ni] = *(const bf16x8*)&sBl[r];
    }
#pragma unroll
    for (int mi = 0; mi < TM; ++mi)
#pragma unroll
      for (int ni = 0; ni < TN; ++ni) {
        acc[mi][ni] = __builtin_amdgcn_mfma_f32_16x16x32_bf16(ah[mi], bh[ni], acc[mi][ni], 0, 0, 0);
        acc[mi][ni] = __builtin_amdgcn_mfma_f32_16x16x32_bf16(ah[mi], bl[ni], acc[mi][ni], 0, 0, 0);
        acc[mi][ni] = __builtin_amdgcn_mfma_f32_16x16x32_bf16(al[mi], bh[ni], acc[mi][ni], 0, 0, 0);
      }
  }

  float* __restrict__ Co = C + (size_t)blockIdx.z * M * N;
#pragma unroll
  for (int mi = 0; mi < TM; ++mi)
#pragma unroll
    for (int ni = 0; ni < TN; ++ni)
#pragma unroll
      for (int r = 0; r < 4; ++r)
        Co[(size_t)(m0 + wm0 + mi * 16 + (lane >> 4) * 4 + r) * N + n0 + wn0 + ni * 16 + fr] =
            acc[mi][ni][r];
}

__device__ __forceinline__ void split_store4(float4 v, ushort* hi, ushort* lo, size_t i) {
  ushort h0 = f2bf(v.x), h1 = f2bf(v.y), h2 = f2bf(v.z), h3 = f2bf(v.w);
  *(ushort4*)&hi[i] = make_ushort4(h0, h1, h2, h3);
  *(ushort4*)&lo[i] = make_ushort4(f2bf(v.x - bf2f(h0)), f2bf(v.y - bf2f(h1)),
                                   f2bf(v.z - bf2f(h2)), f2bf(v.w - bf2f(h3)));
}

// One launch converting in_proj_w, hidden, x1w, x2w -> bf16 hi/lo planes.
__global__ __launch_bounds__(256) void cvt_fused(const float* __restrict__ inw,
                                                 const float* __restrict__ hid,
                                                 const float* __restrict__ x1w,
                                                 const float* __restrict__ x2w,
                                                 ushort* __restrict__ w_hi, ushort* __restrict__ w_lo,
                                                 ushort* __restrict__ h_hi, ushort* __restrict__ h_lo,
                                                 ushort* __restrict__ wx_hi, ushort* __restrict__ wx_lo) {
  const int q = blockIdx.x * 256 + threadIdx.x;  // float4 index
  const float* src; ushort* dhi; ushort* dlo; int base;
  if (q < 1048576)            { src = inw; dhi = w_hi;  dlo = w_lo;  base = q; }
  else if (q < 1572864)       { src = hid; dhi = h_hi;  dlo = h_lo;  base = q - 1048576; }
  else if (q < 1622016)       { src = x1w; dhi = wx_hi; dlo = wx_lo; base = q - 1572864; }
  else                        { src = x2w; dhi = wx_hi + 196608; dlo = wx_lo + 196608; base = q - 1622016; }
  const size_t i = (size_t)base * 4;
  split_store4(*(const float4*)&src[i], dhi, dlo, i);
}

__global__ __launch_bounds__(256) void cvt_split(const float* __restrict__ x,
                                                 ushort* __restrict__ hi,
                                                 ushort* __restrict__ lo, int n) {
  const int i = (blockIdx.x * 256 + threadIdx.x) * 4;
  if (i >= n) return;
  split_store4(*(const float4*)&x[i], hi, lo, i);
}

__global__ __launch_bounds__(256) void reduce_out(const float* __restrict__ p,
                                                  float* __restrict__ o, int n) {
  const int i = (blockIdx.x * 256 + threadIdx.x) * 4;
  if (i >= n) return;
  float4 a = *(const float4*)&p[i];
  float4 b = *(const float4*)&p[(size_t)n + i];
  float4 c = *(const float4*)&p[(size_t)2 * n + i];
  float4 d = *(const float4*)&p[(size_t)3 * n + i];
  *(float4*)&o[i] = make_float4(a.x + b.x + c.x + d.x, a.y + b.y + c.y + d.y,
                                a.z + b.z + c.z + d.z, a.w + b.w + c.w + d.w);
}

// =====================================================================
// Conv (w=4, causal) + bias + SiLU -> transposed bf16 hi/lo planes (l,d).
// =====================================================================
__global__ __launch_bounds__(256) void conv_tr_kernel(const float* __restrict__ xz,
                                                      const float* __restrict__ cw,
                                                      const float* __restrict__ cb,
                                                      ushort* __restrict__ xcT_hi,
                                                      ushort* __restrict__ xcT_lo) {
  const int l0 = blockIdx.x * 64, d0 = blockIdx.y * 64;
  const int tid = threadIdx.x;
  __shared__ float xin[64][68];  // cols 0..66 = l0-3 .. l0+63
  __shared__ float To[64][65];
  __shared__ float cwS[64][4];
  __shared__ float cbS[64];

  for (int i = tid; i < 1024; i += 256) {
    const int d = i >> 4, q = i & 15;
    float4 v = *(const float4*)&xz[(size_t)(d0 + d) * SEQ + l0 + q * 4];
    xin[d][3 + q * 4 + 0] = v.x; xin[d][3 + q * 4 + 1] = v.y;
    xin[d][3 + q * 4 + 2] = v.z; xin[d][3 + q * 4 + 3] = v.w;
  }
  if (tid < 192) {
    const int j = tid >> 6, d = tid & 63;
    const int l = l0 - 3 + j;
    xin[d][j] = (l >= 0) ? xz[(size_t)(d0 + d) * SEQ + l] : 0.f;
  }
  if (tid < 64) {
    cbS[tid] = cb[d0 + tid];
    float4 w = *(const float4*)&cw[(d0 + tid) * 4];
    cwS[tid][0] = w.x; cwS[tid][1] = w.y; cwS[tid][2] = w.z; cwS[tid][3] = w.w;
  }
  __syncthreads();

  for (int i = tid; i < 4096; i += 256) {
    const int d = i >> 6, l = i & 63;
    float a = cbS[d] + cwS[d][0] * xin[d][l] + cwS[d][1] * xin[d][l + 1] +
              cwS[d][2] * xin[d][l + 2] + cwS[d][3] * xin[d][l + 3];
    To[d][l] = a / (1.f + __expf(-a));
  }
  __syncthreads();

  for (int i = tid; i < 4096; i += 256) {
    const int l = i >> 6, dd = i & 63;
    float v = To[dd][l];  // stride-65: conflict-free
    ushort h = f2bf(v);
    xcT_hi[(size_t)(l0 + l) * DIN + d0 + dd] = h;
    xcT_lo[(size_t)(l0 + l) * DIN + d0 + dd] = f2bf(v - bf2f(h));
  }
}

// (y1raw - y2raw) * silu(z), tiled with LDS transpose of z; -> bf16 planes.
__global__ __launch_bounds__(256) void ydiff_tr_kernel(const float* __restrict__ y1,
                                                       const float* __restrict__ y2,
                                                       const float* __restrict__ xz,
                                                       ushort* __restrict__ hi,
                                                       ushort* __restrict__ lo) {
  const int l0 = blockIdx.x * 64, d0 = blockIdx.y * 64;
  const int tid = threadIdx.x;
  __shared__ float Tz[64][65];
  for (int i = tid; i < 1024; i += 256) {
    const int d = i >> 4, q = i & 15;
    float4 v = *(const float4*)&xz[(size_t)(DIN + d0 + d) * SEQ + l0 + q * 4];
    Tz[d][q * 4 + 0] = v.x / (1.f + __expf(-v.x));
    Tz[d][q * 4 + 1] = v.y / (1.f + __expf(-v.y));
    Tz[d][q * 4 + 2] = v.z / (1.f + __expf(-v.z));
    Tz[d][q * 4 + 3] = v.w / (1.f + __expf(-v.w));
  }
  __syncthreads();
  for (int i = tid; i < 1024; i += 256) {
    const int l = i >> 4, dc = (i & 15) * 4;
    const size_t g = (size_t)(l0 + l) * DIN + d0 + dc;
    float4 a = *(const float4*)&y1[g];
    float4 b = *(const float4*)&y2[g];
    float4 v = make_float4((a.x - b.x) * Tz[dc + 0][l], (a.y - b.y) * Tz[dc + 1][l],
                           (a.z - b.z) * Tz[dc + 2][l], (a.w - b.w) * Tz[dc + 3][l]);
    split_store4(v, hi, lo, g);
  }
}

// Reduce 8 x_proj split-K slabs (192 x SEQ) -> dblS; emit B/C (l,n) tables.
__global__ __launch_bounds__(256) void reduce_dblS_kernel(const float* __restrict__ p,
                                                          float* __restrict__ o,
                                                          float* __restrict__ BT1,
                                                          float* __restrict__ CT1,
                                                          float* __restrict__ BT2,
                                                          float* __restrict__ CT2) {
  const int NE = 192 * SEQ;
  const int idx = blockIdx.x * 256 + threadIdx.x;
  float s = 0.f;
#pragma unroll
  for (int cc = 0; cc < 8; ++cc) s += p[(size_t)cc * NE + idx];
  o[idx] = s;
  const int k = idx >> 11, l = idx & (SEQ - 1);
  if (k >= 64 && k < 80)        BT1[l * NST + (k - 64)] = s;
  else if (k >= 80 && k < 96)   CT1[l * NST + (k - 80)] = s;
  else if (k >= 160 && k < 176) BT2[l * NST + (k - 160)] = s;
  else if (k >= 176)            CT2[l * NST + (k - 176)] = s;
}

// =====================================================================
// dt GEMM + fused softplus(dt+bias); output sp in (l,d) layout (coalesced
// for the scan's per-timestep reads).
// =====================================================================
__global__ __launch_bounds__(256) void dt_gemm_kernel(const float* __restrict__ dbl1,
                                                      const float* __restrict__ dbl2,
                                                      const float* __restrict__ w1,
                                                      const float* __restrict__ w2,
                                                      const float* __restrict__ b1,
                                                      const float* __restrict__ b2,
                                                      float* __restrict__ o1,
                                                      float* __restrict__ o2) {
  const int br = blockIdx.z;
  const float* __restrict__ dbl = br ? dbl2 : dbl1;
  const float* __restrict__ W = br ? w2 : w1;
  const float* __restrict__ dtb = br ? b2 : b1;
  float* __restrict__ outp = br ? o2 : o1;
  const int l0 = blockIdx.x * 64, d0 = blockIdx.y * 64;
  __shared__ __align__(16) float Wt[64][68];
  __shared__ __align__(16) float Bs[64][68];
  const int tid = threadIdx.x;
  for (int i = tid; i < 4096; i += 256) {
    int a = i >> 6, b = i & 63;
    Wt[b][a] = W[(size_t)(d0 + a) * DTR + b];
    Bs[a][b] = dbl[(size_t)a * SEQ + l0 + b];
  }
  __syncthreads();
  const int tl_ = tid >> 4, td_ = tid & 15;
  float acc[4][4];  // [i: l][j: d]
#pragma unroll
  for (int i = 0; i < 4; ++i)
#pragma unroll
    for (int j = 0; j < 4; ++j) acc[i][j] = 0.f;
  for (int r = 0; r < 64; ++r) {
    float4 av = *(const float4*)&Bs[r][tl_ * 4];
    float4 bv = *(const float4*)&Wt[r][td_ * 4];
    float am[4] = {av.x, av.y, av.z, av.w};
    float bn[4] = {bv.x, bv.y, bv.z, bv.w};
#pragma unroll
    for (int i = 0; i < 4; ++i)
#pragma unroll
      for (int j = 0; j < 4; ++j) acc[i][j] = fmaf(am[i], bn[j], acc[i][j]);
  }
  const float4 bias4 = *(const float4*)&dtb[d0 + td_ * 4];
#pragma unroll
  for (int i = 0; i < 4; ++i) {
    float4 w = make_float4(splus(acc[i][0] + bias4.x), splus(acc[i][1] + bias4.y),
                           splus(acc[i][2] + bias4.z), splus(acc[i][3] + bias4.w));
    *(float4*)&outp[(size_t)(l0 + tl_ * 4 + i) * DIN + d0 + td_ * 4] = w;
  }
}

// =====================================================================
// Chunked selective scan.  All per-timestep inputs in (l,d) layout ->
// coalesced scalar loads.  u = hi+lo bf16 reconstruction (2^-18 exact).
// dA_n = exp(-k_n*sp); fast path when k_n == n+1 (one exp + mul tree).
// =====================================================================
__global__ __launch_bounds__(256) void scan_phase_a(const ushort* __restrict__ uhi,
                                                    const ushort* __restrict__ ulo,
                                                    const float* __restrict__ sp1T,
                                                    const float* __restrict__ sp2T,
                                                    const float* __restrict__ BT1,
                                                    const float* __restrict__ BT2,
                                                    const float* __restrict__ Al1,
                                                    const float* __restrict__ Al2,
                                                    float* __restrict__ hend,
                                                    float* __restrict__ Pend) {
  const int br = blockIdx.z;
  const float* __restrict__ spp = br ? sp2T : sp1T;
  const float* __restrict__ BT = br ? BT2 : BT1;
  const float* __restrict__ Al = br ? Al2 : Al1;
  const int c = blockIdx.y;
  const int t0 = c * CH;
  const int d = blockIdx.x * 256 + threadIdx.x;
  const size_t gbase = (size_t)t0 * DIN + d;

  __shared__ __align__(16) float Bs[CH][NST];
  ((float4*)Bs)[threadIdx.x] = ((const float4*)&BT[t0 * NST])[threadIdx.x];
  __syncthreads();

  bool fast = true;
#pragma unroll
  for (int n = 0; n < NST; ++n) {
    float kx = __expf(Al[(size_t)d * NST + n]);
    fast = fast && (fabsf(kx - (float)(n + 1)) < 1e-3f);
  }
  float h[NST];
#pragma unroll
  for (int n = 0; n < NST; ++n) h[n] = 0.f;
  float S = 0.f;

  if (fast) {
    for (int tt = 0; tt < CH / 4; ++tt) {
      float sparr[4], uarr[4];
#pragma unroll
      for (int j = 0; j < 4; ++j) {
        const size_t idx = gbase + (size_t)(tt * 4 + j) * DIN;
        sparr[j] = spp[idx];
        uarr[j] = bf2f(uhi[idx]) + bf2f(ulo[idx]);
      }
#pragma unroll
      for (int j = 0; j < 4; ++j) {
        const int t = tt * 4 + j;
        const float sp = sparr[j];
        S += sp;
        const float spu = sp * uarr[j];
        const float e = __expf(-sp);
        float p[NST];
        powers16(e, p);
#pragma unroll
        for (int ng = 0; ng < 4; ++ng) {
          float4 bq = *(const float4*)&Bs[t][ng * 4];
          float bf[4] = {bq.x, bq.y, bq.z, bq.w};
#pragma unroll
          for (int k = 0; k < 4; ++k) {
            int n = ng * 4 + k;
            h[n] = fmaf(p[n], h[n], spu * bf[k]);
          }
        }
      }
    }
  } else {
    float AnL2[NST];
#pragma unroll
    for (int n = 0; n < NST; ++n)
      AnL2[n] = -__expf(Al[(size_t)d * NST + n]) * 1.4426950408889634f;
    for (int tt = 0; tt < CH / 4; ++tt) {
      float sparr[4], uarr[4];
#pragma unroll
      for (int j = 0; j < 4; ++j) {
        const size_t idx = gbase + (size_t)(tt * 4 + j) * DIN;
        sparr[j] = spp[idx];
        uarr[j] = bf2f(uhi[idx]) + bf2f(ulo[idx]);
      }
#pragma unroll
      for (int j = 0; j < 4; ++j) {
        const int t = tt * 4 + j;
        const float sp = sparr[j];
        S += sp;
        const float spu = sp * uarr[j];
#pragma unroll
        for (int ng = 0; ng < 4; ++ng) {
          float4 bq = *(const float4*)&Bs[t][ng * 4];
          float bf[4] = {bq.x, bq.y, bq.z, bq.w};
#pragma unroll
          for (int k = 0; k < 4; ++k) {
            int n = ng * 4 + k;
            float dA = exp2f(AnL2[n] * sp);
            h[n] = fmaf(dA, h[n], spu * bf[k]);
          }
        }
      }
    }
  }

  float P[NST];
  if (fast) {
    powers16(__expf(-S), P);
  } else {
#pragma unroll
    for (int n = 0; n < NST; ++n)
      P[n] = exp2f(-__expf(Al[(size_t)d * NST + n]) * 1.4426950408889634f * S);
  }
  size_t base = ((size_t)(br * NCH + c) * DIN + d) * NST;
#pragma unroll
  for (int n = 0; n < NST; n += 4) {
    *(float4*)&hend[base + n] = make_float4(h[n], h[n + 1], h[n + 2], h[n + 3]);
    *(float4*)&Pend[base + n] = make_float4(P[n], P[n + 1], P[n + 2], P[n + 3]);
  }
}

// Carry across chunks; hin overwrites Pend in place (read P first).
__global__ __launch_bounds__(256) void scan_carry(const float* __restrict__ hend,
                                                  float* __restrict__ PendHin) {
  const int flat = blockIdx.x * 256 + threadIdx.x;
  const int br = flat >> 15;
  const int dn = flat & 32767;
  float h = 0.f;
  for (int c = 0; c < NCH; ++c) {
    size_t idx = ((size_t)(br * NCH + c) << 15) + dn;
    float Pv = PendHin[idx];
    float he = hend[idx];
    PendHin[idx] = h;
    h = fmaf(Pv, h, he);
  }
}

// Phase C: raw y (silu(z) applied later in ydiff_tr), (l,d) writes.
__global__ __launch_bounds__(256) void scan_phase_c(const ushort* __restrict__ uhi,
                                                    const ushort* __restrict__ ulo,
                                                    const float* __restrict__ sp1T,
                                                    const float* __restrict__ sp2T,
                                                    const float* __restrict__ BT1,
                                                    const float* __restrict__ CT1,
                                                    const float* __restrict__ BT2,
                                                    const float* __restrict__ CT2,
                                                    const float* __restrict__ Al1,
                                                    const float* __restrict__ Al2,
                                                    const float* __restrict__ D1,
                                                    const float* __restrict__ D2,
                                                    const float* __restrict__ hin,
                                                    float* __restrict__ y1t,
                                                    float* __restrict__ y2t) {
  const int br = blockIdx.z;
  const float* __restrict__ spp = br ? sp2T : sp1T;
  const float* __restrict__ BT = br ? BT2 : BT1;
  const float* __restrict__ CT = br ? CT2 : CT1;
  const float* __restrict__ Al = br ? Al2 : Al1;
  const float* __restrict__ Dp = br ? D2 : D1;
  float* __restrict__ yt = br ? y2t : y1t;
  const int c = blockIdx.y;
  const int t0 = c * CH;
  const int d = blockIdx.x * 256 + threadIdx.x;
  const size_t gbase = (size_t)t0 * DIN + d;

  __shared__ __align__(16) float Bs[CH][NST];
  __shared__ __align__(16) float Cs[CH][NST];
  ((float4*)Bs)[threadIdx.x] = ((const float4*)&BT[t0 * NST])[threadIdx.x];
  ((float4*)Cs)[threadIdx.x] = ((const float4*)&CT[t0 * NST])[threadIdx.x];
  __syncthreads();

  bool fast = true;
#pragma unroll
  for (int n = 0; n < NST; ++n) {
    float kx = __expf(Al[(size_t)d * NST + n]);
    fast = fast && (fabsf(kx - (float)(n + 1)) < 1e-3f);
  }
  const float Dd = Dp[d];
  float h[NST];
  const size_t hbase = ((size_t)(br * NCH + c) * DIN + d) * NST;
#pragma unroll
  for (int n = 0; n < NST; n += 4) {
    float4 hv = *(const float4*)&hin[hbase + n];
    h[n] = hv.x; h[n + 1] = hv.y; h[n + 2] = hv.z; h[n + 3] = hv.w;
  }

  if (fast) {
    for (int tt = 0; tt < CH / 4; ++tt) {
      float sparr[4], uarr[4];
#pragma unroll
      for (int j = 0; j < 4; ++j) {
        const size_t idx = gbase + (size_t)(tt * 4 + j) * DIN;
        sparr[j] = spp[idx];
        uarr[j] = bf2f(uhi[idx]) + bf2f(ulo[idx]);
      }
#pragma unroll
      for (int j = 0; j < 4; ++j) {
        const int t = tt * 4 + j;
        const float sp = sparr[j];
        const float spu = sp * uarr[j];
        const float e = __expf(-sp);
        float p[NST];
        powers16(e, p);
        float y = 0.f;
#pragma unroll
        for (int ng = 0; ng < 4; ++ng) {
          float4 bq = *(const float4*)&Bs[t][ng * 4];
          float4 cq = *(const float4*)&Cs[t][ng * 4];
          float bf[4] = {bq.x, bq.y, bq.z, bq.w};
          float cf[4] = {cq.x, cq.y, cq.z, cq.w};
#pragma unroll
          for (int k = 0; k < 4; ++k) {
            int n = ng * 4 + k;
            h[n] = fmaf(p[n], h[n], spu * bf[k]);
            y = fmaf(h[n], cf[k], y);
          }
        }
        yt[gbase + (size_t)t * DIN] = y + Dd * uarr[j];
      }
    }
  } else {
    float AnL2[NST];
#pragma unroll
    for (int n = 0; n < NST; ++n)
      AnL2[n] = -__expf(Al[(size_t)d * NST + n]) * 1.4426950408889634f;
    for (int tt = 0; tt < CH / 4; ++tt) {
      float sparr[4], uarr[4];
#pragma unroll
      for (int j = 0; j < 4; ++j) {
        const size_t idx = gbase + (size_t)(tt * 4 + j) * DIN;
        sparr[j] = spp[idx];
        uarr[j] = bf2f(uhi[idx]) + bf2f(ulo[idx]);
      }
#pragma unroll
      for (int j = 0; j < 4; ++j) {
        const int t = tt * 4 + j;
        const float sp = sparr[j];
        const float spu = sp * uarr[j];
        float y = 0.f;
#pragma unroll
        for (int ng = 0; ng < 4; ++ng) {
          float4 bq = *(const float4*)&Bs[t][ng * 4];
          float4 cq = *(const float4*)&Cs[t][ng * 4];
          float bf[4] = {bq.x, bq.y, bq.z, bq.w};
          float cf[4] = {cq.x, cq.y, cq.z, cq.w};
#pragma unroll
          for (int k = 0; k < 4; ++k) {
            int n = ng * 4 + k;
            float dA = exp2f(AnL2[n] * sp);
            h[n] = fmaf(dA, h[n], spu * bf[k]);
            y = fmaf(h[n], cf[k], y);
          }
        }
        yt[gbase + (size_t)t * DIN] = y + Dd * uarr[j];
      }
    }
  }
}

// =====================================================================
extern "C" void kernel_launch(void* const* d_in, const int* in_sizes, int n_in,
                              void* d_out, int out_size, void* d_ws, size_t ws_size,
                              hipStream_t stream) {
  const float* hidden = (const float*)d_in[0];
  const float* in_proj_w = (const float*)d_in[1];
  const float* conv_w = (const float*)d_in[2];
  const float* conv_b = (const float*)d_in[3];
  const float* x1w = (const float*)d_in[4];
  const float* dtw1 = (const float*)d_in[5];
  const float* dtb1 = (const float*)d_in[6];
  const float* Al1 = (const float*)d_in[7];
  const float* D1 = (const float*)d_in[8];
  const float* x2w = (const float*)d_in[9];
  const float* dtw2 = (const float*)d_in[10];
  const float* dtb2 = (const float*)d_in[11];
  const float* Al2 = (const float*)d_in[12];
  const float* D2 = (const float*)d_in[13];
  const float* outw = (const float*)d_in[14];
  float* out = (float*)d_out;

  // Workspace layout (floats), 34.47M = 137.9 MB (same as proven round 5).
  float* ws = (float*)d_ws;
  float* xz = ws;                                   // 8.39M  (x rows, z rows)
  float* xcTbuf = xz + (size_t)4096 * SEQ;          // 4.19M  xcT bf16 hi/lo planes
  float* dblS = xcTbuf + (size_t)SEQ * DIN;         // 393K
  float* sp1T = dblS + (size_t)192 * SEQ;           // 4.19M  softplus'd dt, (l,d)
  float* sp2T = sp1T + (size_t)SEQ * DIN;           // 4.19M
  float* y1t = sp2T + (size_t)SEQ * DIN;            // 4.19M  (l,d) raw y
  float* y2t = y1t + (size_t)SEQ * DIN;             // 4.19M
  float* hend = y2t + (size_t)SEQ * DIN;            // 2.10M
  float* Pend = hend + (size_t)2 * NCH * DIN * NST; // 2.10M (reused as hin)
  float* BT1 = Pend + (size_t)2 * NCH * DIN * NST;  // 32K each
  float* CT1 = BT1 + (size_t)SEQ * NST;
  float* BT2 = CT1 + (size_t)SEQ * NST;
  float* CT2 = BT2 + (size_t)SEQ * NST;
  float* wxp = CT2 + (size_t)SEQ * NST;             // 393K stacked x_proj W planes

  float* dbl1 = dblS;
  float* dbl2 = dblS + (size_t)96 * SEQ;

  // Aliases (lifetime-disjoint):
  ushort* xcT_hi = (ushort*)xcTbuf;                 // steps 3..7
  ushort* xcT_lo = (ushort*)(xcTbuf + 2097152);
  ushort* w_hi = (ushort*)y1t;                      // in_proj_w planes (dead after step 2)
  ushort* w_lo = (ushort*)(y1t + 2097152);
  ushort* h_hi = (ushort*)y2t;                      // hidden planes (dead after step 2)
  ushort* h_lo = (ushort*)(y2t + 1048576);
  ushort* wx_hi = (ushort*)wxp;                     // stacked x_proj weights 192x2048
  ushort* wx_lo = (ushort*)(wxp + 196608);
  float* xp_part = sp1T;                            // 8 slabs x 192*2048 = 3.15M < 4.19M
  ushort* yd_hi = (ushort*)xcTbuf;                  // ydiff planes (xcT dead after phase C)
  ushort* yd_lo = (ushort*)(xcTbuf + 2097152);
  // outw planes fit EXACTLY inside hend's 2.10M floats (1.05M floats each).
  // (Round-6 bug: ow_lo at hend+2097152 clobbered Pend/hin between carry and
  // phase C.  Must stay within hend.)
  ushort* ow_hi = (ushort*)hend;
  ushort* ow_lo = (ushort*)(hend + 1048576);
  float* opart = xz;                                // out_proj split-K partials (xz dead after ydiff)

  dim3 blk(256);

  // 1) fused split-convert: in_proj_w, hidden, x1w, x2w
  cvt_fused<<<dim3(6528), blk, 0, stream>>>(in_proj_w, hidden, x1w, x2w,
                                            w_hi, w_lo, h_hi, h_lo, wx_hi, wx_lo);

  // 2) in_proj via 3-pass bf16 MFMA -> xz (e,l)
  gemm3p<128, 128, 1><<<dim3(SEQ / 128, 4096 / 128, 1), blk, 0, stream>>>(
      w_hi, w_lo, h_hi, h_lo, xz, 4096, SEQ, DMODEL);

  // 3) conv + silu -> xcT bf16 hi/lo planes (l,d)
  conv_tr_kernel<<<dim3(SEQ / 64, DIN / 64), blk, 0, stream>>>(
      xz, conv_w, conv_b, xcT_hi, xcT_lo);

  // 4) x_proj via MFMA, split-K=8 (both branches stacked, M=192)
  gemm3p<64, 128, 8><<<dim3(SEQ / 128, 192 / 64, 8), blk, 0, stream>>>(
      wx_hi, wx_lo, xcT_hi, xcT_lo, xp_part, 192, SEQ, DIN);

  // 5) reduce slabs -> dblS + B/C transpose tables
  reduce_dblS_kernel<<<dim3(192 * SEQ / 256), blk, 0, stream>>>(
      xp_part, dblS, BT1, CT1, BT2, CT2);

  // 6) dt projection + fused softplus -> sp planes, (l,d)
  dt_gemm_kernel<<<dim3(SEQ / 64, DIN / 64, 2), blk, 0, stream>>>(
      dbl1, dbl2, dtw1, dtw2, dtb1, dtb2, sp1T, sp2T);

  // 7) chunked selective scan
  scan_phase_a<<<dim3(DIN / 256, NCH, 2), blk, 0, stream>>>(
      xcT_hi, xcT_lo, sp1T, sp2T, BT1, BT2, Al1, Al2, hend, Pend);
  scan_carry<<<dim3(2 * DIN * NST / 256), blk, 0, stream>>>(hend, Pend);
  cvt_split<<<dim3(2048), blk, 0, stream>>>(outw, ow_hi, ow_lo, DMODEL * DIN);
  scan_phase_c<<<dim3(DIN / 256, NCH, 2), blk, 0, stream>>>(
      xcT_hi, xcT_lo, sp1T, sp2T, BT1, CT1, BT2, CT2, Al1, Al2, D1, D2, Pend, y1t, y2t);

  // 8) (y1-y2)*silu(z) -> bf16 planes (tiled transpose of z)
  ydiff_tr_kernel<<<dim3(SEQ / 64, DIN / 64), blk, 0, stream>>>(
      y1t, y2t, xz, yd_hi, yd_lo);

  // 9) out_proj via 3-pass bf16 MFMA, split-K=4
  gemm3p<128, 128, 4><<<dim3(DMODEL / 128, SEQ / 128, 4), blk, 0, stream>>>(
      yd_hi, yd_lo, ow_hi, ow_lo, opart, SEQ, DMODEL, DIN);
  reduce_out<<<dim3(SEQ * DMODEL / 1024), blk, 0, stream>>>(opart, out, SEQ * DMODEL);
}

// Round 8
// 334.751 us; speedup vs baseline: 3.4958x; 1.0716x over previous
//
#include <hip/hip_runtime.h>
#include <math.h>

#define SEQ 2048
#define DMODEL 1024
#define DIN 2048
#define NST 16
#define DTR 64
#define CH 64
#define NCH (SEQ / CH)

typedef __attribute__((ext_vector_type(8))) short bf16x8;
typedef __attribute__((ext_vector_type(4))) float f32x4;

__device__ __forceinline__ ushort f2bf(float f) {
  union { float f; unsigned u; } c; c.f = f;
  return (ushort)((c.u + 0x7fffu + ((c.u >> 16) & 1u)) >> 16);
}
__device__ __forceinline__ float bf2f(ushort h) {
  union { unsigned u; float f; } c; c.u = ((unsigned)h) << 16;
  return c.f;
}
__device__ __forceinline__ float splus(float v) {
  return v > 20.f ? v : log1pf(__expf(v));
}
// p[n] = e^(n+1), depth-4 mul tree (no transcendentals).
__device__ __forceinline__ void powers16(float e, float* p) {
  float e2 = e * e, e4 = e2 * e2, e8 = e4 * e4;
  p[0] = e;       p[1] = e2;       p[2] = e2 * e;   p[3] = e4;
  p[4] = e4 * e;  p[5] = e4 * e2;  p[6] = e4 * p[2]; p[7] = e8;
  p[8] = e8 * e;  p[9] = e8 * e2;  p[10] = e8 * p[2]; p[11] = e8 * e4;
  p[12] = e8 * p[4]; p[13] = e8 * p[5]; p[14] = e8 * p[6]; p[15] = e8 * e8;
}

#define GLL(g, l) __builtin_amdgcn_global_load_lds( \
    (const __attribute__((address_space(1))) void*)(g), \
    (__attribute__((address_space(3))) void*)(l), 16, 0, 0)

// =====================================================================
// Split-bf16 3-pass MFMA GEMM (fp32-accurate).  C[m,n]=sum_k A[m,k]B[n,k]
// Staging: round-5 global lane map (4 consecutive lanes = one row's 64B,
// burst-coalesced) + XOR swizzle of the 16B k-chunk (phys = c ^ ((r>>1)&3)).
// Fragment ds_read_b128 then lands 2 lanes/bank-quad = 2-way = free.
// =====================================================================
template<int BM, int BN, int SPLITK>
__global__ __launch_bounds__(256) void gemm3p(const ushort* __restrict__ Ahi,
                                              const ushort* __restrict__ Alo,
                                              const ushort* __restrict__ Bhi,
                                              const ushort* __restrict__ Blo,
                                              float* __restrict__ C,
                                              int M, int N, int K) {
  constexpr int BK = 32;
  constexpr int WM = BM / 2, WN = BN / 2, TM = WM / 16, TN = WN / 16;
  constexpr int SA = BM / 16, SB = BN / 16;
  __shared__ __align__(16) ushort sAh[BM * BK], sAl[BM * BK];
  __shared__ __align__(16) ushort sBh[BN * BK], sBl[BN * BK];
  const int tid = threadIdx.x, wid = tid >> 6, lane = tid & 63;
  const int m0 = blockIdx.y * BM, n0 = blockIdx.x * BN;
  const int Kc = K / SPLITK, kbeg = blockIdx.z * Kc;
  const int wm0 = (wid >> 1) * WM, wn0 = (wid & 1) * WN;
  const int fr = lane & 15;
  // store side: lane L -> row L>>2, global k-chunk (L&3)^((L>>3)&3)
  const int lrow = lane >> 2;
  const int lkc = (lane & 3) ^ ((lane >> 3) & 3);
  // read side: lane R -> row R&15, phys chunk (R>>4)^((R>>1)&3)
  const int fpo = fr * 32 + (((lane >> 4) ^ ((lane >> 1) & 3)) * 8);

  f32x4 acc[TM][TN];
#pragma unroll
  for (int mi = 0; mi < TM; ++mi)
#pragma unroll
    for (int ni = 0; ni < TN; ++ni)
#pragma unroll
      for (int r = 0; r < 4; ++r) acc[mi][ni][r] = 0.f;

  for (int k0 = 0; k0 < Kc; k0 += BK) {
    __syncthreads();
    const int kg = kbeg + k0 + lkc * 8;
#pragma unroll
    for (int i = 0; i < SA / 4; ++i) {
      const int seg = wid * (SA / 4) + i;
      const size_t ga = (size_t)(m0 + seg * 16 + lrow) * K + kg;
      GLL(&Ahi[ga], &sAh[seg * 512]);
      GLL(&Alo[ga], &sAl[seg * 512]);
    }
#pragma unroll
    for (int i = 0; i < SB / 4; ++i) {
      const int seg = wid * (SB / 4) + i;
      const size_t ga = (size_t)(n0 + seg * 16 + lrow) * K + kg;
      GLL(&Bhi[ga], &sBh[seg * 512]);
      GLL(&Blo[ga], &sBl[seg * 512]);
    }
    __syncthreads();

    bf16x8 ah[TM], al[TM], bh[TN], bl[TN];
#pragma unroll
    for (int mi = 0; mi < TM; ++mi) {
      const int r = (wm0 / 16 + mi) * 512 + fpo;
      ah[mi] = *(const bf16x8*)&sAh[r];
      al[mi] = *(const bf16x8*)&sAl[r];
    }
#pragma unroll
    for (int ni = 0; ni < TN; ++ni) {
      const int r = (wn0 / 16 + ni) * 512 + fpo;
      bh[ni] = *(const bf16x8*)&sBh[r];
      bl[ni] = *(const bf16x8*)&sBl[r];
    }
#pragma unroll
    for (int mi = 0; mi < TM; ++mi)
#pragma unroll
      for (int ni = 0; ni < TN; ++ni) {
        acc[mi][ni] = __builtin_amdgcn_mfma_f32_16x16x32_bf16(ah[mi], bh[ni], acc[mi][ni], 0, 0, 0);
        acc[mi][ni] = __builtin_amdgcn_mfma_f32_16x16x32_bf16(ah[mi], bl[ni], acc[mi][ni], 0, 0, 0);
        acc[mi][ni] = __builtin_amdgcn_mfma_f32_16x16x32_bf16(al[mi], bh[ni], acc[mi][ni], 0, 0, 0);
      }
  }

  float* __restrict__ Co = C + (size_t)blockIdx.z * M * N;
#pragma unroll
  for (int mi = 0; mi < TM; ++mi)
#pragma unroll
    for (int ni = 0; ni < TN; ++ni)
#pragma unroll
      for (int r = 0; r < 4; ++r)
        Co[(size_t)(m0 + wm0 + mi * 16 + (lane >> 4) * 4 + r) * N + n0 + wn0 + ni * 16 + fr] =
            acc[mi][ni][r];
}

__device__ __forceinline__ void split_store4(float4 v, ushort* hi, ushort* lo, size_t i) {
  ushort h0 = f2bf(v.x), h1 = f2bf(v.y), h2 = f2bf(v.z), h3 = f2bf(v.w);
  *(ushort4*)&hi[i] = make_ushort4(h0, h1, h2, h3);
  *(ushort4*)&lo[i] = make_ushort4(f2bf(v.x - bf2f(h0)), f2bf(v.y - bf2f(h1)),
                                   f2bf(v.z - bf2f(h2)), f2bf(v.w - bf2f(h3)));
}

// One launch converting in_proj_w, hidden, x1w, x2w -> bf16 hi/lo planes.
__global__ __launch_bounds__(256) void cvt_fused(const float* __restrict__ inw,
                                                 const float* __restrict__ hid,
                                                 const float* __restrict__ x1w,
                                                 const float* __restrict__ x2w,
                                                 ushort* __restrict__ w_hi, ushort* __restrict__ w_lo,
                                                 ushort* __restrict__ h_hi, ushort* __restrict__ h_lo,
                                                 ushort* __restrict__ wx_hi, ushort* __restrict__ wx_lo) {
  const int q = blockIdx.x * 256 + threadIdx.x;  // float4 index
  const float* src; ushort* dhi; ushort* dlo; int base;
  if (q < 1048576)            { src = inw; dhi = w_hi;  dlo = w_lo;  base = q; }
  else if (q < 1572864)       { src = hid; dhi = h_hi;  dlo = h_lo;  base = q - 1048576; }
  else if (q < 1622016)       { src = x1w; dhi = wx_hi; dlo = wx_lo; base = q - 1572864; }
  else                        { src = x2w; dhi = wx_hi + 196608; dlo = wx_lo + 196608; base = q - 1622016; }
  const size_t i = (size_t)base * 4;
  split_store4(*(const float4*)&src[i], dhi, dlo, i);
}

__global__ __launch_bounds__(256) void cvt_split(const float* __restrict__ x,
                                                 ushort* __restrict__ hi,
                                                 ushort* __restrict__ lo, int n) {
  const int i = (blockIdx.x * 256 + threadIdx.x) * 4;
  if (i >= n) return;
  split_store4(*(const float4*)&x[i], hi, lo, i);
}

__global__ __launch_bounds__(256) void reduce_out(const float* __restrict__ p,
                                                  float* __restrict__ o, int n) {
  const int i = (blockIdx.x * 256 + threadIdx.x) * 4;
  if (i >= n) return;
  float4 a = *(const float4*)&p[i];
  float4 b = *(const float4*)&p[(size_t)n + i];
  float4 c = *(const float4*)&p[(size_t)2 * n + i];
  float4 d = *(const float4*)&p[(size_t)3 * n + i];
  *(float4*)&o[i] = make_float4(a.x + b.x + c.x + d.x, a.y + b.y + c.y + d.y,
                                a.z + b.z + c.z + d.z, a.w + b.w + c.w + d.w);
}

// =====================================================================
// Conv (w=4, causal) + bias + SiLU -> transposed bf16 hi/lo planes (l,d).
// =====================================================================
__global__ __launch_bounds__(256) void conv_tr_kernel(const float* __restrict__ xz,
                                                      const float* __restrict__ cw,
                                                      const float* __restrict__ cb,
                                                      ushort* __restrict__ xcT_hi,
                                                      ushort* __restrict__ xcT_lo) {
  const int l0 = blockIdx.x * 64, d0 = blockIdx.y * 64;
  const int tid = threadIdx.x;
  __shared__ float xin[64][68];  // cols 0..66 = l0-3 .. l0+63
  __shared__ float To[64][65];
  __shared__ float cwS[64][4];
  __shared__ float cbS[64];

  for (int i = tid; i < 1024; i += 256) {
    const int d = i >> 4, q = i & 15;
    float4 v = *(const float4*)&xz[(size_t)(d0 + d) * SEQ + l0 + q * 4];
    xin[d][3 + q * 4 + 0] = v.x; xin[d][3 + q * 4 + 1] = v.y;
    xin[d][3 + q * 4 + 2] = v.z; xin[d][3 + q * 4 + 3] = v.w;
  }
  if (tid < 192) {
    const int j = tid >> 6, d = tid & 63;
    const int l = l0 - 3 + j;
    xin[d][j] = (l >= 0) ? xz[(size_t)(d0 + d) * SEQ + l] : 0.f;
  }
  if (tid < 64) {
    cbS[tid] = cb[d0 + tid];
    float4 w = *(const float4*)&cw[(d0 + tid) * 4];
    cwS[tid][0] = w.x; cwS[tid][1] = w.y; cwS[tid][2] = w.z; cwS[tid][3] = w.w;
  }
  __syncthreads();

  for (int i = tid; i < 4096; i += 256) {
    const int d = i >> 6, l = i & 63;
    float a = cbS[d] + cwS[d][0] * xin[d][l] + cwS[d][1] * xin[d][l + 1] +
              cwS[d][2] * xin[d][l + 2] + cwS[d][3] * xin[d][l + 3];
    To[d][l] = a / (1.f + __expf(-a));
  }
  __syncthreads();

  for (int i = tid; i < 4096; i += 256) {
    const int l = i >> 6, dd = i & 63;
    float v = To[dd][l];  // stride-65: conflict-free
    ushort h = f2bf(v);
    xcT_hi[(size_t)(l0 + l) * DIN + d0 + dd] = h;
    xcT_lo[(size_t)(l0 + l) * DIN + d0 + dd] = f2bf(v - bf2f(h));
  }
}

// (y1raw - y2raw) * silu(z), tiled with LDS transpose of z; -> bf16 planes.
__global__ __launch_bounds__(256) void ydiff_tr_kernel(const float* __restrict__ y1,
                                                       const float* __restrict__ y2,
                                                       const float* __restrict__ xz,
                                                       ushort* __restrict__ hi,
                                                       ushort* __restrict__ lo) {
  const int l0 = blockIdx.x * 64, d0 = blockIdx.y * 64;
  const int tid = threadIdx.x;
  __shared__ float Tz[64][65];
  for (int i = tid; i < 1024; i += 256) {
    const int d = i >> 4, q = i & 15;
    float4 v = *(const float4*)&xz[(size_t)(DIN + d0 + d) * SEQ + l0 + q * 4];
    Tz[d][q * 4 + 0] = v.x / (1.f + __expf(-v.x));
    Tz[d][q * 4 + 1] = v.y / (1.f + __expf(-v.y));
    Tz[d][q * 4 + 2] = v.z / (1.f + __expf(-v.z));
    Tz[d][q * 4 + 3] = v.w / (1.f + __expf(-v.w));
  }
  __syncthreads();
  for (int i = tid; i < 1024; i += 256) {
    const int l = i >> 4, dc = (i & 15) * 4;
    const size_t g = (size_t)(l0 + l) * DIN + d0 + dc;
    float4 a = *(const float4*)&y1[g];
    float4 b = *(const float4*)&y2[g];
    float4 v = make_float4((a.x - b.x) * Tz[dc + 0][l], (a.y - b.y) * Tz[dc + 1][l],
                           (a.z - b.z) * Tz[dc + 2][l], (a.w - b.w) * Tz[dc + 3][l]);
    split_store4(v, hi, lo, g);
  }
}

// Reduce 8 x_proj split-K slabs (192 x SEQ) -> dblS; emit B/C (l,n) tables.
__global__ __launch_bounds__(256) void reduce_dblS_kernel(const float* __restrict__ p,
                                                          float* __restrict__ o,
                                                          float* __restrict__ BT1,
                                                          float* __restrict__ CT1,
                                                          float* __restrict__ BT2,
                                                          float* __restrict__ CT2) {
  const int NE = 192 * SEQ;
  const int idx = blockIdx.x * 256 + threadIdx.x;
  float s = 0.f;
#pragma unroll
  for (int cc = 0; cc < 8; ++cc) s += p[(size_t)cc * NE + idx];
  o[idx] = s;
  const int k = idx >> 11, l = idx & (SEQ - 1);
  if (k >= 64 && k < 80)        BT1[l * NST + (k - 64)] = s;
  else if (k >= 80 && k < 96)   CT1[l * NST + (k - 80)] = s;
  else if (k >= 160 && k < 176) BT2[l * NST + (k - 160)] = s;
  else if (k >= 176)            CT2[l * NST + (k - 176)] = s;
}

// =====================================================================
// dt GEMM + fused softplus(dt+bias); output sp in (l,d) layout (coalesced
// for the scan's per-timestep reads).
// =====================================================================
__global__ __launch_bounds__(256) void dt_gemm_kernel(const float* __restrict__ dbl1,
                                                      const float* __restrict__ dbl2,
                                                      const float* __restrict__ w1,
                                                      const float* __restrict__ w2,
                                                      const float* __restrict__ b1,
                                                      const float* __restrict__ b2,
                                                      float* __restrict__ o1,
                                                      float* __restrict__ o2) {
  const int br = blockIdx.z;
  const float* __restrict__ dbl = br ? dbl2 : dbl1;
  const float* __restrict__ W = br ? w2 : w1;
  const float* __restrict__ dtb = br ? b2 : b1;
  float* __restrict__ outp = br ? o2 : o1;
  const int l0 = blockIdx.x * 64, d0 = blockIdx.y * 64;
  __shared__ __align__(16) float Wt[64][68];
  __shared__ __align__(16) float Bs[64][68];
  const int tid = threadIdx.x;
  for (int i = tid; i < 4096; i += 256) {
    int a = i >> 6, b = i & 63;
    Wt[b][a] = W[(size_t)(d0 + a) * DTR + b];
    Bs[a][b] = dbl[(size_t)a * SEQ + l0 + b];
  }
  __syncthreads();
  const int tl_ = tid >> 4, td_ = tid & 15;
  float acc[4][4];  // [i: l][j: d]
#pragma unroll
  for (int i = 0; i < 4; ++i)
#pragma unroll
    for (int j = 0; j < 4; ++j) acc[i][j] = 0.f;
  for (int r = 0; r < 64; ++r) {
    float4 av = *(const float4*)&Bs[r][tl_ * 4];
    float4 bv = *(const float4*)&Wt[r][td_ * 4];
    float am[4] = {av.x, av.y, av.z, av.w};
    float bn[4] = {bv.x, bv.y, bv.z, bv.w};
#pragma unroll
    for (int i = 0; i < 4; ++i)
#pragma unroll
      for (int j = 0; j < 4; ++j) acc[i][j] = fmaf(am[i], bn[j], acc[i][j]);
  }
  const float4 bias4 = *(const float4*)&dtb[d0 + td_ * 4];
#pragma unroll
  for (int i = 0; i < 4; ++i) {
    float4 w = make_float4(splus(acc[i][0] + bias4.x), splus(acc[i][1] + bias4.y),
                           splus(acc[i][2] + bias4.z), splus(acc[i][3] + bias4.w));
    *(float4*)&outp[(size_t)(l0 + tl_ * 4 + i) * DIN + d0 + td_ * 4] = w;
  }
}

// =====================================================================
// Chunked selective scan.  All per-timestep inputs in (l,d) layout ->
// coalesced scalar loads.  u = hi+lo bf16 reconstruction (2^-18 exact).
// dA_n = exp(-k_n*sp); fast path when k_n == n+1 (one exp + mul tree).
// =====================================================================
__global__ __launch_bounds__(256) void scan_phase_a(const ushort* __restrict__ uhi,
                                                    const ushort* __restrict__ ulo,
                                                    const float* __restrict__ sp1T,
                                                    const float* __restrict__ sp2T,
                                                    const float* __restrict__ BT1,
                                                    const float* __restrict__ BT2,
                                                    const float* __restrict__ Al1,
                                                    const float* __restrict__ Al2,
                                                    float* __restrict__ hend,
                                                    float* __restrict__ Pend) {
  const int br = blockIdx.z;
  const float* __restrict__ spp = br ? sp2T : sp1T;
  const float* __restrict__ BT = br ? BT2 : BT1;
  const float* __restrict__ Al = br ? Al2 : Al1;
  const int c = blockIdx.y;
  const int t0 = c * CH;
  const int d = blockIdx.x * 256 + threadIdx.x;
  const size_t gbase = (size_t)t0 * DIN + d;

  __shared__ __align__(16) float Bs[CH][NST];
  ((float4*)Bs)[threadIdx.x] = ((const float4*)&BT[t0 * NST])[threadIdx.x];
  __syncthreads();

  bool fast = true;
#pragma unroll
  for (int n = 0; n < NST; ++n) {
    float kx = __expf(Al[(size_t)d * NST + n]);
    fast = fast && (fabsf(kx - (float)(n + 1)) < 1e-3f);
  }
  float h[NST];
#pragma unroll
  for (int n = 0; n < NST; ++n) h[n] = 0.f;
  float S = 0.f;

  if (fast) {
    for (int tt = 0; tt < CH / 4; ++tt) {
      float sparr[4], uarr[4];
#pragma unroll
      for (int j = 0; j < 4; ++j) {
        const size_t idx = gbase + (size_t)(tt * 4 + j) * DIN;
        sparr[j] = spp[idx];
        uarr[j] = bf2f(uhi[idx]) + bf2f(ulo[idx]);
      }
#pragma unroll
      for (int j = 0; j < 4; ++j) {
        const int t = tt * 4 + j;
        const float sp = sparr[j];
        S += sp;
        const float spu = sp * uarr[j];
        const float e = __expf(-sp);
        float p[NST];
        powers16(e, p);
#pragma unroll
        for (int ng = 0; ng < 4; ++ng) {
          float4 bq = *(const float4*)&Bs[t][ng * 4];
          float bf[4] = {bq.x, bq.y, bq.z, bq.w};
#pragma unroll
          for (int k = 0; k < 4; ++k) {
            int n = ng * 4 + k;
            h[n] = fmaf(p[n], h[n], spu * bf[k]);
          }
        }
      }
    }
  } else {
    float AnL2[NST];
#pragma unroll
    for (int n = 0; n < NST; ++n)
      AnL2[n] = -__expf(Al[(size_t)d * NST + n]) * 1.4426950408889634f;
    for (int tt = 0; tt < CH / 4; ++tt) {
      float sparr[4], uarr[4];
#pragma unroll
      for (int j = 0; j < 4; ++j) {
        const size_t idx = gbase + (size_t)(tt * 4 + j) * DIN;
        sparr[j] = spp[idx];
        uarr[j] = bf2f(uhi[idx]) + bf2f(ulo[idx]);
      }
#pragma unroll
      for (int j = 0; j < 4; ++j) {
        const int t = tt * 4 + j;
        const float sp = sparr[j];
        S += sp;
        const float spu = sp * uarr[j];
#pragma unroll
        for (int ng = 0; ng < 4; ++ng) {
          float4 bq = *(const float4*)&Bs[t][ng * 4];
          float bf[4] = {bq.x, bq.y, bq.z, bq.w};
#pragma unroll
          for (int k = 0; k < 4; ++k) {
            int n = ng * 4 + k;
            float dA = exp2f(AnL2[n] * sp);
            h[n] = fmaf(dA, h[n], spu * bf[k]);
          }
        }
      }
    }
  }

  float P[NST];
  if (fast) {
    powers16(__expf(-S), P);
  } else {
#pragma unroll
    for (int n = 0; n < NST; ++n)
      P[n] = exp2f(-__expf(Al[(size_t)d * NST + n]) * 1.4426950408889634f * S);
  }
  size_t base = ((size_t)(br * NCH + c) * DIN + d) * NST;
#pragma unroll
  for (int n = 0; n < NST; n += 4) {
    *(float4*)&hend[base + n] = make_float4(h[n], h[n + 1], h[n + 2], h[n + 3]);
    *(float4*)&Pend[base + n] = make_float4(P[n], P[n + 1], P[n + 2], P[n + 3]);
  }
}

// Carry across chunks; hin overwrites Pend in place (read P first).
__global__ __launch_bounds__(256) void scan_carry(const float* __restrict__ hend,
                                                  float* __restrict__ PendHin) {
  const int flat = blockIdx.x * 256 + threadIdx.x;
  const int br = flat >> 15;
  const int dn = flat & 32767;
  float h = 0.f;
  for (int c = 0; c < NCH; ++c) {
    size_t idx = ((size_t)(br * NCH + c) << 15) + dn;
    float Pv = PendHin[idx];
    float he = hend[idx];
    PendHin[idx] = h;
    h = fmaf(Pv, h, he);
  }
}

// Phase C: raw y (silu(z) applied later in ydiff_tr), (l,d) writes.
__global__ __launch_bounds__(256) void scan_phase_c(const ushort* __restrict__ uhi,
                                                    const ushort* __restrict__ ulo,
                                                    const float* __restrict__ sp1T,
                                                    const float* __restrict__ sp2T,
                                                    const float* __restrict__ BT1,
                                                    const float* __restrict__ CT1,
                                                    const float* __restrict__ BT2,
                                                    const float* __restrict__ CT2,
                                                    const float* __restrict__ Al1,
                                                    const float* __restrict__ Al2,
                                                    const float* __restrict__ D1,
                                                    const float* __restrict__ D2,
                                                    const float* __restrict__ hin,
                                                    float* __restrict__ y1t,
                                                    float* __restrict__ y2t) {
  const int br = blockIdx.z;
  const float* __restrict__ spp = br ? sp2T : sp1T;
  const float* __restrict__ BT = br ? BT2 : BT1;
  const float* __restrict__ CT = br ? CT2 : CT1;
  const float* __restrict__ Al = br ? Al2 : Al1;
  const float* __restrict__ Dp = br ? D2 : D1;
  float* __restrict__ yt = br ? y2t : y1t;
  const int c = blockIdx.y;
  const int t0 = c * CH;
  const int d = blockIdx.x * 256 + threadIdx.x;
  const size_t gbase = (size_t)t0 * DIN + d;

  __shared__ __align__(16) float Bs[CH][NST];
  __shared__ __align__(16) float Cs[CH][NST];
  ((float4*)Bs)[threadIdx.x] = ((const float4*)&BT[t0 * NST])[threadIdx.x];
  ((float4*)Cs)[threadIdx.x] = ((const float4*)&CT[t0 * NST])[threadIdx.x];
  __syncthreads();

  bool fast = true;
#pragma unroll
  for (int n = 0; n < NST; ++n) {
    float kx = __expf(Al[(size_t)d * NST + n]);
    fast = fast && (fabsf(kx - (float)(n + 1)) < 1e-3f);
  }
  const float Dd = Dp[d];
  float h[NST];
  const size_t hbase = ((size_t)(br * NCH + c) * DIN + d) * NST;
#pragma unroll
  for (int n = 0; n < NST; n += 4) {
    float4 hv = *(const float4*)&hin[hbase + n];
    h[n] = hv.x; h[n + 1] = hv.y; h[n + 2] = hv.z; h[n + 3] = hv.w;
  }

  if (fast) {
    for (int tt = 0; tt < CH / 4; ++tt) {
      float sparr[4], uarr[4];
#pragma unroll
      for (int j = 0; j < 4; ++j) {
        const size_t idx = gbase + (size_t)(tt * 4 + j) * DIN;
        sparr[j] = spp[idx];
        uarr[j] = bf2f(uhi[idx]) + bf2f(ulo[idx]);
      }
#pragma unroll
      for (int j = 0; j < 4; ++j) {
        const int t = tt * 4 + j;
        const float sp = sparr[j];
        const float spu = sp * uarr[j];
        const float e = __expf(-sp);
        float p[NST];
        powers16(e, p);
        float y = 0.f;
#pragma unroll
        for (int ng = 0; ng < 4; ++ng) {
          float4 bq = *(const float4*)&Bs[t][ng * 4];
          float4 cq = *(const float4*)&Cs[t][ng * 4];
          float bf[4] = {bq.x, bq.y, bq.z, bq.w};
          float cf[4] = {cq.x, cq.y, cq.z, cq.w};
#pragma unroll
          for (int k = 0; k < 4; ++k) {
            int n = ng * 4 + k;
            h[n] = fmaf(p[n], h[n], spu * bf[k]);
            y = fmaf(h[n], cf[k], y);
          }
        }
        yt[gbase + (size_t)t * DIN] = y + Dd * uarr[j];
      }
    }
  } else {
    float AnL2[NST];
#pragma unroll
    for (int n = 0; n < NST; ++n)
      AnL2[n] = -__expf(Al[(size_t)d * NST + n]) * 1.4426950408889634f;
    for (int tt = 0; tt < CH / 4; ++tt) {
      float sparr[4], uarr[4];
#pragma unroll
      for (int j = 0; j < 4; ++j) {
        const size_t idx = gbase + (size_t)(tt * 4 + j) * DIN;
        sparr[j] = spp[idx];
        uarr[j] = bf2f(uhi[idx]) + bf2f(ulo[idx]);
      }
#pragma unroll
      for (int j = 0; j < 4; ++j) {
        const int t = tt * 4 + j;
        const float sp = sparr[j];
        const float spu = sp * uarr[j];
        float y = 0.f;
#pragma unroll
        for (int ng = 0; ng < 4; ++ng) {
          float4 bq = *(const float4*)&Bs[t][ng * 4];
          float4 cq = *(const float4*)&Cs[t][ng * 4];
          float bf[4] = {bq.x, bq.y, bq.z, bq.w};
          float cf[4] = {cq.x, cq.y, cq.z, cq.w};
#pragma unroll
          for (int k = 0; k < 4; ++k) {
            int n = ng * 4 + k;
            float dA = exp2f(AnL2[n] * sp);
            h[n] = fmaf(dA, h[n], spu * bf[k]);
            y = fmaf(h[n], cf[k], y);
          }
        }
        yt[gbase + (size_t)t * DIN] = y + Dd * uarr[j];
      }
    }
  }
}

// =====================================================================
extern "C" void kernel_launch(void* const* d_in, const int* in_sizes, int n_in,
                              void* d_out, int out_size, void* d_ws, size_t ws_size,
                              hipStream_t stream) {
  const float* hidden = (const float*)d_in[0];
  const float* in_proj_w = (const float*)d_in[1];
  const float* conv_w = (const float*)d_in[2];
  const float* conv_b = (const float*)d_in[3];
  const float* x1w = (const float*)d_in[4];
  const float* dtw1 = (const float*)d_in[5];
  const float* dtb1 = (const float*)d_in[6];
  const float* Al1 = (const float*)d_in[7];
  const float* D1 = (const float*)d_in[8];
  const float* x2w = (const float*)d_in[9];
  const float* dtw2 = (const float*)d_in[10];
  const float* dtb2 = (const float*)d_in[11];
  const float* Al2 = (const float*)d_in[12];
  const float* D2 = (const float*)d_in[13];
  const float* outw = (const float*)d_in[14];
  float* out = (float*)d_out;

  // Workspace layout (floats), 34.47M = 137.9 MB (same as proven round 5).
  float* ws = (float*)d_ws;
  float* xz = ws;                                   // 8.39M  (x rows, z rows)
  float* xcTbuf = xz + (size_t)4096 * SEQ;          // 4.19M  xcT bf16 hi/lo planes
  float* dblS = xcTbuf + (size_t)SEQ * DIN;         // 393K
  float* sp1T = dblS + (size_t)192 * SEQ;           // 4.19M  softplus'd dt, (l,d)
  float* sp2T = sp1T + (size_t)SEQ * DIN;           // 4.19M
  float* y1t = sp2T + (size_t)SEQ * DIN;            // 4.19M  (l,d) raw y
  float* y2t = y1t + (size_t)SEQ * DIN;             // 4.19M
  float* hend = y2t + (size_t)SEQ * DIN;            // 2.10M
  float* Pend = hend + (size_t)2 * NCH * DIN * NST; // 2.10M (reused as hin)
  float* BT1 = Pend + (size_t)2 * NCH * DIN * NST;  // 32K each
  float* CT1 = BT1 + (size_t)SEQ * NST;
  float* BT2 = CT1 + (size_t)SEQ * NST;
  float* CT2 = BT2 + (size_t)SEQ * NST;
  float* wxp = CT2 + (size_t)SEQ * NST;             // 393K stacked x_proj W planes

  float* dbl1 = dblS;
  float* dbl2 = dblS + (size_t)96 * SEQ;

  // Aliases (lifetime-disjoint):
  ushort* xcT_hi = (ushort*)xcTbuf;                 // steps 3..7
  ushort* xcT_lo = (ushort*)(xcTbuf + 2097152);
  ushort* w_hi = (ushort*)y1t;                      // in_proj_w planes (dead after step 2)
  ushort* w_lo = (ushort*)(y1t + 2097152);
  ushort* h_hi = (ushort*)y2t;                      // hidden planes (dead after step 2)
  ushort* h_lo = (ushort*)(y2t + 1048576);
  ushort* wx_hi = (ushort*)wxp;                     // stacked x_proj weights 192x2048
  ushort* wx_lo = (ushort*)(wxp + 196608);
  float* xp_part = sp1T;                            // 8 slabs x 192*2048 = 3.15M < 4.19M
  ushort* yd_hi = (ushort*)xcTbuf;                  // ydiff planes (xcT dead after phase C)
  ushort* yd_lo = (ushort*)(xcTbuf + 2097152);
  // outw planes fit EXACTLY inside hend's 2.10M floats (1.05M floats each).
  ushort* ow_hi = (ushort*)hend;
  ushort* ow_lo = (ushort*)(hend + 1048576);
  float* opart = xz;                                // out_proj split-K partials (xz dead after ydiff)

  dim3 blk(256);

  // 1) fused split-convert: in_proj_w, hidden, x1w, x2w
  cvt_fused<<<dim3(6528), blk, 0, stream>>>(in_proj_w, hidden, x1w, x2w,
                                            w_hi, w_lo, h_hi, h_lo, wx_hi, wx_lo);

  // 2) in_proj via 3-pass bf16 MFMA -> xz (e,l)
  gemm3p<128, 128, 1><<<dim3(SEQ / 128, 4096 / 128, 1), blk, 0, stream>>>(
      w_hi, w_lo, h_hi, h_lo, xz, 4096, SEQ, DMODEL);

  // 3) conv + silu -> xcT bf16 hi/lo planes (l,d)
  conv_tr_kernel<<<dim3(SEQ / 64, DIN / 64), blk, 0, stream>>>(
      xz, conv_w, conv_b, xcT_hi, xcT_lo);

  // 4) x_proj via MFMA, split-K=8 (both branches stacked, M=192)
  gemm3p<64, 128, 8><<<dim3(SEQ / 128, 192 / 64, 8), blk, 0, stream>>>(
      wx_hi, wx_lo, xcT_hi, xcT_lo, xp_part, 192, SEQ, DIN);

  // 5) reduce slabs -> dblS + B/C transpose tables
  reduce_dblS_kernel<<<dim3(192 * SEQ / 256), blk, 0, stream>>>(
      xp_part, dblS, BT1, CT1, BT2, CT2);

  // 6) dt projection + fused softplus -> sp planes, (l,d)
  dt_gemm_kernel<<<dim3(SEQ / 64, DIN / 64, 2), blk, 0, stream>>>(
      dbl1, dbl2, dtw1, dtw2, dtb1, dtb2, sp1T, sp2T);

  // 7) chunked selective scan
  scan_phase_a<<<dim3(DIN / 256, NCH, 2), blk, 0, stream>>>(
      xcT_hi, xcT_lo, sp1T, sp2T, BT1, BT2, Al1, Al2, hend, Pend);
  scan_carry<<<dim3(2 * DIN * NST / 256), blk, 0, stream>>>(hend, Pend);
  cvt_split<<<dim3(2048), blk, 0, stream>>>(outw, ow_hi, ow_lo, DMODEL * DIN);
  scan_phase_c<<<dim3(DIN / 256, NCH, 2), blk, 0, stream>>>(
      xcT_hi, xcT_lo, sp1T, sp2T, BT1, CT1, BT2, CT2, Al1, Al2, D1, D2, Pend, y1t, y2t);

  // 8) (y1-y2)*silu(z) -> bf16 planes (tiled transpose of z)
  ydiff_tr_kernel<<<dim3(SEQ / 64, DIN / 64), blk, 0, stream>>>(
      y1t, y2t, xz, yd_hi, yd_lo);

  // 9) out_proj via 3-pass bf16 MFMA, split-K=4
  gemm3p<128, 128, 4><<<dim3(DMODEL / 128, SEQ / 128, 4), blk, 0, stream>>>(
      yd_hi, yd_lo, ow_hi, ow_lo, opart, SEQ, DMODEL, DIN);
  reduce_out<<<dim3(SEQ * DMODEL / 1024), blk, 0, stream>>>(opart, out, SEQ * DMODEL);
}